// Round 3
// baseline (8242.533 us; speedup 1.0000x reference)
//
#include <hip/hip_runtime.h>

// ---------------------------------------------------------------------------
// GraphSAGE GNN forward, MI355X round 3: dtype-agnostic (probe f32 vs bf16),
// canonical bf16 internal pipeline.
// ws (132 MB):
//  [0: deg 256K][256K: m1 128K][384K: m2 128K][512K: lst 1K][516K: flag]
//  [520K: pooled f32 384K][1MB: PB param pool bf16 ~1.9MB]
//  [4MB: S0 32MB][36MB: S1][68MB: S2][100MB: S3]  (S1..S3 = qkv 96MB overlay)
//  [100MB: XB x-bf16 16MB overlays S3 (dead until attention)]
// ---------------------------------------------------------------------------

#define N_TOT   65536
#define B_GR    128
#define NP_     512
#define E_TOT   524288
#define EPG     4096
#define DIN_    128
#define C_      256
#define C3_     768
#define H_      4

typedef unsigned int uint;
typedef unsigned short ushort;

// param pool element offsets (ushorts)
#define O_L0LW  0u
#define O_L0LB  32768u
#define O_L0RW  33024u
#define O_L0RES 65792u
#define O_LWL   98560u
#define O_LBL   295168u
#define O_LWR   295936u
#define O_GNW   492544u
#define O_GNB   493568u
#define O_GNA   494592u
#define O_AIW   495616u
#define O_AIB   692224u
#define O_AOW   692992u
#define O_AOB   758528u
#define O_LNW   758784u
#define O_LNB   759040u
#define O_PLW   759296u
#define O_PLB   955904u
#define TOTALP  956160u

__device__ __forceinline__ float bf2f(ushort u){ union{uint i; float f;} v; v.i = ((uint)u) << 16; return v.f; }
__device__ __forceinline__ float u2f_lo(uint u){ union{uint i; float f;} v; v.i = u << 16; return v.f; }
__device__ __forceinline__ float u2f_hi(uint u){ union{uint i; float f;} v; v.i = u & 0xffff0000u; return v.f; }
__device__ __forceinline__ ushort f2bf(float f){
  union{float f; uint u;} v; v.f = f;
  uint u = v.u;
  u += 0x7fffu + ((u >> 16) & 1u);   // RNE
  return (ushort)(u >> 16);
}
__device__ __forceinline__ uint pack2(float a, float b){ return (uint)f2bf(a) | ((uint)f2bf(b) << 16); }
__device__ __forceinline__ float gelu_f(float x){ return 0.5f * x * (1.0f + erff(x * 0.70710678118654752440f)); }
__device__ __forceinline__ float wredsum(float v){
  #pragma unroll
  for (int off = 32; off; off >>= 1) v += __shfl_xor(v, off, 64);
  return v;
}
__device__ __forceinline__ float wredmax(float v){
  #pragma unroll
  for (int off = 32; off; off >>= 1) v = fmaxf(v, __shfl_xor(v, off, 64));
  return v;
}

// ---------------------------------------------------------------------------
// dtype probe: gn_w[0] is 1.0.  f32 -> dword 0x3F800000 ; bf16 pair -> 0x3F803F80
__global__ void probe_dtype(const uint* __restrict__ gnw_raw, uint* __restrict__ flag){
  if (threadIdx.x == 0 && blockIdx.x == 0)
    *flag = (gnw_raw[0] == 0x3F800000u) ? 1u : 0u;   // 1 = f32 inputs
}

struct Seg { const void* p; uint ofs; };
struct CvtArgs { Seg s[19]; };

__global__ __launch_bounds__(256) void cvt_params(CvtArgs a, ushort* __restrict__ pb,
                                                  const uint* __restrict__ flag){
  uint gi = blockIdx.x * 256u + threadIdx.x;
  if (gi >= TOTALP) return;
  int lo = 0;
  #pragma unroll
  for (int s = 1; s < 18; ++s) if (gi >= a.s[s].ofs) lo = s;
  uint rel = gi - a.s[lo].ofs;
  pb[gi] = (*flag) ? f2bf(((const float*)a.s[lo].p)[rel]) : ((const ushort*)a.s[lo].p)[rel];
}

__global__ __launch_bounds__(256) void cvt_flat(const void* __restrict__ in, ushort* __restrict__ out,
                                                const uint* __restrict__ flag){
  uint i = blockIdx.x * 256u + threadIdx.x;
  out[i] = (*flag) ? f2bf(((const float*)in)[i]) : ((const ushort*)in)[i];
}

// ---------------------------------------------------------------------------
__global__ void deg_count(const int* __restrict__ dst, uint* __restrict__ deg){
  int e = blockIdx.x * 256 + threadIdx.x;
  atomicAdd(&deg[dst[e]], 1u);
}

// ---------------------------------------------------------------------------
// mean-aggregation: agg[n][:] = sum_{dst=n} X[src] / max(deg,1). bf16 in/out.
__global__ __launch_bounds__(256) void sage_agg(const ushort* __restrict__ X,
    const int* __restrict__ src, const int* __restrict__ dst,
    const uint* __restrict__ deg, ushort* __restrict__ agg, int D)
{
  __shared__ float acc[128 * 64];
  const int g = blockIdx.x, cc = blockIdx.y, q = blockIdx.z;
  const int tid = threadIdx.x;
  const int c = tid & 63, eo = tid >> 6;
  for (int i = tid; i < 128 * 64; i += 256) acc[i] = 0.0f;
  __syncthreads();
  const int ebase = g * EPG;
  const int nbase = g * NP_ + q * 128;
  const int ch = cc * 64 + c;
  for (int e0 = 0; e0 < EPG; e0 += 4) {
    int e = ebase + e0 + eo;
    int d = dst[e] - nbase;            // wave-uniform
    if (d >= 0 && d < 128) {
      int s = src[e];
      atomicAdd(&acc[(d << 6) + c], bf2f(X[(size_t)s * D + ch]));
    }
  }
  __syncthreads();
  for (int i = tid; i < 128 * 64; i += 256) {
    int nl = i >> 6, cl = i & 63;
    int n = nbase + nl;
    uint dg = deg[n]; if (dg < 1u) dg = 1u;
    agg[(size_t)n * D + cc * 64 + cl] = f2bf(acc[i] / (float)dg);
  }
}

// ---------------------------------------------------------------------------
// Tiled GEMM: out bf16 = A1@W1^T (+A2@W2^T) (+bias) (+addend). bf16 operands,
// fp32 acc. BM=128 BN=64 BK=16, 256 thr, 8x4 microtile.
#define LDA 132
#define LDW 68

__device__ __forceinline__ void gemm_stage(const ushort* __restrict__ A, int lda,
    const ushort* __restrict__ W, int K, int bm, int bn, int tid,
    float acc[8][4], float* As, float* Ws)
{
  const int tx = tid & 15, ty = tid >> 4;
  const int am = tid >> 1;
  const int ak = (tid & 1) * 8;
  const int wn = tid >> 2;
  const int wk = (tid & 3) * 4;
  for (int kb = 0; kb < K; kb += 16) {
    uint4 u = *(const uint4*)(A + (size_t)(bm * 128 + am) * lda + kb + ak);
    As[(ak+0)*LDA + am] = u2f_lo(u.x); As[(ak+1)*LDA + am] = u2f_hi(u.x);
    As[(ak+2)*LDA + am] = u2f_lo(u.y); As[(ak+3)*LDA + am] = u2f_hi(u.y);
    As[(ak+4)*LDA + am] = u2f_lo(u.z); As[(ak+5)*LDA + am] = u2f_hi(u.z);
    As[(ak+6)*LDA + am] = u2f_lo(u.w); As[(ak+7)*LDA + am] = u2f_hi(u.w);
    uint2 wv = *(const uint2*)(W + (size_t)(bn * 64 + wn) * K + kb + wk);
    Ws[(wk+0)*LDW + wn] = u2f_lo(wv.x); Ws[(wk+1)*LDW + wn] = u2f_hi(wv.x);
    Ws[(wk+2)*LDW + wn] = u2f_lo(wv.y); Ws[(wk+3)*LDW + wn] = u2f_hi(wv.y);
    __syncthreads();
    #pragma unroll
    for (int kk = 0; kk < 16; ++kk) {
      float a[8], wl[4];
      #pragma unroll
      for (int j = 0; j < 8; ++j) a[j] = As[kk*LDA + ty*8 + j];
      #pragma unroll
      for (int j = 0; j < 4; ++j) wl[j] = Ws[kk*LDW + tx*4 + j];
      #pragma unroll
      for (int ji = 0; ji < 8; ++ji)
        #pragma unroll
        for (int jj = 0; jj < 4; ++jj)
          acc[ji][jj] += a[ji] * wl[jj];
    }
    __syncthreads();
  }
}

template<bool DUAL>
__global__ __launch_bounds__(256) void gemm_tn(
    const ushort* __restrict__ A1, int lda1, const ushort* __restrict__ W1,
    const ushort* __restrict__ A2, int lda2, const ushort* __restrict__ W2,
    const ushort* __restrict__ bias, const ushort* addend,   // addend may alias out!
    ushort* out, int K, int ldOut)
{
  __shared__ float As[16 * LDA];
  __shared__ float Ws[16 * LDW];
  float acc[8][4];
  #pragma unroll
  for (int i = 0; i < 8; ++i)
    #pragma unroll
    for (int j = 0; j < 4; ++j) acc[i][j] = 0.0f;
  const int tid = threadIdx.x, bm = blockIdx.x, bn = blockIdx.y;
  gemm_stage(A1, lda1, W1, K, bm, bn, tid, acc, As, Ws);
  if constexpr (DUAL) gemm_stage(A2, lda2, W2, K, bm, bn, tid, acc, As, Ws);
  const int tx = tid & 15, ty = tid >> 4;
  float bv[4] = {0.f, 0.f, 0.f, 0.f};
  if (bias) {
    #pragma unroll
    for (int j = 0; j < 4; ++j) bv[j] = bf2f(bias[bn*64 + tx*4 + j]);
  }
  #pragma unroll
  for (int ji = 0; ji < 8; ++ji) {
    int m = bm*128 + ty*8 + ji;
    size_t ob = (size_t)m * ldOut + bn*64 + tx*4;
    float r0 = acc[ji][0] + bv[0], r1 = acc[ji][1] + bv[1];
    float r2 = acc[ji][2] + bv[2], r3 = acc[ji][3] + bv[3];
    if (addend) {
      uint2 ad = *(const uint2*)(addend + ob);
      r0 += u2f_lo(ad.x); r1 += u2f_hi(ad.x);
      r2 += u2f_lo(ad.y); r3 += u2f_hi(ad.y);
    }
    uint2 o; o.x = pack2(r0, r1); o.y = pack2(r2, r3);
    *(uint2*)(out + ob) = o;
  }
}

// ---------------------------------------------------------------------------
// Per-graph: in-place row L2-normalize + per-(g,c) moments for GraphNorm.
__global__ __launch_bounds__(256) void rownorm_stats(ushort* __restrict__ h,
    float* __restrict__ m1, float* __restrict__ m2)
{
  __shared__ float s1[256], s2[256];
  const int g = blockIdx.x, tid = threadIdx.x, lane = tid & 63, wave = tid >> 6;
  s1[tid] = 0.0f; s2[tid] = 0.0f;
  __syncthreads();
  for (int r = wave; r < NP_; r += 4) {
    size_t idx = ((size_t)g * NP_ + r) * C_;
    float v0 = bf2f(h[idx + lane]),       v1 = bf2f(h[idx + 64 + lane]);
    float v2 = bf2f(h[idx + 128 + lane]), v3 = bf2f(h[idx + 192 + lane]);
    float ss = v0*v0 + v1*v1 + v2*v2 + v3*v3;
    ss = wredsum(ss);
    float inv = 1.0f / fmaxf(sqrtf(ss), 1e-12f);
    v0 *= inv; v1 *= inv; v2 *= inv; v3 *= inv;
    h[idx + lane] = f2bf(v0);       h[idx + 64 + lane] = f2bf(v1);
    h[idx + 128 + lane] = f2bf(v2); h[idx + 192 + lane] = f2bf(v3);
    atomicAdd(&s1[lane], v0);        atomicAdd(&s1[lane + 64], v1);
    atomicAdd(&s1[lane + 128], v2);  atomicAdd(&s1[lane + 192], v3);
    atomicAdd(&s2[lane], v0*v0);       atomicAdd(&s2[lane + 64], v1*v1);
    atomicAdd(&s2[lane + 128], v2*v2); atomicAdd(&s2[lane + 192], v3*v3);
  }
  __syncthreads();
  m1[g*C_ + tid] = s1[tid] * (1.0f / 512.0f);
  m2[g*C_ + tid] = s2[tid] * (1.0f / 512.0f);
}

// GraphNorm + GELU + residual (res may alias out -> no restrict on those)
__global__ __launch_bounds__(256) void gn_gelu_add(const ushort* __restrict__ h,
    const ushort* res,
    const float* __restrict__ m1, const float* __restrict__ m2,
    const ushort* __restrict__ gw, const ushort* __restrict__ gb, const ushort* __restrict__ ga,
    ushort* out)
{
  size_t b4 = ((size_t)blockIdx.x * 256 + threadIdx.x) * 4;
  int c = (int)(b4 & (C_ - 1));
  int n = (int)(b4 >> 8);
  int g = n >> 9;
  uint2 hv = *(const uint2*)(h + b4);
  uint2 rv = *(const uint2*)(res + b4);
  float hh[4] = {u2f_lo(hv.x), u2f_hi(hv.x), u2f_lo(hv.y), u2f_hi(hv.y)};
  float rr[4] = {u2f_lo(rv.x), u2f_hi(rv.x), u2f_lo(rv.y), u2f_hi(rv.y)};
  float oo[4];
  #pragma unroll
  for (int j = 0; j < 4; ++j) {
    int cc = c + j;
    float a  = bf2f(ga[cc]);
    float mm = m1[g*C_ + cc];
    float q2 = m2[g*C_ + cc];
    float var = q2 - a * (2.0f - a) * mm * mm;
    float xo = hh[j] - a * mm;
    float y = bf2f(gw[cc]) * xo * rsqrtf(var + 1e-5f) + bf2f(gb[cc]);
    oo[j] = gelu_f(y) + rr[j];
  }
  uint2 ov; ov.x = pack2(oo[0], oo[1]); ov.y = pack2(oo[2], oo[3]);
  *(uint2*)(out + b4) = ov;
}

// ---------------------------------------------------------------------------
// Attention: one block per (graph, head). o written into dead K columns.
__global__ __launch_bounds__(256) void attn_kernel(ushort* __restrict__ qkv)
{
  __shared__ ushort Kt[64 * 512];
  __shared__ ushort Vs[512 * 64];
  __shared__ float  ps[4 * 512];
  const int bid = blockIdx.x;
  const int g = bid >> 2, h = bid & 3;
  const int tid = threadIdx.x, lane = tid & 63, wave = tid >> 6;
  const size_t base = (size_t)g * NP_ * C3_;
  const int qoff = h * 64, koff = C_ + h * 64, voff = 2 * C_ + h * 64;
  for (int idx = tid; idx < NP_ * 64; idx += 256) {
    int j = idx >> 6, c = idx & 63;
    const ushort* row = qkv + base + (size_t)j * C3_;
    Kt[(c << 9) + j] = row[koff + c];
    Vs[idx]          = row[voff + c];
  }
  __syncthreads();
  const int pw = wave << 9;
  for (int r = wave; r < NP_; r += 4) {
    float qv = bf2f(qkv[base + (size_t)r * C3_ + qoff + lane]);
    float s[8];
    #pragma unroll
    for (int i = 0; i < 8; ++i) s[i] = 0.0f;
    for (int c = 0; c < 64; ++c) {
      float qc = __shfl(qv, c, 64);
      const ushort* kp = Kt + (c << 9) + lane;
      #pragma unroll
      for (int i = 0; i < 8; ++i) s[i] += qc * bf2f(kp[i * 64]);
    }
    float mx = -1e30f;
    #pragma unroll
    for (int i = 0; i < 8; ++i) { s[i] *= 0.125f; mx = fmaxf(mx, s[i]); }
    mx = wredmax(mx);
    float e[8]; float sum = 0.0f;
    #pragma unroll
    for (int i = 0; i < 8; ++i) { e[i] = expf(s[i] - mx); sum += e[i]; }
    sum = wredsum(sum);
    float inv = 1.0f / sum;
    #pragma unroll
    for (int i = 0; i < 8; ++i) ps[pw + i*64 + lane] = e[i] * inv;
    __threadfence_block();
    float o0 = 0, o1 = 0, o2 = 0, o3 = 0;
    for (int j = 0; j < NP_; j += 4) {
      o0 += ps[pw + j    ] * bf2f(Vs[(j    ) * 64 + lane]);
      o1 += ps[pw + j + 1] * bf2f(Vs[(j + 1) * 64 + lane]);
      o2 += ps[pw + j + 2] * bf2f(Vs[(j + 2) * 64 + lane]);
      o3 += ps[pw + j + 3] * bf2f(Vs[(j + 3) * 64 + lane]);
    }
    qkv[base + (size_t)r * C3_ + koff + lane] = f2bf((o0 + o1) + (o2 + o3));
  }
}

// ---------------------------------------------------------------------------
__global__ __launch_bounds__(256) void ln_stats(const ushort* __restrict__ x2, float* __restrict__ st)
{
  __shared__ float a1[4], a2[4];
  const int g = blockIdx.x, tid = threadIdx.x, lane = tid & 63, wave = tid >> 6;
  const ushort* p = x2 + (size_t)g * NP_ * C_;
  float s = 0.0f, q = 0.0f;
  for (int i = tid; i < NP_ * C_; i += 256) { float v = bf2f(p[i]); s += v; q += v * v; }
  s = wredsum(s); q = wredsum(q);
  if (lane == 0) { a1[wave] = s; a2[wave] = q; }
  __syncthreads();
  if (tid == 0) {
    float S = a1[0] + a1[1] + a1[2] + a1[3];
    float Q = a2[0] + a2[1] + a2[2] + a2[3];
    float mu = S * (1.0f / (NP_ * C_));
    float var = Q * (1.0f / (NP_ * C_)) - mu * mu;
    st[g * 2] = mu; st[g * 2 + 1] = var;
  }
}

__global__ __launch_bounds__(256) void ln_gelu(const ushort* __restrict__ x2, const float* __restrict__ st,
    const ushort* __restrict__ lw, const ushort* __restrict__ lb, ushort* __restrict__ x3)
{
  size_t b4 = ((size_t)blockIdx.x * 256 + threadIdx.x) * 4;
  int c = (int)(b4 & (C_ - 1));
  int n = (int)(b4 >> 8);
  int g = n >> 9;
  float mu = st[g * 2], var = st[g * 2 + 1];
  float rs = rsqrtf(var + 1e-5f);
  uint2 v = *(const uint2*)(x2 + b4);
  float vv[4] = {u2f_lo(v.x), u2f_hi(v.x), u2f_lo(v.y), u2f_hi(v.y)};
  float oo[4];
  #pragma unroll
  for (int j = 0; j < 4; ++j) {
    int cc = c + j;
    float y = (vv[j] - mu) * rs * bf2f(lw[cc]) + bf2f(lb[cc]);
    oo[j] = gelu_f(y);
  }
  uint2 ov; ov.x = pack2(oo[0], oo[1]); ov.y = pack2(oo[2], oo[3]);
  *(uint2*)(x3 + b4) = ov;
}

__global__ __launch_bounds__(256) void pool_kernel(const ushort* __restrict__ x3, float* __restrict__ pooled)
{
  const int g = blockIdx.x, c = threadIdx.x;
  float s = 0.0f, mx = -3.0e38f;
  for (int r = 0; r < NP_; ++r) {
    float v = bf2f(x3[((size_t)g * NP_ + r) * C_ + c]);
    s += v; mx = fmaxf(mx, v);
  }
  pooled[(size_t)g * C3_ + c]        = s * (1.0f / 512.0f);
  pooled[(size_t)g * C3_ + C_ + c]   = mx;
  pooled[(size_t)g * C3_ + 2*C_ + c] = s;
}

__global__ __launch_bounds__(256) void final_gemm(const float* __restrict__ pooled,
    const ushort* __restrict__ W, const ushort* __restrict__ b, void* __restrict__ out,
    const uint* __restrict__ flag)
{
  const int g = blockIdx.x, c = threadIdx.x;
  float acc = bf2f(b[c]);
  const float* p = pooled + (size_t)g * C3_;
  for (int k = 0; k < C3_; ++k) acc += p[k] * bf2f(W[(size_t)c * C3_ + k]);
  if (*flag) ((float*)out)[g * C_ + c] = acc;
  else       ((ushort*)out)[g * C_ + c] = f2bf(acc);
}

// ---------------------------------------------------------------------------
extern "C" void kernel_launch(void* const* d_in, const int* in_sizes, int n_in,
                              void* d_out, int out_size, void* d_ws, size_t ws_size,
                              hipStream_t stream)
{
  const int* ei   = (const int*)d_in[1];
  const int* srcp = ei;
  const int* dstp = ei + E_TOT;

  const size_t NC = (size_t)N_TOT * C_;                        // 16,777,216
  const size_t NEEDED = (4ull << 20) + 4 * NC * sizeof(ushort); // 132 MB
  if (ws_size < NEEDED) return;

  unsigned char* wsb = (unsigned char*)d_ws;
  uint*   deg    = (uint*)wsb;
  float*  m1     = (float*)(wsb + (256u << 10));
  float*  m2     = (float*)(wsb + (384u << 10));
  float*  lst    = (float*)(wsb + (512u << 10));
  uint*   flag   = (uint*)(wsb + (516u << 10));
  float*  pooled = (float*)(wsb + (520u << 10));
  ushort* PB     = (ushort*)(wsb + (1u << 20));       // param pool bf16
  ushort* S0     = (ushort*)(wsb + (4u << 20));       // x1
  ushort* S1     = S0 + NC;
  ushort* S2     = S1 + NC;
  ushort* S3     = S2 + NC;
  ushort* qkvb   = S1;                                // [N][768] overlay
  ushort* XB     = S3;                                // x bf16 overlay (dead by attn)

  // ---- dtype probe + import ----
  probe_dtype<<<1, 1, 0, stream>>>((const uint*)d_in[10], flag);
  CvtArgs ca;
  ca.s[0]  = { d_in[3],  O_L0LW };  ca.s[1]  = { d_in[4],  O_L0LB };
  ca.s[2]  = { d_in[5],  O_L0RW };  ca.s[3]  = { d_in[6],  O_L0RES };
  ca.s[4]  = { d_in[7],  O_LWL  };  ca.s[5]  = { d_in[8],  O_LBL  };
  ca.s[6]  = { d_in[9],  O_LWR  };  ca.s[7]  = { d_in[10], O_GNW  };
  ca.s[8]  = { d_in[11], O_GNB  };  ca.s[9]  = { d_in[12], O_GNA  };
  ca.s[10] = { d_in[13], O_AIW  };  ca.s[11] = { d_in[14], O_AIB  };
  ca.s[12] = { d_in[15], O_AOW  };  ca.s[13] = { d_in[16], O_AOB  };
  ca.s[14] = { d_in[17], O_LNW  };  ca.s[15] = { d_in[18], O_LNB  };
  ca.s[16] = { d_in[19], O_PLW  };  ca.s[17] = { d_in[20], O_PLB  };
  ca.s[18] = { nullptr,  TOTALP };
  cvt_params<<<(TOTALP + 255) / 256, 256, 0, stream>>>(ca, PB, flag);
  cvt_flat<<<(N_TOT * DIN_) / 256, 256, 0, stream>>>(d_in[0], XB, flag);

  hipMemsetAsync(deg, 0, N_TOT * sizeof(uint), stream);
  deg_count<<<E_TOT / 256, 256, 0, stream>>>(dstp, deg);

  // ---- layer 0 (DIN=128 -> C=256) ----
  sage_agg<<<dim3(B_GR, DIN_ / 64, 4), 256, 0, stream>>>(XB, srcp, dstp, deg, S1, DIN_);
  gemm_tn<true><<<dim3(N_TOT / 128, C_ / 64), 256, 0, stream>>>(
      S1, DIN_, PB + O_L0LW, XB, DIN_, PB + O_L0RW, PB + O_L0LB, nullptr, S2, DIN_, C_);
  gemm_tn<false><<<dim3(N_TOT / 128, C_ / 64), 256, 0, stream>>>(
      XB, DIN_, PB + O_L0RES, nullptr, 0, nullptr, nullptr, nullptr, S0, DIN_, C_);
  rownorm_stats<<<B_GR, 256, 0, stream>>>(S2, m1, m2);
  gn_gelu_add<<<(N_TOT * C_) / 1024, 256, 0, stream>>>(S2, S0, m1, m2,
      PB + O_GNW, PB + O_GNB, PB + O_GNA, S0);

  // ---- layers 1..3 (C -> C) ----
  for (int i = 0; i < 3; ++i) {
    sage_agg<<<dim3(B_GR, C_ / 64, 4), 256, 0, stream>>>(S0, srcp, dstp, deg, S1, C_);
    gemm_tn<true><<<dim3(N_TOT / 128, C_ / 64), 256, 0, stream>>>(
        S1, C_, PB + O_LWL + (size_t)i * C_ * C_, S0, C_, PB + O_LWR + (size_t)i * C_ * C_,
        PB + O_LBL + i * C_, nullptr, S2, C_, C_);
    rownorm_stats<<<B_GR, 256, 0, stream>>>(S2, m1, m2);
    gn_gelu_add<<<(N_TOT * C_) / 1024, 256, 0, stream>>>(S2, S0, m1, m2,
        PB + O_GNW + (i + 1) * C_, PB + O_GNB + (i + 1) * C_, PB + O_GNA + (i + 1) * C_, S0);
  }

  // ---- attention ----
  gemm_tn<false><<<dim3(N_TOT / 128, C3_ / 64), 256, 0, stream>>>(
      S0, C_, PB + O_AIW, nullptr, 0, nullptr, PB + O_AIB, nullptr, qkvb, C_, C3_);
  attn_kernel<<<B_GR * H_, 256, 0, stream>>>(qkvb);
  gemm_tn<false><<<dim3(N_TOT / 128, C_ / 64), 256, 0, stream>>>(
      qkvb + C_, C3_, PB + O_AOW, nullptr, 0, nullptr, PB + O_AOB, S0, S0, C_, C_);

  // ---- graph LayerNorm + gelu ----
  ln_stats<<<B_GR, 256, 0, stream>>>(S0, lst);
  ln_gelu<<<(N_TOT * C_) / 1024, 256, 0, stream>>>(S0, lst, PB + O_LNW, PB + O_LNB, S1);

  // ---- pool + projection ----
  pool_kernel<<<B_GR, 256, 0, stream>>>(S1, pooled);
  final_gemm<<<B_GR, 256, 0, stream>>>(pooled, PB + O_PLW, PB + O_PLB, d_out, flag);
}

// Round 4
// 7403.535 us; speedup vs baseline: 1.1133x; 1.1133x over previous
//
#include <hip/hip_runtime.h>

// ---------------------------------------------------------------------------
// GraphSAGE GNN forward, MI355X round 4: MFMA bf16 GEMMs + attn occupancy fix.
// Pipeline identical to round 3 (passed, absmax 4.0).
// ---------------------------------------------------------------------------

#define N_TOT   65536
#define B_GR    128
#define NP_     512
#define E_TOT   524288
#define EPG     4096
#define DIN_    128
#define C_      256
#define C3_     768
#define H_      4

typedef unsigned int uint;
typedef unsigned short ushort;

// param pool element offsets (ushorts)
#define O_L0LW  0u
#define O_L0LB  32768u
#define O_L0RW  33024u
#define O_L0RES 65792u
#define O_LWL   98560u
#define O_LBL   295168u
#define O_LWR   295936u
#define O_GNW   492544u
#define O_GNB   493568u
#define O_GNA   494592u
#define O_AIW   495616u
#define O_AIB   692224u
#define O_AOW   692992u
#define O_AOB   758528u
#define O_LNW   758784u
#define O_LNB   759040u
#define O_PLW   759296u
#define O_PLB   955904u
#define TOTALP  956160u

typedef __attribute__((ext_vector_type(8))) short bf16x8_t;
typedef __attribute__((ext_vector_type(4))) float f32x4_t;

__device__ __forceinline__ float bf2f(ushort u){ union{uint i; float f;} v; v.i = ((uint)u) << 16; return v.f; }
__device__ __forceinline__ ushort f2bf(float f){
  union{float f; uint u;} v; v.f = f;
  uint u = v.u;
  u += 0x7fffu + ((u >> 16) & 1u);   // RNE
  return (ushort)(u >> 16);
}
__device__ __forceinline__ uint pack2(float a, float b){ return (uint)f2bf(a) | ((uint)f2bf(b) << 16); }
__device__ __forceinline__ float u2f_lo(uint u){ union{uint i; float f;} v; v.i = u << 16; return v.f; }
__device__ __forceinline__ float u2f_hi(uint u){ union{uint i; float f;} v; v.i = u & 0xffff0000u; return v.f; }
__device__ __forceinline__ float gelu_f(float x){ return 0.5f * x * (1.0f + erff(x * 0.70710678118654752440f)); }
__device__ __forceinline__ float wredsum(float v){
  #pragma unroll
  for (int off = 32; off; off >>= 1) v += __shfl_xor(v, off, 64);
  return v;
}
__device__ __forceinline__ float wredmax(float v){
  #pragma unroll
  for (int off = 32; off; off >>= 1) v = fmaxf(v, __shfl_xor(v, off, 64));
  return v;
}

// ---------------------------------------------------------------------------
// dtype probe: gn_w[0]==1.0. f32 -> 0x3F800000 ; bf16 pair -> 0x3F803F80
__global__ void probe_dtype(const uint* __restrict__ gnw_raw, uint* __restrict__ flag){
  if (threadIdx.x == 0 && blockIdx.x == 0)
    *flag = (gnw_raw[0] == 0x3F800000u) ? 1u : 0u;   // 1 = f32 inputs
}

struct Seg { const void* p; uint ofs; };
struct CvtArgs { Seg s[19]; };

__global__ __launch_bounds__(256) void cvt_params(CvtArgs a, ushort* __restrict__ pb,
                                                  const uint* __restrict__ flag){
  uint gi = blockIdx.x * 256u + threadIdx.x;
  if (gi >= TOTALP) return;
  int lo = 0;
  #pragma unroll
  for (int s = 1; s < 18; ++s) if (gi >= a.s[s].ofs) lo = s;
  uint rel = gi - a.s[lo].ofs;
  pb[gi] = (*flag) ? f2bf(((const float*)a.s[lo].p)[rel]) : ((const ushort*)a.s[lo].p)[rel];
}

__global__ __launch_bounds__(256) void cvt_flat(const void* __restrict__ in, ushort* __restrict__ out,
                                                const uint* __restrict__ flag){
  uint i = blockIdx.x * 256u + threadIdx.x;
  out[i] = (*flag) ? f2bf(((const float*)in)[i]) : ((const ushort*)in)[i];
}

// ---------------------------------------------------------------------------
__global__ void deg_count(const int* __restrict__ dst, uint* __restrict__ deg){
  int e = blockIdx.x * 256 + threadIdx.x;
  atomicAdd(&deg[dst[e]], 1u);
}

// ---------------------------------------------------------------------------
// mean-aggregation: agg[n][:] = sum_{dst=n} X[src] / max(deg,1). bf16 in/out.
__global__ __launch_bounds__(256) void sage_agg(const ushort* __restrict__ X,
    const int* __restrict__ src, const int* __restrict__ dst,
    const uint* __restrict__ deg, ushort* __restrict__ agg, int D)
{
  __shared__ float acc[128 * 64];
  const int g = blockIdx.x, cc = blockIdx.y, q = blockIdx.z;
  const int tid = threadIdx.x;
  const int c = tid & 63, eo = tid >> 6;
  for (int i = tid; i < 128 * 64; i += 256) acc[i] = 0.0f;
  __syncthreads();
  const int ebase = g * EPG;
  const int nbase = g * NP_ + q * 128;
  const int ch = cc * 64 + c;
  for (int e0 = 0; e0 < EPG; e0 += 4) {
    int e = ebase + e0 + eo;
    int d = dst[e] - nbase;            // wave-uniform
    if (d >= 0 && d < 128) {
      int s = src[e];
      atomicAdd(&acc[(d << 6) + c], bf2f(X[(size_t)s * D + ch]));
    }
  }
  __syncthreads();
  for (int i = tid; i < 128 * 64; i += 256) {
    int nl = i >> 6, cl = i & 63;
    int n = nbase + nl;
    uint dg = deg[n]; if (dg < 1u) dg = 1u;
    agg[(size_t)n * D + cc * 64 + cl] = f2bf(acc[i] / (float)dg);
  }
}

// ---------------------------------------------------------------------------
// MFMA GEMM: out[M x Cout] bf16 = A1@W1^T (+A2@W2^T) (+bias) (+addend).
// A row-major [M][lda] bf16, W row-major [Cout][K] bf16. 64x64 block tile,
// 4 waves (16 rows each) x 4 col-subtiles, 16x16x32 MFMA, fp32 acc, no LDS.
// A-frag: lane holds A[m0+(lane&15)][kb+(lane>>4)*8 .. +8] (contiguous 16B).
// B-frag: lane holds W[n0+(lane&15)][kb+(lane>>4)*8 .. +8].
// C/D:    col = lane&15, row = (lane>>4)*4 + reg.
template<bool DUAL>
__global__ __launch_bounds__(256) void gemm_mfma(
    const ushort* __restrict__ A1, int lda1, const ushort* __restrict__ W1,
    const ushort* __restrict__ A2, int lda2, const ushort* __restrict__ W2,
    const ushort* __restrict__ bias, const ushort* addend,   // addend may alias out
    ushort* out, int K, int ldOut)
{
  const int lane = threadIdx.x & 63, wave = threadIdx.x >> 6;
  const int lr = lane & 15;
  const int lk = (lane >> 4) << 3;
  const int m0 = blockIdx.x * 64 + wave * 16;
  const int n0 = blockIdx.y * 64;
  f32x4_t acc[4];
  #pragma unroll
  for (int t = 0; t < 4; ++t) acc[t] = (f32x4_t){0.f, 0.f, 0.f, 0.f};
  {
    const ushort* ap = A1 + (size_t)(m0 + lr) * lda1 + lk;
    const ushort* wp = W1 + (size_t)(n0 + lr) * K + lk;
    for (int kb = 0; kb < K; kb += 32) {
      bf16x8_t a = *(const bf16x8_t*)(ap + kb);
      #pragma unroll
      for (int t = 0; t < 4; ++t) {
        bf16x8_t b = *(const bf16x8_t*)(wp + (size_t)(t * 16) * K + kb);
        acc[t] = __builtin_amdgcn_mfma_f32_16x16x32_bf16(a, b, acc[t], 0, 0, 0);
      }
    }
  }
  if constexpr (DUAL) {
    const ushort* ap = A2 + (size_t)(m0 + lr) * lda2 + lk;
    const ushort* wp = W2 + (size_t)(n0 + lr) * K + lk;
    for (int kb = 0; kb < K; kb += 32) {
      bf16x8_t a = *(const bf16x8_t*)(ap + kb);
      #pragma unroll
      for (int t = 0; t < 4; ++t) {
        bf16x8_t b = *(const bf16x8_t*)(wp + (size_t)(t * 16) * K + kb);
        acc[t] = __builtin_amdgcn_mfma_f32_16x16x32_bf16(a, b, acc[t], 0, 0, 0);
      }
    }
  }
  const int rbase = (lane >> 4) << 2;
  #pragma unroll
  for (int t = 0; t < 4; ++t) {
    const int col = n0 + t * 16 + lr;
    float bv = bias ? bf2f(bias[col]) : 0.0f;
    #pragma unroll
    for (int r = 0; r < 4; ++r) {
      int row = m0 + rbase + r;
      size_t ob = (size_t)row * ldOut + col;
      float v = acc[t][r] + bv;
      if (addend) v += bf2f(addend[ob]);
      out[ob] = f2bf(v);
    }
  }
}

// ---------------------------------------------------------------------------
// Per-graph: in-place row L2-normalize + per-(g,c) moments for GraphNorm.
__global__ __launch_bounds__(256) void rownorm_stats(ushort* __restrict__ h,
    float* __restrict__ m1, float* __restrict__ m2)
{
  __shared__ float s1[256], s2[256];
  const int g = blockIdx.x, tid = threadIdx.x, lane = tid & 63, wave = tid >> 6;
  s1[tid] = 0.0f; s2[tid] = 0.0f;
  __syncthreads();
  for (int r = wave; r < NP_; r += 4) {
    size_t idx = ((size_t)g * NP_ + r) * C_;
    float v0 = bf2f(h[idx + lane]),       v1 = bf2f(h[idx + 64 + lane]);
    float v2 = bf2f(h[idx + 128 + lane]), v3 = bf2f(h[idx + 192 + lane]);
    float ss = v0*v0 + v1*v1 + v2*v2 + v3*v3;
    ss = wredsum(ss);
    float inv = 1.0f / fmaxf(sqrtf(ss), 1e-12f);
    v0 *= inv; v1 *= inv; v2 *= inv; v3 *= inv;
    h[idx + lane] = f2bf(v0);       h[idx + 64 + lane] = f2bf(v1);
    h[idx + 128 + lane] = f2bf(v2); h[idx + 192 + lane] = f2bf(v3);
    atomicAdd(&s1[lane], v0);        atomicAdd(&s1[lane + 64], v1);
    atomicAdd(&s1[lane + 128], v2);  atomicAdd(&s1[lane + 192], v3);
    atomicAdd(&s2[lane], v0*v0);       atomicAdd(&s2[lane + 64], v1*v1);
    atomicAdd(&s2[lane + 128], v2*v2); atomicAdd(&s2[lane + 192], v3*v3);
  }
  __syncthreads();
  m1[g*C_ + tid] = s1[tid] * (1.0f / 512.0f);
  m2[g*C_ + tid] = s2[tid] * (1.0f / 512.0f);
}

// GraphNorm + GELU + residual (res may alias out)
__global__ __launch_bounds__(256) void gn_gelu_add(const ushort* __restrict__ h,
    const ushort* res,
    const float* __restrict__ m1, const float* __restrict__ m2,
    const ushort* __restrict__ gw, const ushort* __restrict__ gb, const ushort* __restrict__ ga,
    ushort* out)
{
  size_t b4 = ((size_t)blockIdx.x * 256 + threadIdx.x) * 4;
  int c = (int)(b4 & (C_ - 1));
  int n = (int)(b4 >> 8);
  int g = n >> 9;
  uint2 hv = *(const uint2*)(h + b4);
  uint2 rv = *(const uint2*)(res + b4);
  float hh[4] = {u2f_lo(hv.x), u2f_hi(hv.x), u2f_lo(hv.y), u2f_hi(hv.y)};
  float rr[4] = {u2f_lo(rv.x), u2f_hi(rv.x), u2f_lo(rv.y), u2f_hi(rv.y)};
  float oo[4];
  #pragma unroll
  for (int j = 0; j < 4; ++j) {
    int cc = c + j;
    float a  = bf2f(ga[cc]);
    float mm = m1[g*C_ + cc];
    float q2 = m2[g*C_ + cc];
    float var = q2 - a * (2.0f - a) * mm * mm;
    float xo = hh[j] - a * mm;
    float y = bf2f(gw[cc]) * xo * rsqrtf(var + 1e-5f) + bf2f(gb[cc]);
    oo[j] = gelu_f(y) + rr[j];
  }
  uint2 ov; ov.x = pack2(oo[0], oo[1]); ov.y = pack2(oo[2], oo[3]);
  *(uint2*)(out + b4) = ov;
}

// ---------------------------------------------------------------------------
// Attention: one block (512 thr = 8 waves) per (graph, head). K ch-major with
// pitch 514 (conflict-free staging), V row-major. o -> dead K columns.
#define KT_P 514
__global__ __launch_bounds__(512) void attn_kernel(ushort* __restrict__ qkv)
{
  __shared__ ushort Kt[64 * KT_P];  // Kt[c][j], pitch 514
  __shared__ ushort Vs[512 * 64];   // V[j][c]
  __shared__ float  ps[8 * 512];    // per-wave p row
  const int bid = blockIdx.x;
  const int g = bid >> 2, h = bid & 3;
  const int tid = threadIdx.x, lane = tid & 63, wave = tid >> 6;
  const size_t base = (size_t)g * NP_ * C3_;
  const int qoff = h * 64, koff = C_ + h * 64, voff = 2 * C_ + h * 64;
  for (int idx = tid; idx < NP_ * 64; idx += 512) {
    int j = idx >> 6, c = idx & 63;
    const ushort* row = qkv + base + (size_t)j * C3_;
    Kt[c * KT_P + j] = row[koff + c];
    Vs[idx]          = row[voff + c];
  }
  __syncthreads();
  const int pw = wave << 9;
  for (int r = wave; r < NP_; r += 8) {
    float qv = bf2f(qkv[base + (size_t)r * C3_ + qoff + lane]);
    float s[8];
    #pragma unroll
    for (int i = 0; i < 8; ++i) s[i] = 0.0f;
    for (int c = 0; c < 64; ++c) {
      float qc = __shfl(qv, c, 64);
      const ushort* kp = Kt + c * KT_P + lane;
      #pragma unroll
      for (int i = 0; i < 8; ++i) s[i] += qc * bf2f(kp[i * 64]);
    }
    float mx = -1e30f;
    #pragma unroll
    for (int i = 0; i < 8; ++i) { s[i] *= 0.125f; mx = fmaxf(mx, s[i]); }
    mx = wredmax(mx);
    float e[8]; float sum = 0.0f;
    #pragma unroll
    for (int i = 0; i < 8; ++i) { e[i] = expf(s[i] - mx); sum += e[i]; }
    sum = wredsum(sum);
    float inv = 1.0f / sum;
    #pragma unroll
    for (int i = 0; i < 8; ++i) ps[pw + i*64 + lane] = e[i] * inv;
    __threadfence_block();
    float o0 = 0, o1 = 0, o2 = 0, o3 = 0;
    for (int j = 0; j < NP_; j += 4) {
      o0 += ps[pw + j    ] * bf2f(Vs[(j    ) * 64 + lane]);
      o1 += ps[pw + j + 1] * bf2f(Vs[(j + 1) * 64 + lane]);
      o2 += ps[pw + j + 2] * bf2f(Vs[(j + 2) * 64 + lane]);
      o3 += ps[pw + j + 3] * bf2f(Vs[(j + 3) * 64 + lane]);
    }
    qkv[base + (size_t)r * C3_ + koff + lane] = f2bf((o0 + o1) + (o2 + o3));
  }
}

// ---------------------------------------------------------------------------
__global__ __launch_bounds__(256) void ln_stats(const ushort* __restrict__ x2, float* __restrict__ st)
{
  __shared__ float a1[4], a2[4];
  const int g = blockIdx.x, tid = threadIdx.x, lane = tid & 63, wave = tid >> 6;
  const ushort* p = x2 + (size_t)g * NP_ * C_;
  float s = 0.0f, q = 0.0f;
  for (int i = tid; i < NP_ * C_; i += 256) { float v = bf2f(p[i]); s += v; q += v * v; }
  s = wredsum(s); q = wredsum(q);
  if (lane == 0) { a1[wave] = s; a2[wave] = q; }
  __syncthreads();
  if (tid == 0) {
    float S = a1[0] + a1[1] + a1[2] + a1[3];
    float Q = a2[0] + a2[1] + a2[2] + a2[3];
    float mu = S * (1.0f / (NP_ * C_));
    float var = Q * (1.0f / (NP_ * C_)) - mu * mu;
    st[g * 2] = mu; st[g * 2 + 1] = var;
  }
}

__global__ __launch_bounds__(256) void ln_gelu(const ushort* __restrict__ x2, const float* __restrict__ st,
    const ushort* __restrict__ lw, const ushort* __restrict__ lb, ushort* __restrict__ x3)
{
  size_t b4 = ((size_t)blockIdx.x * 256 + threadIdx.x) * 4;
  int c = (int)(b4 & (C_ - 1));
  int n = (int)(b4 >> 8);
  int g = n >> 9;
  float mu = st[g * 2], var = st[g * 2 + 1];
  float rs = rsqrtf(var + 1e-5f);
  uint2 v = *(const uint2*)(x2 + b4);
  float vv[4] = {u2f_lo(v.x), u2f_hi(v.x), u2f_lo(v.y), u2f_hi(v.y)};
  float oo[4];
  #pragma unroll
  for (int j = 0; j < 4; ++j) {
    int cc = c + j;
    float y = (vv[j] - mu) * rs * bf2f(lw[cc]) + bf2f(lb[cc]);
    oo[j] = gelu_f(y);
  }
  uint2 ov; ov.x = pack2(oo[0], oo[1]); ov.y = pack2(oo[2], oo[3]);
  *(uint2*)(x3 + b4) = ov;
}

__global__ __launch_bounds__(256) void pool_kernel(const ushort* __restrict__ x3, float* __restrict__ pooled)
{
  const int g = blockIdx.x, c = threadIdx.x;
  float s = 0.0f, mx = -3.0e38f;
  for (int r = 0; r < NP_; ++r) {
    float v = bf2f(x3[((size_t)g * NP_ + r) * C_ + c]);
    s += v; mx = fmaxf(mx, v);
  }
  pooled[(size_t)g * C3_ + c]        = s * (1.0f / 512.0f);
  pooled[(size_t)g * C3_ + C_ + c]   = mx;
  pooled[(size_t)g * C3_ + 2*C_ + c] = s;
}

__global__ __launch_bounds__(256) void final_gemm(const float* __restrict__ pooled,
    const ushort* __restrict__ W, const ushort* __restrict__ b, void* __restrict__ out,
    const uint* __restrict__ flag)
{
  const int g = blockIdx.x, c = threadIdx.x;
  float acc = bf2f(b[c]);
  const float* p = pooled + (size_t)g * C3_;
  for (int k = 0; k < C3_; ++k) acc += p[k] * bf2f(W[(size_t)c * C3_ + k]);
  if (*flag) ((float*)out)[g * C_ + c] = acc;
  else       ((ushort*)out)[g * C_ + c] = f2bf(acc);
}

// ---------------------------------------------------------------------------
extern "C" void kernel_launch(void* const* d_in, const int* in_sizes, int n_in,
                              void* d_out, int out_size, void* d_ws, size_t ws_size,
                              hipStream_t stream)
{
  const int* ei   = (const int*)d_in[1];
  const int* srcp = ei;
  const int* dstp = ei + E_TOT;

  const size_t NC = (size_t)N_TOT * C_;                        // 16,777,216
  const size_t NEEDED = (4ull << 20) + 4 * NC * sizeof(ushort); // 132 MB
  if (ws_size < NEEDED) return;

  unsigned char* wsb = (unsigned char*)d_ws;
  uint*   deg    = (uint*)wsb;
  float*  m1     = (float*)(wsb + (256u << 10));
  float*  m2     = (float*)(wsb + (384u << 10));
  float*  lst    = (float*)(wsb + (512u << 10));
  uint*   flag   = (uint*)(wsb + (516u << 10));
  float*  pooled = (float*)(wsb + (520u << 10));
  ushort* PB     = (ushort*)(wsb + (1u << 20));       // param pool bf16
  ushort* S0     = (ushort*)(wsb + (4u << 20));       // x1
  ushort* S1     = S0 + NC;
  ushort* S2     = S1 + NC;
  ushort* S3     = S2 + NC;
  ushort* qkvb   = S1;                                // [N][768] overlay
  ushort* XB     = S3;                                // x bf16 overlay (dead by attn)

  // ---- dtype probe + import ----
  probe_dtype<<<1, 1, 0, stream>>>((const uint*)d_in[10], flag);
  CvtArgs ca;
  ca.s[0]  = { d_in[3],  O_L0LW };  ca.s[1]  = { d_in[4],  O_L0LB };
  ca.s[2]  = { d_in[5],  O_L0RW };  ca.s[3]  = { d_in[6],  O_L0RES };
  ca.s[4]  = { d_in[7],  O_LWL  };  ca.s[5]  = { d_in[8],  O_LBL  };
  ca.s[6]  = { d_in[9],  O_LWR  };  ca.s[7]  = { d_in[10], O_GNW  };
  ca.s[8]  = { d_in[11], O_GNB  };  ca.s[9]  = { d_in[12], O_GNA  };
  ca.s[10] = { d_in[13], O_AIW  };  ca.s[11] = { d_in[14], O_AIB  };
  ca.s[12] = { d_in[15], O_AOW  };  ca.s[13] = { d_in[16], O_AOB  };
  ca.s[14] = { d_in[17], O_LNW  };  ca.s[15] = { d_in[18], O_LNB  };
  ca.s[16] = { d_in[19], O_PLW  };  ca.s[17] = { d_in[20], O_PLB  };
  ca.s[18] = { nullptr,  TOTALP };
  cvt_params<<<(TOTALP + 255) / 256, 256, 0, stream>>>(ca, PB, flag);
  cvt_flat<<<(N_TOT * DIN_) / 256, 256, 0, stream>>>(d_in[0], XB, flag);

  hipMemsetAsync(deg, 0, N_TOT * sizeof(uint), stream);
  deg_count<<<E_TOT / 256, 256, 0, stream>>>(dstp, deg);

  // ---- layer 0 (DIN=128 -> C=256) ----
  sage_agg<<<dim3(B_GR, DIN_ / 64, 4), 256, 0, stream>>>(XB, srcp, dstp, deg, S1, DIN_);
  gemm_mfma<true><<<dim3(N_TOT / 64, C_ / 64), 256, 0, stream>>>(
      S1, DIN_, PB + O_L0LW, XB, DIN_, PB + O_L0RW, PB + O_L0LB, nullptr, S2, DIN_, C_);
  gemm_mfma<false><<<dim3(N_TOT / 64, C_ / 64), 256, 0, stream>>>(
      XB, DIN_, PB + O_L0RES, nullptr, 0, nullptr, nullptr, nullptr, S0, DIN_, C_);
  rownorm_stats<<<B_GR, 256, 0, stream>>>(S2, m1, m2);
  gn_gelu_add<<<(N_TOT * C_) / 1024, 256, 0, stream>>>(S2, S0, m1, m2,
      PB + O_GNW, PB + O_GNB, PB + O_GNA, S0);

  // ---- layers 1..3 (C -> C) ----
  for (int i = 0; i < 3; ++i) {
    sage_agg<<<dim3(B_GR, C_ / 64, 4), 256, 0, stream>>>(S0, srcp, dstp, deg, S1, C_);
    gemm_mfma<true><<<dim3(N_TOT / 64, C_ / 64), 256, 0, stream>>>(
        S1, C_, PB + O_LWL + (size_t)i * C_ * C_, S0, C_, PB + O_LWR + (size_t)i * C_ * C_,
        PB + O_LBL + i * C_, nullptr, S2, C_, C_);
    rownorm_stats<<<B_GR, 256, 0, stream>>>(S2, m1, m2);
    gn_gelu_add<<<(N_TOT * C_) / 1024, 256, 0, stream>>>(S2, S0, m1, m2,
        PB + O_GNW + (i + 1) * C_, PB + O_GNB + (i + 1) * C_, PB + O_GNA + (i + 1) * C_, S0);
  }

  // ---- attention ----
  gemm_mfma<false><<<dim3(N_TOT / 64, C3_ / 64), 256, 0, stream>>>(
      S0, C_, PB + O_AIW, nullptr, 0, nullptr, PB + O_AIB, nullptr, qkvb, C_, C3_);
  attn_kernel<<<B_GR * H_, 512, 0, stream>>>(qkvb);
  gemm_mfma<false><<<dim3(N_TOT / 64, C_ / 64), 256, 0, stream>>>(
      qkvb + C_, C3_, PB + O_AOW, nullptr, 0, nullptr, PB + O_AOB, S0, S0, C_, C_);

  // ---- graph LayerNorm + gelu ----
  ln_stats<<<B_GR, 256, 0, stream>>>(S0, lst);
  ln_gelu<<<(N_TOT * C_) / 1024, 256, 0, stream>>>(S0, lst, PB + O_LNW, PB + O_LNB, S1);

  // ---- pool + projection ----
  pool_kernel<<<B_GR, 256, 0, stream>>>(S1, pooled);
  final_gemm<<<B_GR, 256, 0, stream>>>(pooled, PB + O_PLW, PB + O_PLB, d_out, flag);
}

// Round 5
// 5611.642 us; speedup vs baseline: 1.4688x; 1.3193x over previous
//
#include <hip/hip_runtime.h>

// ---------------------------------------------------------------------------
// GraphSAGE GNN forward, MI355X round 5: MFMA attention (QK^T and PV on
// matrix cores; P transposed via per-wave LDS round-trip). Rest = round 4.
// ---------------------------------------------------------------------------

#define N_TOT   65536
#define B_GR    128
#define NP_     512
#define E_TOT   524288
#define EPG     4096
#define DIN_    128
#define C_      256
#define C3_     768
#define H_      4

typedef unsigned int uint;
typedef unsigned short ushort;

// param pool element offsets (ushorts)
#define O_L0LW  0u
#define O_L0LB  32768u
#define O_L0RW  33024u
#define O_L0RES 65792u
#define O_LWL   98560u
#define O_LBL   295168u
#define O_LWR   295936u
#define O_GNW   492544u
#define O_GNB   493568u
#define O_GNA   494592u
#define O_AIW   495616u
#define O_AIB   692224u
#define O_AOW   692992u
#define O_AOB   758528u
#define O_LNW   758784u
#define O_LNB   759040u
#define O_PLW   759296u
#define O_PLB   955904u
#define TOTALP  956160u

typedef __attribute__((ext_vector_type(8))) short bf16x8_t;
typedef __attribute__((ext_vector_type(4))) float f32x4_t;

__device__ __forceinline__ float bf2f(ushort u){ union{uint i; float f;} v; v.i = ((uint)u) << 16; return v.f; }
__device__ __forceinline__ ushort f2bf(float f){
  union{float f; uint u;} v; v.f = f;
  uint u = v.u;
  u += 0x7fffu + ((u >> 16) & 1u);   // RNE
  return (ushort)(u >> 16);
}
__device__ __forceinline__ uint pack2(float a, float b){ return (uint)f2bf(a) | ((uint)f2bf(b) << 16); }
__device__ __forceinline__ float u2f_lo(uint u){ union{uint i; float f;} v; v.i = u << 16; return v.f; }
__device__ __forceinline__ float u2f_hi(uint u){ union{uint i; float f;} v; v.i = u & 0xffff0000u; return v.f; }
__device__ __forceinline__ float gelu_f(float x){ return 0.5f * x * (1.0f + erff(x * 0.70710678118654752440f)); }
__device__ __forceinline__ float wredsum(float v){
  #pragma unroll
  for (int off = 32; off; off >>= 1) v += __shfl_xor(v, off, 64);
  return v;
}

// ---------------------------------------------------------------------------
// dtype probe: gn_w[0]==1.0. f32 -> 0x3F800000 ; bf16 pair -> 0x3F803F80
__global__ void probe_dtype(const uint* __restrict__ gnw_raw, uint* __restrict__ flag){
  if (threadIdx.x == 0 && blockIdx.x == 0)
    *flag = (gnw_raw[0] == 0x3F800000u) ? 1u : 0u;   // 1 = f32 inputs
}

struct Seg { const void* p; uint ofs; };
struct CvtArgs { Seg s[19]; };

__global__ __launch_bounds__(256) void cvt_params(CvtArgs a, ushort* __restrict__ pb,
                                                  const uint* __restrict__ flag){
  uint gi = blockIdx.x * 256u + threadIdx.x;
  if (gi >= TOTALP) return;
  int lo = 0;
  #pragma unroll
  for (int s = 1; s < 18; ++s) if (gi >= a.s[s].ofs) lo = s;
  uint rel = gi - a.s[lo].ofs;
  pb[gi] = (*flag) ? f2bf(((const float*)a.s[lo].p)[rel]) : ((const ushort*)a.s[lo].p)[rel];
}

__global__ __launch_bounds__(256) void cvt_flat(const void* __restrict__ in, ushort* __restrict__ out,
                                                const uint* __restrict__ flag){
  uint i = blockIdx.x * 256u + threadIdx.x;
  out[i] = (*flag) ? f2bf(((const float*)in)[i]) : ((const ushort*)in)[i];
}

// ---------------------------------------------------------------------------
__global__ void deg_count(const int* __restrict__ dst, uint* __restrict__ deg){
  int e = blockIdx.x * 256 + threadIdx.x;
  atomicAdd(&deg[dst[e]], 1u);
}

// ---------------------------------------------------------------------------
// mean-aggregation: agg[n][:] = sum_{dst=n} X[src] / max(deg,1). bf16 in/out.
__global__ __launch_bounds__(256) void sage_agg(const ushort* __restrict__ X,
    const int* __restrict__ src, const int* __restrict__ dst,
    const uint* __restrict__ deg, ushort* __restrict__ agg, int D)
{
  __shared__ float acc[128 * 64];
  const int g = blockIdx.x, cc = blockIdx.y, q = blockIdx.z;
  const int tid = threadIdx.x;
  const int c = tid & 63, eo = tid >> 6;
  for (int i = tid; i < 128 * 64; i += 256) acc[i] = 0.0f;
  __syncthreads();
  const int ebase = g * EPG;
  const int nbase = g * NP_ + q * 128;
  const int ch = cc * 64 + c;
  for (int e0 = 0; e0 < EPG; e0 += 4) {
    int e = ebase + e0 + eo;
    int d = dst[e] - nbase;            // wave-uniform
    if (d >= 0 && d < 128) {
      int s = src[e];
      atomicAdd(&acc[(d << 6) + c], bf2f(X[(size_t)s * D + ch]));
    }
  }
  __syncthreads();
  for (int i = tid; i < 128 * 64; i += 256) {
    int nl = i >> 6, cl = i & 63;
    int n = nbase + nl;
    uint dg = deg[n]; if (dg < 1u) dg = 1u;
    agg[(size_t)n * D + cc * 64 + cl] = f2bf(acc[i] / (float)dg);
  }
}

// ---------------------------------------------------------------------------
// MFMA GEMM (unchanged from round 4): out = A1@W1^T (+A2@W2^T)(+bias)(+addend)
template<bool DUAL>
__global__ __launch_bounds__(256) void gemm_mfma(
    const ushort* __restrict__ A1, int lda1, const ushort* __restrict__ W1,
    const ushort* __restrict__ A2, int lda2, const ushort* __restrict__ W2,
    const ushort* __restrict__ bias, const ushort* addend,   // addend may alias out
    ushort* out, int K, int ldOut)
{
  const int lane = threadIdx.x & 63, wave = threadIdx.x >> 6;
  const int lr = lane & 15;
  const int lk = (lane >> 4) << 3;
  const int m0 = blockIdx.x * 64 + wave * 16;
  const int n0 = blockIdx.y * 64;
  f32x4_t acc[4];
  #pragma unroll
  for (int t = 0; t < 4; ++t) acc[t] = (f32x4_t){0.f, 0.f, 0.f, 0.f};
  {
    const ushort* ap = A1 + (size_t)(m0 + lr) * lda1 + lk;
    const ushort* wp = W1 + (size_t)(n0 + lr) * K + lk;
    for (int kb = 0; kb < K; kb += 32) {
      bf16x8_t a = *(const bf16x8_t*)(ap + kb);
      #pragma unroll
      for (int t = 0; t < 4; ++t) {
        bf16x8_t b = *(const bf16x8_t*)(wp + (size_t)(t * 16) * K + kb);
        acc[t] = __builtin_amdgcn_mfma_f32_16x16x32_bf16(a, b, acc[t], 0, 0, 0);
      }
    }
  }
  if constexpr (DUAL) {
    const ushort* ap = A2 + (size_t)(m0 + lr) * lda2 + lk;
    const ushort* wp = W2 + (size_t)(n0 + lr) * K + lk;
    for (int kb = 0; kb < K; kb += 32) {
      bf16x8_t a = *(const bf16x8_t*)(ap + kb);
      #pragma unroll
      for (int t = 0; t < 4; ++t) {
        bf16x8_t b = *(const bf16x8_t*)(wp + (size_t)(t * 16) * K + kb);
        acc[t] = __builtin_amdgcn_mfma_f32_16x16x32_bf16(a, b, acc[t], 0, 0, 0);
      }
    }
  }
  const int rbase = (lane >> 4) << 2;
  #pragma unroll
  for (int t = 0; t < 4; ++t) {
    const int col = n0 + t * 16 + lr;
    float bv = bias ? bf2f(bias[col]) : 0.0f;
    #pragma unroll
    for (int r = 0; r < 4; ++r) {
      int row = m0 + rbase + r;
      size_t ob = (size_t)row * ldOut + col;
      float v = acc[t][r] + bv;
      if (addend) v += bf2f(addend[ob]);
      out[ob] = f2bf(v);
    }
  }
}

// ---------------------------------------------------------------------------
// Per-graph: in-place row L2-normalize + per-(g,c) moments for GraphNorm.
__global__ __launch_bounds__(256) void rownorm_stats(ushort* __restrict__ h,
    float* __restrict__ m1, float* __restrict__ m2)
{
  __shared__ float s1[256], s2[256];
  const int g = blockIdx.x, tid = threadIdx.x, lane = tid & 63, wave = tid >> 6;
  s1[tid] = 0.0f; s2[tid] = 0.0f;
  __syncthreads();
  for (int r = wave; r < NP_; r += 4) {
    size_t idx = ((size_t)g * NP_ + r) * C_;
    float v0 = bf2f(h[idx + lane]),       v1 = bf2f(h[idx + 64 + lane]);
    float v2 = bf2f(h[idx + 128 + lane]), v3 = bf2f(h[idx + 192 + lane]);
    float ss = v0*v0 + v1*v1 + v2*v2 + v3*v3;
    ss = wredsum(ss);
    float inv = 1.0f / fmaxf(sqrtf(ss), 1e-12f);
    v0 *= inv; v1 *= inv; v2 *= inv; v3 *= inv;
    h[idx + lane] = f2bf(v0);       h[idx + 64 + lane] = f2bf(v1);
    h[idx + 128 + lane] = f2bf(v2); h[idx + 192 + lane] = f2bf(v3);
    atomicAdd(&s1[lane], v0);        atomicAdd(&s1[lane + 64], v1);
    atomicAdd(&s1[lane + 128], v2);  atomicAdd(&s1[lane + 192], v3);
    atomicAdd(&s2[lane], v0*v0);       atomicAdd(&s2[lane + 64], v1*v1);
    atomicAdd(&s2[lane + 128], v2*v2); atomicAdd(&s2[lane + 192], v3*v3);
  }
  __syncthreads();
  m1[g*C_ + tid] = s1[tid] * (1.0f / 512.0f);
  m2[g*C_ + tid] = s2[tid] * (1.0f / 512.0f);
}

// GraphNorm + GELU + residual (res may alias out)
__global__ __launch_bounds__(256) void gn_gelu_add(const ushort* __restrict__ h,
    const ushort* res,
    const float* __restrict__ m1, const float* __restrict__ m2,
    const ushort* __restrict__ gw, const ushort* __restrict__ gb, const ushort* __restrict__ ga,
    ushort* out)
{
  size_t b4 = ((size_t)blockIdx.x * 256 + threadIdx.x) * 4;
  int c = (int)(b4 & (C_ - 1));
  int n = (int)(b4 >> 8);
  int g = n >> 9;
  uint2 hv = *(const uint2*)(h + b4);
  uint2 rv = *(const uint2*)(res + b4);
  float hh[4] = {u2f_lo(hv.x), u2f_hi(hv.x), u2f_lo(hv.y), u2f_hi(hv.y)};
  float rr[4] = {u2f_lo(rv.x), u2f_hi(rv.x), u2f_lo(rv.y), u2f_hi(rv.y)};
  float oo[4];
  #pragma unroll
  for (int j = 0; j < 4; ++j) {
    int cc = c + j;
    float a  = bf2f(ga[cc]);
    float mm = m1[g*C_ + cc];
    float q2 = m2[g*C_ + cc];
    float var = q2 - a * (2.0f - a) * mm * mm;
    float xo = hh[j] - a * mm;
    float y = bf2f(gw[cc]) * xo * rsqrtf(var + 1e-5f) + bf2f(gb[cc]);
    oo[j] = gelu_f(y) + rr[j];
  }
  uint2 ov; ov.x = pack2(oo[0], oo[1]); ov.y = pack2(oo[2], oo[3]);
  *(uint2*)(out + b4) = ov;
}

// ---------------------------------------------------------------------------
// MFMA attention: one block (512 thr = 8 waves) per (graph, head).
// LDS: K rows (pitch 72), V^T (pitch 520), per-wave P scratch 16x32 (pitch 40).
// Each wave: 4 q-tiles of 16 rows; S = 32 MFMA tiles; softmax in C/D layout;
// P -> LDS -> A-layout; O = P.V via Vt B-frags. O -> dead K columns.
#define KS_P 72
#define VT_P 520
#define PW_P 40
__global__ __launch_bounds__(512, 2) void attn_kernel(ushort* __restrict__ qkv)
{
  __shared__ ushort Ks[NP_ * KS_P];       // K[j][c]
  __shared__ ushort Vt[64 * VT_P];        // V^T[c][j]
  __shared__ ushort Pw[8][16 * PW_P];     // per-wave P chunk
  const int bid = blockIdx.x;
  const int g = bid >> 2, h = bid & 3;
  const int tid = threadIdx.x, lane = tid & 63, wave = tid >> 6;
  const int lr = lane & 15, quad = lane >> 4;
  const size_t base = (size_t)g * NP_ * C3_;
  const int qoff = h * 64, koff = C_ + h * 64, voff = 2 * C_ + h * 64;
  for (int idx = tid; idx < NP_ * 64; idx += 512) {
    int j = idx >> 6, c = idx & 63;
    const ushort* row = qkv + base + (size_t)j * C3_;
    Ks[j * KS_P + c] = row[koff + c];
    Vt[c * VT_P + j] = row[voff + c];
  }
  __syncthreads();
  ushort* pw = &Pw[wave][0];
  const int q0 = wave * 64;
  for (int qt = 0; qt < 4; ++qt) {
    const int qr = q0 + qt * 16;
    const ushort* qp = qkv + base + (size_t)(qr + lr) * C3_ + qoff + quad * 8;
    bf16x8_t qa0 = *(const bf16x8_t*)(qp);
    bf16x8_t qa1 = *(const bf16x8_t*)(qp + 32);
    // S = Q.K^T : 32 tiles of 16x16 (cols t*16+lr, rows quad*4+r)
    f32x4_t s[32];
    #pragma unroll
    for (int t = 0; t < 32; ++t) {
      const ushort* kp = Ks + (size_t)(t * 16 + lr) * KS_P + quad * 8;
      bf16x8_t b0 = *(const bf16x8_t*)(kp);
      bf16x8_t b1 = *(const bf16x8_t*)(kp + 32);
      f32x4_t a = (f32x4_t){0.f, 0.f, 0.f, 0.f};
      a = __builtin_amdgcn_mfma_f32_16x16x32_bf16(qa0, b0, a, 0, 0, 0);
      a = __builtin_amdgcn_mfma_f32_16x16x32_bf16(qa1, b1, a, 0, 0, 0);
      s[t] = a;
    }
    // softmax over cols (scale 1/8); rows quad*4+r
    float invv[4];
    #pragma unroll
    for (int r = 0; r < 4; ++r) {
      float m = s[0][r];
      #pragma unroll
      for (int t = 1; t < 32; ++t) m = fmaxf(m, s[t][r]);
      #pragma unroll
      for (int off = 8; off; off >>= 1) m = fmaxf(m, __shfl_xor(m, off, 64));
      float sm = 0.0f;
      #pragma unroll
      for (int t = 0; t < 32; ++t) {
        float e = expf((s[t][r] - m) * 0.125f);
        s[t][r] = e; sm += e;
      }
      #pragma unroll
      for (int off = 8; off; off >>= 1) sm += __shfl_xor(sm, off, 64);
      invv[r] = 1.0f / sm;
    }
    // O = P.V
    f32x4_t o[4];
    #pragma unroll
    for (int t = 0; t < 4; ++t) o[t] = (f32x4_t){0.f, 0.f, 0.f, 0.f};
    for (int kc = 0; kc < 16; ++kc) {
      #pragma unroll
      for (int half = 0; half < 2; ++half) {
        int t = kc * 2 + half;
        #pragma unroll
        for (int r = 0; r < 4; ++r)
          pw[(quad * 4 + r) * PW_P + half * 16 + lr] = f2bf(s[t][r] * invv[r]);
      }
      __threadfence_block();
      bf16x8_t pa = *(const bf16x8_t*)(pw + lr * PW_P + quad * 8);
      #pragma unroll
      for (int nt = 0; nt < 4; ++nt) {
        const ushort* vp = Vt + (size_t)(nt * 16 + lr) * VT_P + kc * 32 + quad * 8;
        bf16x8_t b = *(const bf16x8_t*)(vp);
        o[nt] = __builtin_amdgcn_mfma_f32_16x16x32_bf16(pa, b, o[nt], 0, 0, 0);
      }
    }
    #pragma unroll
    for (int nt = 0; nt < 4; ++nt)
      #pragma unroll
      for (int r = 0; r < 4; ++r)
        qkv[base + (size_t)(qr + quad * 4 + r) * C3_ + koff + nt * 16 + lr] =
            f2bf(o[nt][r]);
  }
}

// ---------------------------------------------------------------------------
__global__ __launch_bounds__(256) void ln_stats(const ushort* __restrict__ x2, float* __restrict__ st)
{
  __shared__ float a1[4], a2[4];
  const int g = blockIdx.x, tid = threadIdx.x, lane = tid & 63, wave = tid >> 6;
  const ushort* p = x2 + (size_t)g * NP_ * C_;
  float s = 0.0f, q = 0.0f;
  for (int i = tid; i < NP_ * C_; i += 256) { float v = bf2f(p[i]); s += v; q += v * v; }
  s = wredsum(s); q = wredsum(q);
  if (lane == 0) { a1[wave] = s; a2[wave] = q; }
  __syncthreads();
  if (tid == 0) {
    float S = a1[0] + a1[1] + a1[2] + a1[3];
    float Q = a2[0] + a2[1] + a2[2] + a2[3];
    float mu = S * (1.0f / (NP_ * C_));
    float var = Q * (1.0f / (NP_ * C_)) - mu * mu;
    st[g * 2] = mu; st[g * 2 + 1] = var;
  }
}

__global__ __launch_bounds__(256) void ln_gelu(const ushort* __restrict__ x2, const float* __restrict__ st,
    const ushort* __restrict__ lw, const ushort* __restrict__ lb, ushort* __restrict__ x3)
{
  size_t b4 = ((size_t)blockIdx.x * 256 + threadIdx.x) * 4;
  int c = (int)(b4 & (C_ - 1));
  int n = (int)(b4 >> 8);
  int g = n >> 9;
  float mu = st[g * 2], var = st[g * 2 + 1];
  float rs = rsqrtf(var + 1e-5f);
  uint2 v = *(const uint2*)(x2 + b4);
  float vv[4] = {u2f_lo(v.x), u2f_hi(v.x), u2f_lo(v.y), u2f_hi(v.y)};
  float oo[4];
  #pragma unroll
  for (int j = 0; j < 4; ++j) {
    int cc = c + j;
    float y = (vv[j] - mu) * rs * bf2f(lw[cc]) + bf2f(lb[cc]);
    oo[j] = gelu_f(y);
  }
  uint2 ov; ov.x = pack2(oo[0], oo[1]); ov.y = pack2(oo[2], oo[3]);
  *(uint2*)(x3 + b4) = ov;
}

__global__ __launch_bounds__(256) void pool_kernel(const ushort* __restrict__ x3, float* __restrict__ pooled)
{
  const int g = blockIdx.x, c = threadIdx.x;
  float s = 0.0f, mx = -3.0e38f;
  for (int r = 0; r < NP_; ++r) {
    float v = bf2f(x3[((size_t)g * NP_ + r) * C_ + c]);
    s += v; mx = fmaxf(mx, v);
  }
  pooled[(size_t)g * C3_ + c]        = s * (1.0f / 512.0f);
  pooled[(size_t)g * C3_ + C_ + c]   = mx;
  pooled[(size_t)g * C3_ + 2*C_ + c] = s;
}

__global__ __launch_bounds__(256) void final_gemm(const float* __restrict__ pooled,
    const ushort* __restrict__ W, const ushort* __restrict__ b, void* __restrict__ out,
    const uint* __restrict__ flag)
{
  const int g = blockIdx.x, c = threadIdx.x;
  float acc = bf2f(b[c]);
  const float* p = pooled + (size_t)g * C3_;
  for (int k = 0; k < C3_; ++k) acc += p[k] * bf2f(W[(size_t)c * C3_ + k]);
  if (*flag) ((float*)out)[g * C_ + c] = acc;
  else       ((ushort*)out)[g * C_ + c] = f2bf(acc);
}

// ---------------------------------------------------------------------------
extern "C" void kernel_launch(void* const* d_in, const int* in_sizes, int n_in,
                              void* d_out, int out_size, void* d_ws, size_t ws_size,
                              hipStream_t stream)
{
  const int* ei   = (const int*)d_in[1];
  const int* srcp = ei;
  const int* dstp = ei + E_TOT;

  const size_t NC = (size_t)N_TOT * C_;                        // 16,777,216
  const size_t NEEDED = (4ull << 20) + 4 * NC * sizeof(ushort); // 132 MB
  if (ws_size < NEEDED) return;

  unsigned char* wsb = (unsigned char*)d_ws;
  uint*   deg    = (uint*)wsb;
  float*  m1     = (float*)(wsb + (256u << 10));
  float*  m2     = (float*)(wsb + (384u << 10));
  float*  lst    = (float*)(wsb + (512u << 10));
  uint*   flag   = (uint*)(wsb + (516u << 10));
  float*  pooled = (float*)(wsb + (520u << 10));
  ushort* PB     = (ushort*)(wsb + (1u << 20));       // param pool bf16
  ushort* S0     = (ushort*)(wsb + (4u << 20));       // x1
  ushort* S1     = S0 + NC;
  ushort* S2     = S1 + NC;
  ushort* S3     = S2 + NC;
  ushort* qkvb   = S1;                                // [N][768] overlay
  ushort* XB     = S3;                                // x bf16 overlay (dead by attn)

  // ---- dtype probe + import ----
  probe_dtype<<<1, 1, 0, stream>>>((const uint*)d_in[10], flag);
  CvtArgs ca;
  ca.s[0]  = { d_in[3],  O_L0LW };  ca.s[1]  = { d_in[4],  O_L0LB };
  ca.s[2]  = { d_in[5],  O_L0RW };  ca.s[3]  = { d_in[6],  O_L0RES };
  ca.s[4]  = { d_in[7],  O_LWL  };  ca.s[5]  = { d_in[8],  O_LBL  };
  ca.s[6]  = { d_in[9],  O_LWR  };  ca.s[7]  = { d_in[10], O_GNW  };
  ca.s[8]  = { d_in[11], O_GNB  };  ca.s[9]  = { d_in[12], O_GNA  };
  ca.s[10] = { d_in[13], O_AIW  };  ca.s[11] = { d_in[14], O_AIB  };
  ca.s[12] = { d_in[15], O_AOW  };  ca.s[13] = { d_in[16], O_AOB  };
  ca.s[14] = { d_in[17], O_LNW  };  ca.s[15] = { d_in[18], O_LNB  };
  ca.s[16] = { d_in[19], O_PLW  };  ca.s[17] = { d_in[20], O_PLB  };
  ca.s[18] = { nullptr,  TOTALP };
  cvt_params<<<(TOTALP + 255) / 256, 256, 0, stream>>>(ca, PB, flag);
  cvt_flat<<<(N_TOT * DIN_) / 256, 256, 0, stream>>>(d_in[0], XB, flag);

  hipMemsetAsync(deg, 0, N_TOT * sizeof(uint), stream);
  deg_count<<<E_TOT / 256, 256, 0, stream>>>(dstp, deg);

  // ---- layer 0 (DIN=128 -> C=256) ----
  sage_agg<<<dim3(B_GR, DIN_ / 64, 4), 256, 0, stream>>>(XB, srcp, dstp, deg, S1, DIN_);
  gemm_mfma<true><<<dim3(N_TOT / 64, C_ / 64), 256, 0, stream>>>(
      S1, DIN_, PB + O_L0LW, XB, DIN_, PB + O_L0RW, PB + O_L0LB, nullptr, S2, DIN_, C_);
  gemm_mfma<false><<<dim3(N_TOT / 64, C_ / 64), 256, 0, stream>>>(
      XB, DIN_, PB + O_L0RES, nullptr, 0, nullptr, nullptr, nullptr, S0, DIN_, C_);
  rownorm_stats<<<B_GR, 256, 0, stream>>>(S2, m1, m2);
  gn_gelu_add<<<(N_TOT * C_) / 1024, 256, 0, stream>>>(S2, S0, m1, m2,
      PB + O_GNW, PB + O_GNB, PB + O_GNA, S0);

  // ---- layers 1..3 (C -> C) ----
  for (int i = 0; i < 3; ++i) {
    sage_agg<<<dim3(B_GR, C_ / 64, 4), 256, 0, stream>>>(S0, srcp, dstp, deg, S1, C_);
    gemm_mfma<true><<<dim3(N_TOT / 64, C_ / 64), 256, 0, stream>>>(
        S1, C_, PB + O_LWL + (size_t)i * C_ * C_, S0, C_, PB + O_LWR + (size_t)i * C_ * C_,
        PB + O_LBL + i * C_, nullptr, S2, C_, C_);
    rownorm_stats<<<B_GR, 256, 0, stream>>>(S2, m1, m2);
    gn_gelu_add<<<(N_TOT * C_) / 1024, 256, 0, stream>>>(S2, S0, m1, m2,
        PB + O_GNW + (i + 1) * C_, PB + O_GNB + (i + 1) * C_, PB + O_GNA + (i + 1) * C_, S0);
  }

  // ---- attention ----
  gemm_mfma<false><<<dim3(N_TOT / 64, C3_ / 64), 256, 0, stream>>>(
      S0, C_, PB + O_AIW, nullptr, 0, nullptr, PB + O_AIB, nullptr, qkvb, C_, C3_);
  attn_kernel<<<B_GR * H_, 512, 0, stream>>>(qkvb);
  gemm_mfma<false><<<dim3(N_TOT / 64, C_ / 64), 256, 0, stream>>>(
      qkvb + C_, C3_, PB + O_AOW, nullptr, 0, nullptr, PB + O_AOB, S0, S0, C_, C_);

  // ---- graph LayerNorm + gelu ----
  ln_stats<<<B_GR, 256, 0, stream>>>(S0, lst);
  ln_gelu<<<(N_TOT * C_) / 1024, 256, 0, stream>>>(S0, lst, PB + O_LNW, PB + O_LNB, S1);

  // ---- pool + projection ----
  pool_kernel<<<B_GR, 256, 0, stream>>>(S1, pooled);
  final_gemm<<<B_GR, 256, 0, stream>>>(pooled, PB + O_PLW, PB + O_PLB, d_out, flag);
}

// Round 6
// 3176.262 us; speedup vs baseline: 2.5950x; 1.7667x over previous
//
#include <hip/hip_runtime.h>

// ---------------------------------------------------------------------------
// GraphSAGE GNN forward, MI355X round 6: CSR-gather aggregation (replaces the
// 755 us/dispatch edge-scan). MFMA GEMMs + MFMA attention from rounds 4/5.
// ---------------------------------------------------------------------------

#define N_TOT   65536
#define B_GR    128
#define NP_     512
#define E_TOT   524288
#define EPG     4096
#define DIN_    128
#define C_      256
#define C3_     768
#define H_      4

typedef unsigned int uint;
typedef unsigned short ushort;

// param pool element offsets (ushorts)
#define O_L0LW  0u
#define O_L0LB  32768u
#define O_L0RW  33024u
#define O_L0RES 65792u
#define O_LWL   98560u
#define O_LBL   295168u
#define O_LWR   295936u
#define O_GNW   492544u
#define O_GNB   493568u
#define O_GNA   494592u
#define O_AIW   495616u
#define O_AIB   692224u
#define O_AOW   692992u
#define O_AOB   758528u
#define O_LNW   758784u
#define O_LNB   759040u
#define O_PLW   759296u
#define O_PLB   955904u
#define TOTALP  956160u

typedef __attribute__((ext_vector_type(8))) short bf16x8_t;
typedef __attribute__((ext_vector_type(4))) float f32x4_t;

__device__ __forceinline__ float bf2f(ushort u){ union{uint i; float f;} v; v.i = ((uint)u) << 16; return v.f; }
__device__ __forceinline__ ushort f2bf(float f){
  union{float f; uint u;} v; v.f = f;
  uint u = v.u;
  u += 0x7fffu + ((u >> 16) & 1u);   // RNE
  return (ushort)(u >> 16);
}
__device__ __forceinline__ uint pack2(float a, float b){ return (uint)f2bf(a) | ((uint)f2bf(b) << 16); }
__device__ __forceinline__ float u2f_lo(uint u){ union{uint i; float f;} v; v.i = u << 16; return v.f; }
__device__ __forceinline__ float u2f_hi(uint u){ union{uint i; float f;} v; v.i = u & 0xffff0000u; return v.f; }
__device__ __forceinline__ float gelu_f(float x){ return 0.5f * x * (1.0f + erff(x * 0.70710678118654752440f)); }
__device__ __forceinline__ float wredsum(float v){
  #pragma unroll
  for (int off = 32; off; off >>= 1) v += __shfl_xor(v, off, 64);
  return v;
}

// ---------------------------------------------------------------------------
// dtype probe: gn_w[0]==1.0. f32 -> 0x3F800000 ; bf16 pair -> 0x3F803F80
__global__ void probe_dtype(const uint* __restrict__ gnw_raw, uint* __restrict__ flag){
  if (threadIdx.x == 0 && blockIdx.x == 0)
    *flag = (gnw_raw[0] == 0x3F800000u) ? 1u : 0u;   // 1 = f32 inputs
}

struct Seg { const void* p; uint ofs; };
struct CvtArgs { Seg s[19]; };

__global__ __launch_bounds__(256) void cvt_params(CvtArgs a, ushort* __restrict__ pb,
                                                  const uint* __restrict__ flag){
  uint gi = blockIdx.x * 256u + threadIdx.x;
  if (gi >= TOTALP) return;
  int lo = 0;
  #pragma unroll
  for (int s = 1; s < 18; ++s) if (gi >= a.s[s].ofs) lo = s;
  uint rel = gi - a.s[lo].ofs;
  pb[gi] = (*flag) ? f2bf(((const float*)a.s[lo].p)[rel]) : ((const ushort*)a.s[lo].p)[rel];
}

__global__ __launch_bounds__(256) void cvt_flat(const void* __restrict__ in, ushort* __restrict__ out,
                                                const uint* __restrict__ flag){
  uint i = blockIdx.x * 256u + threadIdx.x;
  out[i] = (*flag) ? f2bf(((const float*)in)[i]) : ((const ushort*)in)[i];
}

// ---------------------------------------------------------------------------
__global__ void deg_count(const int* __restrict__ dst, uint* __restrict__ deg){
  int e = blockIdx.x * 256 + threadIdx.x;
  atomicAdd(&deg[dst[e]], 1u);
}

// per-graph exclusive scan of deg (512 nodes) -> rowptr/cursor (global edge idx)
__global__ __launch_bounds__(512) void scan_deg(const uint* __restrict__ deg,
    uint* __restrict__ rowptr, uint* __restrict__ cursor)
{
  __shared__ uint s[512];
  const int g = blockIdx.x, tid = threadIdx.x;
  uint v = deg[g * NP_ + tid];
  s[tid] = v;
  __syncthreads();
  #pragma unroll
  for (int off = 1; off < 512; off <<= 1) {
    uint t = (tid >= off) ? s[tid - off] : 0u;
    __syncthreads();
    s[tid] += t;
    __syncthreads();
  }
  uint p = g * EPG + (s[tid] - v);
  rowptr[g * NP_ + tid] = p;
  cursor[g * NP_ + tid] = p;
}

// bucket edges by dst: csr[pos] = src
__global__ void scatter_edges(const int* __restrict__ src, const int* __restrict__ dst,
    uint* __restrict__ cursor, int* __restrict__ csr)
{
  int e = blockIdx.x * 256 + threadIdx.x;
  uint p = atomicAdd(&cursor[dst[e]], 1u);
  csr[p] = src[e];
}

// ---------------------------------------------------------------------------
// CSR mean-aggregation: one wave per node. Lane owns D/64 channels.
template<int D>
__global__ __launch_bounds__(256) void sage_agg_csr(const ushort* __restrict__ X,
    const int* __restrict__ csr, const uint* __restrict__ rowptr,
    const uint* __restrict__ deg, ushort* __restrict__ agg)
{
  constexpr int CPL = D / 64;     // 2 (D=128) or 4 (D=256) channels per lane
  const int tid = threadIdx.x, lane = tid & 63, wave = tid >> 6;
  const int n = blockIdx.x * 4 + wave;
  const uint start = rowptr[n];
  const uint dg = deg[n];
  const int co = lane * CPL;
  float acc[CPL];
  #pragma unroll
  for (int k = 0; k < CPL; ++k) acc[k] = 0.0f;

  auto addrow = [&](int s) {
    const ushort* r = X + (size_t)s * D + co;
    if constexpr (CPL == 2) {
      uint u = *(const uint*)r;
      acc[0] += u2f_lo(u); acc[1] += u2f_hi(u);
    } else {
      uint2 u = *(const uint2*)r;
      acc[0] += u2f_lo(u.x); acc[1] += u2f_hi(u.x);
      acc[2] += u2f_lo(u.y); acc[3] += u2f_hi(u.y);
    }
  };

  uint j = 0;
  for (; j + 4 <= dg; j += 4) {
    int s0 = csr[start + j],     s1 = csr[start + j + 1];
    int s2 = csr[start + j + 2], s3 = csr[start + j + 3];
    addrow(s0); addrow(s1); addrow(s2); addrow(s3);
  }
  for (; j < dg; ++j) addrow(csr[start + j]);

  float inv = 1.0f / (float)(dg < 1u ? 1u : dg);
  ushort* op = agg + (size_t)n * D + co;
  if constexpr (CPL == 2) {
    *(uint*)op = pack2(acc[0] * inv, acc[1] * inv);
  } else {
    uint2 o; o.x = pack2(acc[0] * inv, acc[1] * inv);
    o.y = pack2(acc[2] * inv, acc[3] * inv);
    *(uint2*)op = o;
  }
}

// ---------------------------------------------------------------------------
// MFMA GEMM: out = A1@W1^T (+A2@W2^T)(+bias)(+addend)
template<bool DUAL>
__global__ __launch_bounds__(256) void gemm_mfma(
    const ushort* __restrict__ A1, int lda1, const ushort* __restrict__ W1,
    const ushort* __restrict__ A2, int lda2, const ushort* __restrict__ W2,
    const ushort* __restrict__ bias, const ushort* addend,   // addend may alias out
    ushort* out, int K, int ldOut)
{
  const int lane = threadIdx.x & 63, wave = threadIdx.x >> 6;
  const int lr = lane & 15;
  const int lk = (lane >> 4) << 3;
  const int m0 = blockIdx.x * 64 + wave * 16;
  const int n0 = blockIdx.y * 64;
  f32x4_t acc[4];
  #pragma unroll
  for (int t = 0; t < 4; ++t) acc[t] = (f32x4_t){0.f, 0.f, 0.f, 0.f};
  {
    const ushort* ap = A1 + (size_t)(m0 + lr) * lda1 + lk;
    const ushort* wp = W1 + (size_t)(n0 + lr) * K + lk;
    for (int kb = 0; kb < K; kb += 32) {
      bf16x8_t a = *(const bf16x8_t*)(ap + kb);
      #pragma unroll
      for (int t = 0; t < 4; ++t) {
        bf16x8_t b = *(const bf16x8_t*)(wp + (size_t)(t * 16) * K + kb);
        acc[t] = __builtin_amdgcn_mfma_f32_16x16x32_bf16(a, b, acc[t], 0, 0, 0);
      }
    }
  }
  if constexpr (DUAL) {
    const ushort* ap = A2 + (size_t)(m0 + lr) * lda2 + lk;
    const ushort* wp = W2 + (size_t)(n0 + lr) * K + lk;
    for (int kb = 0; kb < K; kb += 32) {
      bf16x8_t a = *(const bf16x8_t*)(ap + kb);
      #pragma unroll
      for (int t = 0; t < 4; ++t) {
        bf16x8_t b = *(const bf16x8_t*)(wp + (size_t)(t * 16) * K + kb);
        acc[t] = __builtin_amdgcn_mfma_f32_16x16x32_bf16(a, b, acc[t], 0, 0, 0);
      }
    }
  }
  const int rbase = (lane >> 4) << 2;
  #pragma unroll
  for (int t = 0; t < 4; ++t) {
    const int col = n0 + t * 16 + lr;
    float bv = bias ? bf2f(bias[col]) : 0.0f;
    #pragma unroll
    for (int r = 0; r < 4; ++r) {
      int row = m0 + rbase + r;
      size_t ob = (size_t)row * ldOut + col;
      float v = acc[t][r] + bv;
      if (addend) v += bf2f(addend[ob]);
      out[ob] = f2bf(v);
    }
  }
}

// ---------------------------------------------------------------------------
// Per-graph: in-place row L2-normalize + per-(g,c) moments for GraphNorm.
__global__ __launch_bounds__(256) void rownorm_stats(ushort* __restrict__ h,
    float* __restrict__ m1, float* __restrict__ m2)
{
  __shared__ float s1[256], s2[256];
  const int g = blockIdx.x, tid = threadIdx.x, lane = tid & 63, wave = tid >> 6;
  s1[tid] = 0.0f; s2[tid] = 0.0f;
  __syncthreads();
  for (int r = wave; r < NP_; r += 4) {
    size_t idx = ((size_t)g * NP_ + r) * C_;
    float v0 = bf2f(h[idx + lane]),       v1 = bf2f(h[idx + 64 + lane]);
    float v2 = bf2f(h[idx + 128 + lane]), v3 = bf2f(h[idx + 192 + lane]);
    float ss = v0*v0 + v1*v1 + v2*v2 + v3*v3;
    ss = wredsum(ss);
    float inv = 1.0f / fmaxf(sqrtf(ss), 1e-12f);
    v0 *= inv; v1 *= inv; v2 *= inv; v3 *= inv;
    h[idx + lane] = f2bf(v0);       h[idx + 64 + lane] = f2bf(v1);
    h[idx + 128 + lane] = f2bf(v2); h[idx + 192 + lane] = f2bf(v3);
    atomicAdd(&s1[lane], v0);        atomicAdd(&s1[lane + 64], v1);
    atomicAdd(&s1[lane + 128], v2);  atomicAdd(&s1[lane + 192], v3);
    atomicAdd(&s2[lane], v0*v0);       atomicAdd(&s2[lane + 64], v1*v1);
    atomicAdd(&s2[lane + 128], v2*v2); atomicAdd(&s2[lane + 192], v3*v3);
  }
  __syncthreads();
  m1[g*C_ + tid] = s1[tid] * (1.0f / 512.0f);
  m2[g*C_ + tid] = s2[tid] * (1.0f / 512.0f);
}

// GraphNorm + GELU + residual (res may alias out)
__global__ __launch_bounds__(256) void gn_gelu_add(const ushort* __restrict__ h,
    const ushort* res,
    const float* __restrict__ m1, const float* __restrict__ m2,
    const ushort* __restrict__ gw, const ushort* __restrict__ gb, const ushort* __restrict__ ga,
    ushort* out)
{
  size_t b4 = ((size_t)blockIdx.x * 256 + threadIdx.x) * 4;
  int c = (int)(b4 & (C_ - 1));
  int n = (int)(b4 >> 8);
  int g = n >> 9;
  uint2 hv = *(const uint2*)(h + b4);
  uint2 rv = *(const uint2*)(res + b4);
  float hh[4] = {u2f_lo(hv.x), u2f_hi(hv.x), u2f_lo(hv.y), u2f_hi(hv.y)};
  float rr[4] = {u2f_lo(rv.x), u2f_hi(rv.x), u2f_lo(rv.y), u2f_hi(rv.y)};
  float oo[4];
  #pragma unroll
  for (int j = 0; j < 4; ++j) {
    int cc = c + j;
    float a  = bf2f(ga[cc]);
    float mm = m1[g*C_ + cc];
    float q2 = m2[g*C_ + cc];
    float var = q2 - a * (2.0f - a) * mm * mm;
    float xo = hh[j] - a * mm;
    float y = bf2f(gw[cc]) * xo * rsqrtf(var + 1e-5f) + bf2f(gb[cc]);
    oo[j] = gelu_f(y) + rr[j];
  }
  uint2 ov; ov.x = pack2(oo[0], oo[1]); ov.y = pack2(oo[2], oo[3]);
  *(uint2*)(out + b4) = ov;
}

// ---------------------------------------------------------------------------
// MFMA attention (round 5): one block (512 thr = 8 waves) per (graph, head).
#define KS_P 72
#define VT_P 520
#define PW_P 40
__global__ __launch_bounds__(512, 2) void attn_kernel(ushort* __restrict__ qkv)
{
  __shared__ ushort Ks[NP_ * KS_P];       // K[j][c]
  __shared__ ushort Vt[64 * VT_P];        // V^T[c][j]
  __shared__ ushort Pw[8][16 * PW_P];     // per-wave P chunk
  const int bid = blockIdx.x;
  const int g = bid >> 2, h = bid & 3;
  const int tid = threadIdx.x, lane = tid & 63, wave = tid >> 6;
  const int lr = lane & 15, quad = lane >> 4;
  const size_t base = (size_t)g * NP_ * C3_;
  const int qoff = h * 64, koff = C_ + h * 64, voff = 2 * C_ + h * 64;
  for (int idx = tid; idx < NP_ * 64; idx += 512) {
    int j = idx >> 6, c = idx & 63;
    const ushort* row = qkv + base + (size_t)j * C3_;
    Ks[j * KS_P + c] = row[koff + c];
    Vt[c * VT_P + j] = row[voff + c];
  }
  __syncthreads();
  ushort* pw = &Pw[wave][0];
  const int q0 = wave * 64;
  for (int qt = 0; qt < 4; ++qt) {
    const int qr = q0 + qt * 16;
    const ushort* qp = qkv + base + (size_t)(qr + lr) * C3_ + qoff + quad * 8;
    bf16x8_t qa0 = *(const bf16x8_t*)(qp);
    bf16x8_t qa1 = *(const bf16x8_t*)(qp + 32);
    f32x4_t s[32];
    #pragma unroll
    for (int t = 0; t < 32; ++t) {
      const ushort* kp = Ks + (size_t)(t * 16 + lr) * KS_P + quad * 8;
      bf16x8_t b0 = *(const bf16x8_t*)(kp);
      bf16x8_t b1 = *(const bf16x8_t*)(kp + 32);
      f32x4_t a = (f32x4_t){0.f, 0.f, 0.f, 0.f};
      a = __builtin_amdgcn_mfma_f32_16x16x32_bf16(qa0, b0, a, 0, 0, 0);
      a = __builtin_amdgcn_mfma_f32_16x16x32_bf16(qa1, b1, a, 0, 0, 0);
      s[t] = a;
    }
    float invv[4];
    #pragma unroll
    for (int r = 0; r < 4; ++r) {
      float m = s[0][r];
      #pragma unroll
      for (int t = 1; t < 32; ++t) m = fmaxf(m, s[t][r]);
      #pragma unroll
      for (int off = 8; off; off >>= 1) m = fmaxf(m, __shfl_xor(m, off, 64));
      float sm = 0.0f;
      #pragma unroll
      for (int t = 0; t < 32; ++t) {
        float e = expf((s[t][r] - m) * 0.125f);
        s[t][r] = e; sm += e;
      }
      #pragma unroll
      for (int off = 8; off; off >>= 1) sm += __shfl_xor(sm, off, 64);
      invv[r] = 1.0f / sm;
    }
    f32x4_t o[4];
    #pragma unroll
    for (int t = 0; t < 4; ++t) o[t] = (f32x4_t){0.f, 0.f, 0.f, 0.f};
    for (int kc = 0; kc < 16; ++kc) {
      #pragma unroll
      for (int half = 0; half < 2; ++half) {
        int t = kc * 2 + half;
        #pragma unroll
        for (int r = 0; r < 4; ++r)
          pw[(quad * 4 + r) * PW_P + half * 16 + lr] = f2bf(s[t][r] * invv[r]);
      }
      __threadfence_block();
      bf16x8_t pa = *(const bf16x8_t*)(pw + lr * PW_P + quad * 8);
      #pragma unroll
      for (int nt = 0; nt < 4; ++nt) {
        const ushort* vp = Vt + (size_t)(nt * 16 + lr) * VT_P + kc * 32 + quad * 8;
        bf16x8_t b = *(const bf16x8_t*)(vp);
        o[nt] = __builtin_amdgcn_mfma_f32_16x16x32_bf16(pa, b, o[nt], 0, 0, 0);
      }
    }
    #pragma unroll
    for (int nt = 0; nt < 4; ++nt)
      #pragma unroll
      for (int r = 0; r < 4; ++r)
        qkv[base + (size_t)(qr + quad * 4 + r) * C3_ + koff + nt * 16 + lr] =
            f2bf(o[nt][r]);
  }
}

// ---------------------------------------------------------------------------
__global__ __launch_bounds__(256) void ln_stats(const ushort* __restrict__ x2, float* __restrict__ st)
{
  __shared__ float a1[4], a2[4];
  const int g = blockIdx.x, tid = threadIdx.x, lane = tid & 63, wave = tid >> 6;
  const ushort* p = x2 + (size_t)g * NP_ * C_;
  float s = 0.0f, q = 0.0f;
  for (int i = tid; i < NP_ * C_; i += 256) { float v = bf2f(p[i]); s += v; q += v * v; }
  s = wredsum(s); q = wredsum(q);
  if (lane == 0) { a1[wave] = s; a2[wave] = q; }
  __syncthreads();
  if (tid == 0) {
    float S = a1[0] + a1[1] + a1[2] + a1[3];
    float Q = a2[0] + a2[1] + a2[2] + a2[3];
    float mu = S * (1.0f / (NP_ * C_));
    float var = Q * (1.0f / (NP_ * C_)) - mu * mu;
    st[g * 2] = mu; st[g * 2 + 1] = var;
  }
}

__global__ __launch_bounds__(256) void ln_gelu(const ushort* __restrict__ x2, const float* __restrict__ st,
    const ushort* __restrict__ lw, const ushort* __restrict__ lb, ushort* __restrict__ x3)
{
  size_t b4 = ((size_t)blockIdx.x * 256 + threadIdx.x) * 4;
  int c = (int)(b4 & (C_ - 1));
  int n = (int)(b4 >> 8);
  int g = n >> 9;
  float mu = st[g * 2], var = st[g * 2 + 1];
  float rs = rsqrtf(var + 1e-5f);
  uint2 v = *(const uint2*)(x2 + b4);
  float vv[4] = {u2f_lo(v.x), u2f_hi(v.x), u2f_lo(v.y), u2f_hi(v.y)};
  float oo[4];
  #pragma unroll
  for (int j = 0; j < 4; ++j) {
    int cc = c + j;
    float y = (vv[j] - mu) * rs * bf2f(lw[cc]) + bf2f(lb[cc]);
    oo[j] = gelu_f(y);
  }
  uint2 ov; ov.x = pack2(oo[0], oo[1]); ov.y = pack2(oo[2], oo[3]);
  *(uint2*)(x3 + b4) = ov;
}

__global__ __launch_bounds__(256) void pool_kernel(const ushort* __restrict__ x3, float* __restrict__ pooled)
{
  const int g = blockIdx.x, c = threadIdx.x;
  float s = 0.0f, mx = -3.0e38f;
  for (int r = 0; r < NP_; ++r) {
    float v = bf2f(x3[((size_t)g * NP_ + r) * C_ + c]);
    s += v; mx = fmaxf(mx, v);
  }
  pooled[(size_t)g * C3_ + c]        = s * (1.0f / 512.0f);
  pooled[(size_t)g * C3_ + C_ + c]   = mx;
  pooled[(size_t)g * C3_ + 2*C_ + c] = s;
}

__global__ __launch_bounds__(256) void final_gemm(const float* __restrict__ pooled,
    const ushort* __restrict__ W, const ushort* __restrict__ b, void* __restrict__ out,
    const uint* __restrict__ flag)
{
  const int g = blockIdx.x, c = threadIdx.x;
  float acc = bf2f(b[c]);
  const float* p = pooled + (size_t)g * C3_;
  for (int k = 0; k < C3_; ++k) acc += p[k] * bf2f(W[(size_t)c * C3_ + k]);
  if (*flag) ((float*)out)[g * C_ + c] = acc;
  else       ((ushort*)out)[g * C_ + c] = f2bf(acc);
}

// ---------------------------------------------------------------------------
extern "C" void kernel_launch(void* const* d_in, const int* in_sizes, int n_in,
                              void* d_out, int out_size, void* d_ws, size_t ws_size,
                              hipStream_t stream)
{
  const int* ei   = (const int*)d_in[1];
  const int* srcp = ei;
  const int* dstp = ei + E_TOT;

  const size_t NC = (size_t)N_TOT * C_;                        // 16,777,216
  const size_t NEEDED = (4ull << 20) + 4 * NC * sizeof(ushort); // 132 MB
  if (ws_size < NEEDED) return;

  unsigned char* wsb = (unsigned char*)d_ws;
  uint*   deg    = (uint*)wsb;
  float*  m1     = (float*)(wsb + (256u << 10));
  float*  m2     = (float*)(wsb + (384u << 10));
  float*  lst    = (float*)(wsb + (512u << 10));
  uint*   flag   = (uint*)(wsb + (516u << 10));
  float*  pooled = (float*)(wsb + (520u << 10));
  ushort* PB     = (ushort*)(wsb + (1u << 20));       // param pool bf16
  ushort* S0     = (ushort*)(wsb + (4u << 20));       // x1
  ushort* S1     = S0 + NC;
  ushort* S2     = S1 + NC;
  ushort* S3     = S2 + NC;
  ushort* qkvb   = S1;                                // [N][768] overlay
  ushort* XB     = S3;                                // x bf16 (lower 16MB of S3 slab)
  // CSR arrays in the dead upper half of the S3 slab (freed before qkv GEMM)
  unsigned char* s3hi = (unsigned char*)(S3 + (size_t)N_TOT * DIN_);  // byte ofs 116MB
  int*  csr    = (int*)s3hi;                          // 2 MB
  uint* rowptr = (uint*)(s3hi + (2u << 20));          // 256 KB
  uint* cursor = (uint*)(s3hi + (2u << 20) + (256u << 10));

  // ---- dtype probe + import ----
  probe_dtype<<<1, 1, 0, stream>>>((const uint*)d_in[10], flag);
  CvtArgs ca;
  ca.s[0]  = { d_in[3],  O_L0LW };  ca.s[1]  = { d_in[4],  O_L0LB };
  ca.s[2]  = { d_in[5],  O_L0RW };  ca.s[3]  = { d_in[6],  O_L0RES };
  ca.s[4]  = { d_in[7],  O_LWL  };  ca.s[5]  = { d_in[8],  O_LBL  };
  ca.s[6]  = { d_in[9],  O_LWR  };  ca.s[7]  = { d_in[10], O_GNW  };
  ca.s[8]  = { d_in[11], O_GNB  };  ca.s[9]  = { d_in[12], O_GNA  };
  ca.s[10] = { d_in[13], O_AIW  };  ca.s[11] = { d_in[14], O_AIB  };
  ca.s[12] = { d_in[15], O_AOW  };  ca.s[13] = { d_in[16], O_AOB  };
  ca.s[14] = { d_in[17], O_LNW  };  ca.s[15] = { d_in[18], O_LNB  };
  ca.s[16] = { d_in[19], O_PLW  };  ca.s[17] = { d_in[20], O_PLB  };
  ca.s[18] = { nullptr,  TOTALP };
  cvt_params<<<(TOTALP + 255) / 256, 256, 0, stream>>>(ca, PB, flag);
  cvt_flat<<<(N_TOT * DIN_) / 256, 256, 0, stream>>>(d_in[0], XB, flag);

  // ---- degree + CSR build (reused by all 4 layers) ----
  hipMemsetAsync(deg, 0, N_TOT * sizeof(uint), stream);
  deg_count<<<E_TOT / 256, 256, 0, stream>>>(dstp, deg);
  scan_deg<<<B_GR, 512, 0, stream>>>(deg, rowptr, cursor);
  scatter_edges<<<E_TOT / 256, 256, 0, stream>>>(srcp, dstp, cursor, csr);

  // ---- layer 0 (DIN=128 -> C=256) ----
  sage_agg_csr<DIN_><<<N_TOT / 4, 256, 0, stream>>>(XB, csr, rowptr, deg, S1);
  gemm_mfma<true><<<dim3(N_TOT / 64, C_ / 64), 256, 0, stream>>>(
      S1, DIN_, PB + O_L0LW, XB, DIN_, PB + O_L0RW, PB + O_L0LB, nullptr, S2, DIN_, C_);
  gemm_mfma<false><<<dim3(N_TOT / 64, C_ / 64), 256, 0, stream>>>(
      XB, DIN_, PB + O_L0RES, nullptr, 0, nullptr, nullptr, nullptr, S0, DIN_, C_);
  rownorm_stats<<<B_GR, 256, 0, stream>>>(S2, m1, m2);
  gn_gelu_add<<<(N_TOT * C_) / 1024, 256, 0, stream>>>(S2, S0, m1, m2,
      PB + O_GNW, PB + O_GNB, PB + O_GNA, S0);

  // ---- layers 1..3 (C -> C) ----
  for (int i = 0; i < 3; ++i) {
    sage_agg_csr<C_><<<N_TOT / 4, 256, 0, stream>>>(S0, csr, rowptr, deg, S1);
    gemm_mfma<true><<<dim3(N_TOT / 64, C_ / 64), 256, 0, stream>>>(
        S1, C_, PB + O_LWL + (size_t)i * C_ * C_, S0, C_, PB + O_LWR + (size_t)i * C_ * C_,
        PB + O_LBL + i * C_, nullptr, S2, C_, C_);
    rownorm_stats<<<B_GR, 256, 0, stream>>>(S2, m1, m2);
    gn_gelu_add<<<(N_TOT * C_) / 1024, 256, 0, stream>>>(S2, S0, m1, m2,
        PB + O_GNW + (i + 1) * C_, PB + O_GNB + (i + 1) * C_, PB + O_GNA + (i + 1) * C_, S0);
  }

  // ---- attention ----
  gemm_mfma<false><<<dim3(N_TOT / 64, C3_ / 64), 256, 0, stream>>>(
      S0, C_, PB + O_AIW, nullptr, 0, nullptr, PB + O_AIB, nullptr, qkvb, C_, C3_);
  attn_kernel<<<B_GR * H_, 512, 0, stream>>>(qkvb);
  gemm_mfma<false><<<dim3(N_TOT / 64, C_ / 64), 256, 0, stream>>>(
      qkvb + C_, C3_, PB + O_AOW, nullptr, 0, nullptr, PB + O_AOB, S0, S0, C_, C_);

  // ---- graph LayerNorm + gelu ----
  ln_stats<<<B_GR, 256, 0, stream>>>(S0, lst);
  ln_gelu<<<(N_TOT * C_) / 1024, 256, 0, stream>>>(S0, lst, PB + O_LNW, PB + O_LNB, S1);

  // ---- pool + projection ----
  pool_kernel<<<B_GR, 256, 0, stream>>>(S1, pooled);
  final_gemm<<<B_GR, 256, 0, stream>>>(pooled, PB + O_PLW, PB + O_PLB, d_out, flag);
}

// Round 7
// 1856.126 us; speedup vs baseline: 4.4407x; 1.7112x over previous
//
#include <hip/hip_runtime.h>

// ---------------------------------------------------------------------------
// GraphSAGE GNN forward, MI355X round 7: parallelize per-graph reductions
// (rownorm/ln/pool were 128-block serial loops = 46%+ of runtime).
// CSR aggregation + MFMA GEMMs + MFMA attention from rounds 4-6.
// ---------------------------------------------------------------------------

#define N_TOT   65536
#define B_GR    128
#define NP_     512
#define E_TOT   524288
#define EPG     4096
#define DIN_    128
#define C_      256
#define C3_     768
#define H_      4

typedef unsigned int uint;
typedef unsigned short ushort;

// param pool element offsets (ushorts)
#define O_L0LW  0u
#define O_L0LB  32768u
#define O_L0RW  33024u
#define O_L0RES 65792u
#define O_LWL   98560u
#define O_LBL   295168u
#define O_LWR   295936u
#define O_GNW   492544u
#define O_GNB   493568u
#define O_GNA   494592u
#define O_AIW   495616u
#define O_AIB   692224u
#define O_AOW   692992u
#define O_AOB   758528u
#define O_LNW   758784u
#define O_LNB   759040u
#define O_PLW   759296u
#define O_PLB   955904u
#define TOTALP  956160u

typedef __attribute__((ext_vector_type(8))) short bf16x8_t;
typedef __attribute__((ext_vector_type(4))) float f32x4_t;

__device__ __forceinline__ float bf2f(ushort u){ union{uint i; float f;} v; v.i = ((uint)u) << 16; return v.f; }
__device__ __forceinline__ ushort f2bf(float f){
  union{float f; uint u;} v; v.f = f;
  uint u = v.u;
  u += 0x7fffu + ((u >> 16) & 1u);   // RNE
  return (ushort)(u >> 16);
}
__device__ __forceinline__ uint pack2(float a, float b){ return (uint)f2bf(a) | ((uint)f2bf(b) << 16); }
__device__ __forceinline__ float u2f_lo(uint u){ union{uint i; float f;} v; v.i = u << 16; return v.f; }
__device__ __forceinline__ float u2f_hi(uint u){ union{uint i; float f;} v; v.i = u & 0xffff0000u; return v.f; }
__device__ __forceinline__ float gelu_f(float x){ return 0.5f * x * (1.0f + erff(x * 0.70710678118654752440f)); }
__device__ __forceinline__ float wredsum(float v){
  #pragma unroll
  for (int off = 32; off; off >>= 1) v += __shfl_xor(v, off, 64);
  return v;
}

// ---------------------------------------------------------------------------
// dtype probe: gn_w[0]==1.0. f32 -> 0x3F800000 ; bf16 pair -> 0x3F803F80
__global__ void probe_dtype(const uint* __restrict__ gnw_raw, uint* __restrict__ flag){
  if (threadIdx.x == 0 && blockIdx.x == 0)
    *flag = (gnw_raw[0] == 0x3F800000u) ? 1u : 0u;   // 1 = f32 inputs
}

struct Seg { const void* p; uint ofs; };
struct CvtArgs { Seg s[19]; };

__global__ __launch_bounds__(256) void cvt_params(CvtArgs a, ushort* __restrict__ pb,
                                                  const uint* __restrict__ flag){
  uint gi = blockIdx.x * 256u + threadIdx.x;
  if (gi >= TOTALP) return;
  int lo = 0;
  #pragma unroll
  for (int s = 1; s < 18; ++s) if (gi >= a.s[s].ofs) lo = s;
  uint rel = gi - a.s[lo].ofs;
  pb[gi] = (*flag) ? f2bf(((const float*)a.s[lo].p)[rel]) : ((const ushort*)a.s[lo].p)[rel];
}

__global__ __launch_bounds__(256) void cvt_flat(const void* __restrict__ in, ushort* __restrict__ out,
                                                const uint* __restrict__ flag){
  uint i = blockIdx.x * 256u + threadIdx.x;
  out[i] = (*flag) ? f2bf(((const float*)in)[i]) : ((const ushort*)in)[i];
}

// ---------------------------------------------------------------------------
__global__ void deg_count(const int* __restrict__ dst, uint* __restrict__ deg){
  int e = blockIdx.x * 256 + threadIdx.x;
  atomicAdd(&deg[dst[e]], 1u);
}

// per-graph exclusive scan of deg (512 nodes) -> rowptr/cursor
__global__ __launch_bounds__(512) void scan_deg(const uint* __restrict__ deg,
    uint* __restrict__ rowptr, uint* __restrict__ cursor)
{
  __shared__ uint s[512];
  const int g = blockIdx.x, tid = threadIdx.x;
  uint v = deg[g * NP_ + tid];
  s[tid] = v;
  __syncthreads();
  #pragma unroll
  for (int off = 1; off < 512; off <<= 1) {
    uint t = (tid >= off) ? s[tid - off] : 0u;
    __syncthreads();
    s[tid] += t;
    __syncthreads();
  }
  uint p = g * EPG + (s[tid] - v);
  rowptr[g * NP_ + tid] = p;
  cursor[g * NP_ + tid] = p;
}

__global__ void scatter_edges(const int* __restrict__ src, const int* __restrict__ dst,
    uint* __restrict__ cursor, int* __restrict__ csr)
{
  int e = blockIdx.x * 256 + threadIdx.x;
  uint p = atomicAdd(&cursor[dst[e]], 1u);
  csr[p] = src[e];
}

// ---------------------------------------------------------------------------
// CSR mean-aggregation: one wave per node. Lane owns D/64 channels.
template<int D>
__global__ __launch_bounds__(256) void sage_agg_csr(const ushort* __restrict__ X,
    const int* __restrict__ csr, const uint* __restrict__ rowptr,
    const uint* __restrict__ deg, ushort* __restrict__ agg)
{
  constexpr int CPL = D / 64;
  const int tid = threadIdx.x, lane = tid & 63, wave = tid >> 6;
  const int n = blockIdx.x * 4 + wave;
  const uint start = rowptr[n];
  const uint dg = deg[n];
  const int co = lane * CPL;
  float acc[CPL];
  #pragma unroll
  for (int k = 0; k < CPL; ++k) acc[k] = 0.0f;

  auto addrow = [&](int s) {
    const ushort* r = X + (size_t)s * D + co;
    if constexpr (CPL == 2) {
      uint u = *(const uint*)r;
      acc[0] += u2f_lo(u); acc[1] += u2f_hi(u);
    } else {
      uint2 u = *(const uint2*)r;
      acc[0] += u2f_lo(u.x); acc[1] += u2f_hi(u.x);
      acc[2] += u2f_lo(u.y); acc[3] += u2f_hi(u.y);
    }
  };

  uint j = 0;
  for (; j + 4 <= dg; j += 4) {
    int s0 = csr[start + j],     s1 = csr[start + j + 1];
    int s2 = csr[start + j + 2], s3 = csr[start + j + 3];
    addrow(s0); addrow(s1); addrow(s2); addrow(s3);
  }
  for (; j < dg; ++j) addrow(csr[start + j]);

  float inv = 1.0f / (float)(dg < 1u ? 1u : dg);
  ushort* op = agg + (size_t)n * D + co;
  if constexpr (CPL == 2) {
    *(uint*)op = pack2(acc[0] * inv, acc[1] * inv);
  } else {
    uint2 o; o.x = pack2(acc[0] * inv, acc[1] * inv);
    o.y = pack2(acc[2] * inv, acc[3] * inv);
    *(uint2*)op = o;
  }
}

// ---------------------------------------------------------------------------
// MFMA GEMM: out = A1@W1^T (+A2@W2^T)(+bias)(+addend)
template<bool DUAL>
__global__ __launch_bounds__(256) void gemm_mfma(
    const ushort* __restrict__ A1, int lda1, const ushort* __restrict__ W1,
    const ushort* __restrict__ A2, int lda2, const ushort* __restrict__ W2,
    const ushort* __restrict__ bias, const ushort* addend,   // addend may alias out
    ushort* out, int K, int ldOut)
{
  const int lane = threadIdx.x & 63, wave = threadIdx.x >> 6;
  const int lr = lane & 15;
  const int lk = (lane >> 4) << 3;
  const int m0 = blockIdx.x * 64 + wave * 16;
  const int n0 = blockIdx.y * 64;
  f32x4_t acc[4];
  #pragma unroll
  for (int t = 0; t < 4; ++t) acc[t] = (f32x4_t){0.f, 0.f, 0.f, 0.f};
  {
    const ushort* ap = A1 + (size_t)(m0 + lr) * lda1 + lk;
    const ushort* wp = W1 + (size_t)(n0 + lr) * K + lk;
    for (int kb = 0; kb < K; kb += 32) {
      bf16x8_t a = *(const bf16x8_t*)(ap + kb);
      #pragma unroll
      for (int t = 0; t < 4; ++t) {
        bf16x8_t b = *(const bf16x8_t*)(wp + (size_t)(t * 16) * K + kb);
        acc[t] = __builtin_amdgcn_mfma_f32_16x16x32_bf16(a, b, acc[t], 0, 0, 0);
      }
    }
  }
  if constexpr (DUAL) {
    const ushort* ap = A2 + (size_t)(m0 + lr) * lda2 + lk;
    const ushort* wp = W2 + (size_t)(n0 + lr) * K + lk;
    for (int kb = 0; kb < K; kb += 32) {
      bf16x8_t a = *(const bf16x8_t*)(ap + kb);
      #pragma unroll
      for (int t = 0; t < 4; ++t) {
        bf16x8_t b = *(const bf16x8_t*)(wp + (size_t)(t * 16) * K + kb);
        acc[t] = __builtin_amdgcn_mfma_f32_16x16x32_bf16(a, b, acc[t], 0, 0, 0);
      }
    }
  }
  const int rbase = (lane >> 4) << 2;
  #pragma unroll
  for (int t = 0; t < 4; ++t) {
    const int col = n0 + t * 16 + lr;
    float bv = bias ? bf2f(bias[col]) : 0.0f;
    #pragma unroll
    for (int r = 0; r < 4; ++r) {
      int row = m0 + rbase + r;
      size_t ob = (size_t)row * ldOut + col;
      float v = acc[t][r] + bv;
      if (addend) v += bf2f(addend[ob]);
      out[ob] = f2bf(v);
    }
  }
}

// ---------------------------------------------------------------------------
// Row L2-normalize (in place) + per-(g,c) SUM moments via global atomics.
// One wave = 8 rows of one graph. Lane owns 4 channels. m1/m2 pre-zeroed.
__global__ __launch_bounds__(256) void rownorm_part(ushort* __restrict__ h,
    float* __restrict__ m1, float* __restrict__ m2)
{
  const int tid = threadIdx.x, lane = tid & 63, wave = tid >> 6;
  const int wid = blockIdx.x * 4 + wave;     // 0..8191
  const int r0 = wid * 8;                    // 8 rows, same graph (512 % 8 == 0)
  const int g = r0 >> 9;
  const int co = lane * 4;
  float a1[4] = {0.f, 0.f, 0.f, 0.f}, a2[4] = {0.f, 0.f, 0.f, 0.f};
  #pragma unroll
  for (int j = 0; j < 8; ++j) {
    size_t idx = ((size_t)(r0 + j)) * C_ + co;
    uint2 u = *(const uint2*)(h + idx);
    float v0 = u2f_lo(u.x), v1 = u2f_hi(u.x), v2 = u2f_lo(u.y), v3 = u2f_hi(u.y);
    float ss = v0*v0 + v1*v1 + v2*v2 + v3*v3;
    ss = wredsum(ss);
    float inv = 1.0f / fmaxf(sqrtf(ss), 1e-12f);
    v0 *= inv; v1 *= inv; v2 *= inv; v3 *= inv;
    uint2 o; o.x = pack2(v0, v1); o.y = pack2(v2, v3);
    *(uint2*)(h + idx) = o;
    a1[0] += v0; a1[1] += v1; a1[2] += v2; a1[3] += v3;
    a2[0] += v0*v0; a2[1] += v1*v1; a2[2] += v2*v2; a2[3] += v3*v3;
  }
  #pragma unroll
  for (int k = 0; k < 4; ++k) {
    atomicAdd(&m1[g*C_ + co + k], a1[k]);
    atomicAdd(&m2[g*C_ + co + k], a2[k]);
  }
}

// GraphNorm + GELU + residual. m1/m2 hold SUMS over 512 nodes.
__global__ __launch_bounds__(256) void gn_gelu_add(const ushort* __restrict__ h,
    const ushort* res,
    const float* __restrict__ m1, const float* __restrict__ m2,
    const ushort* __restrict__ gw, const ushort* __restrict__ gb, const ushort* __restrict__ ga,
    ushort* out)
{
  size_t b4 = ((size_t)blockIdx.x * 256 + threadIdx.x) * 4;
  int c = (int)(b4 & (C_ - 1));
  int n = (int)(b4 >> 8);
  int g = n >> 9;
  uint2 hv = *(const uint2*)(h + b4);
  uint2 rv = *(const uint2*)(res + b4);
  float hh[4] = {u2f_lo(hv.x), u2f_hi(hv.x), u2f_lo(hv.y), u2f_hi(hv.y)};
  float rr[4] = {u2f_lo(rv.x), u2f_hi(rv.x), u2f_lo(rv.y), u2f_hi(rv.y)};
  float oo[4];
  #pragma unroll
  for (int j = 0; j < 4; ++j) {
    int cc = c + j;
    float a  = bf2f(ga[cc]);
    float mm = m1[g*C_ + cc] * (1.0f / 512.0f);
    float q2 = m2[g*C_ + cc] * (1.0f / 512.0f);
    float var = q2 - a * (2.0f - a) * mm * mm;
    float xo = hh[j] - a * mm;
    float y = bf2f(gw[cc]) * xo * rsqrtf(var + 1e-5f) + bf2f(gb[cc]);
    oo[j] = gelu_f(y) + rr[j];
  }
  uint2 ov; ov.x = pack2(oo[0], oo[1]); ov.y = pack2(oo[2], oo[3]);
  *(uint2*)(out + b4) = ov;
}

// ---------------------------------------------------------------------------
// MFMA attention (round 5): one block (512 thr = 8 waves) per (graph, head).
#define KS_P 72
#define VT_P 520
#define PW_P 40
__global__ __launch_bounds__(512, 2) void attn_kernel(ushort* __restrict__ qkv)
{
  __shared__ ushort Ks[NP_ * KS_P];
  __shared__ ushort Vt[64 * VT_P];
  __shared__ ushort Pw[8][16 * PW_P];
  const int bid = blockIdx.x;
  const int g = bid >> 2, h = bid & 3;
  const int tid = threadIdx.x, lane = tid & 63, wave = tid >> 6;
  const int lr = lane & 15, quad = lane >> 4;
  const size_t base = (size_t)g * NP_ * C3_;
  const int qoff = h * 64, koff = C_ + h * 64, voff = 2 * C_ + h * 64;
  for (int idx = tid; idx < NP_ * 64; idx += 512) {
    int j = idx >> 6, c = idx & 63;
    const ushort* row = qkv + base + (size_t)j * C3_;
    Ks[j * KS_P + c] = row[koff + c];
    Vt[c * VT_P + j] = row[voff + c];
  }
  __syncthreads();
  ushort* pw = &Pw[wave][0];
  const int q0 = wave * 64;
  for (int qt = 0; qt < 4; ++qt) {
    const int qr = q0 + qt * 16;
    const ushort* qp = qkv + base + (size_t)(qr + lr) * C3_ + qoff + quad * 8;
    bf16x8_t qa0 = *(const bf16x8_t*)(qp);
    bf16x8_t qa1 = *(const bf16x8_t*)(qp + 32);
    f32x4_t s[32];
    #pragma unroll
    for (int t = 0; t < 32; ++t) {
      const ushort* kp = Ks + (size_t)(t * 16 + lr) * KS_P + quad * 8;
      bf16x8_t b0 = *(const bf16x8_t*)(kp);
      bf16x8_t b1 = *(const bf16x8_t*)(kp + 32);
      f32x4_t a = (f32x4_t){0.f, 0.f, 0.f, 0.f};
      a = __builtin_amdgcn_mfma_f32_16x16x32_bf16(qa0, b0, a, 0, 0, 0);
      a = __builtin_amdgcn_mfma_f32_16x16x32_bf16(qa1, b1, a, 0, 0, 0);
      s[t] = a;
    }
    float invv[4];
    #pragma unroll
    for (int r = 0; r < 4; ++r) {
      float m = s[0][r];
      #pragma unroll
      for (int t = 1; t < 32; ++t) m = fmaxf(m, s[t][r]);
      #pragma unroll
      for (int off = 8; off; off >>= 1) m = fmaxf(m, __shfl_xor(m, off, 64));
      float sm = 0.0f;
      #pragma unroll
      for (int t = 0; t < 32; ++t) {
        float e = expf((s[t][r] - m) * 0.125f);
        s[t][r] = e; sm += e;
      }
      #pragma unroll
      for (int off = 8; off; off >>= 1) sm += __shfl_xor(sm, off, 64);
      invv[r] = 1.0f / sm;
    }
    f32x4_t o[4];
    #pragma unroll
    for (int t = 0; t < 4; ++t) o[t] = (f32x4_t){0.f, 0.f, 0.f, 0.f};
    for (int kc = 0; kc < 16; ++kc) {
      #pragma unroll
      for (int half = 0; half < 2; ++half) {
        int t = kc * 2 + half;
        #pragma unroll
        for (int r = 0; r < 4; ++r)
          pw[(quad * 4 + r) * PW_P + half * 16 + lr] = f2bf(s[t][r] * invv[r]);
      }
      __threadfence_block();
      bf16x8_t pa = *(const bf16x8_t*)(pw + lr * PW_P + quad * 8);
      #pragma unroll
      for (int nt = 0; nt < 4; ++nt) {
        const ushort* vp = Vt + (size_t)(nt * 16 + lr) * VT_P + kc * 32 + quad * 8;
        bf16x8_t b = *(const bf16x8_t*)(vp);
        o[nt] = __builtin_amdgcn_mfma_f32_16x16x32_bf16(pa, b, o[nt], 0, 0, 0);
      }
    }
    #pragma unroll
    for (int nt = 0; nt < 4; ++nt)
      #pragma unroll
      for (int r = 0; r < 4; ++r)
        qkv[base + (size_t)(qr + quad * 4 + r) * C3_ + koff + nt * 16 + lr] =
            f2bf(o[nt][r]);
  }
}

// ---------------------------------------------------------------------------
// Graph-LN: partial sums (grid 128x8) -> atomics; finalize converts to mu/var.
__global__ __launch_bounds__(256) void ln_part(const ushort* __restrict__ x2, float* __restrict__ st)
{
  __shared__ float a1[4], a2[4];
  const int g = blockIdx.x, sl = blockIdx.y;
  const int tid = threadIdx.x, lane = tid & 63, wave = tid >> 6;
  const ushort* p = x2 + ((size_t)g * NP_ + sl * 64) * C_;
  float s = 0.0f, q = 0.0f;
  for (int i = tid; i < 64 * C_; i += 256) { float v = bf2f(p[i]); s += v; q += v * v; }
  s = wredsum(s); q = wredsum(q);
  if (lane == 0) { a1[wave] = s; a2[wave] = q; }
  __syncthreads();
  if (tid == 0) {
    atomicAdd(&st[g * 2],     a1[0] + a1[1] + a1[2] + a1[3]);
    atomicAdd(&st[g * 2 + 1], a2[0] + a2[1] + a2[2] + a2[3]);
  }
}

__global__ void ln_finalize(float* __restrict__ st)
{
  int g = threadIdx.x;
  float S = st[g * 2], Q = st[g * 2 + 1];
  float mu = S * (1.0f / (NP_ * C_));
  float var = Q * (1.0f / (NP_ * C_)) - mu * mu;
  st[g * 2] = mu; st[g * 2 + 1] = var;
}

__global__ __launch_bounds__(256) void ln_gelu(const ushort* __restrict__ x2, const float* __restrict__ st,
    const ushort* __restrict__ lw, const ushort* __restrict__ lb, ushort* __restrict__ x3)
{
  size_t b4 = ((size_t)blockIdx.x * 256 + threadIdx.x) * 4;
  int c = (int)(b4 & (C_ - 1));
  int n = (int)(b4 >> 8);
  int g = n >> 9;
  float mu = st[g * 2], var = st[g * 2 + 1];
  float rs = rsqrtf(var + 1e-5f);
  uint2 v = *(const uint2*)(x2 + b4);
  float vv[4] = {u2f_lo(v.x), u2f_hi(v.x), u2f_lo(v.y), u2f_hi(v.y)};
  float oo[4];
  #pragma unroll
  for (int j = 0; j < 4; ++j) {
    int cc = c + j;
    float y = (vv[j] - mu) * rs * bf2f(lw[cc]) + bf2f(lb[cc]);
    oo[j] = gelu_f(y);
  }
  uint2 ov; ov.x = pack2(oo[0], oo[1]); ov.y = pack2(oo[2], oo[3]);
  *(uint2*)(x3 + b4) = ov;
}

// ---------------------------------------------------------------------------
// Pool: per-slice partials (grid 128x8) then combine.
__global__ __launch_bounds__(256) void pool_part(const ushort* __restrict__ x3,
    float* __restrict__ psum, float* __restrict__ pmax)
{
  const int g = blockIdx.x, sl = blockIdx.y, c = threadIdx.x;
  const ushort* p = x3 + ((size_t)g * NP_ + sl * 64) * C_ + c;
  float s = 0.0f, mx = -3.0e38f;
  #pragma unroll 4
  for (int r = 0; r < 64; ++r) {
    float v = bf2f(p[(size_t)r * C_]);
    s += v; mx = fmaxf(mx, v);
  }
  psum[((size_t)g * 8 + sl) * C_ + c] = s;
  pmax[((size_t)g * 8 + sl) * C_ + c] = mx;
}

__global__ __launch_bounds__(256) void pool_final(const float* __restrict__ psum,
    const float* __restrict__ pmax, float* __restrict__ pooled)
{
  const int g = blockIdx.x, c = threadIdx.x;
  float s = 0.0f, mx = -3.0e38f;
  #pragma unroll
  for (int sl = 0; sl < 8; ++sl) {
    s += psum[((size_t)g * 8 + sl) * C_ + c];
    mx = fmaxf(mx, pmax[((size_t)g * 8 + sl) * C_ + c]);
  }
  pooled[(size_t)g * C3_ + c]        = s * (1.0f / 512.0f);
  pooled[(size_t)g * C3_ + C_ + c]   = mx;
  pooled[(size_t)g * C3_ + 2*C_ + c] = s;
}

__global__ __launch_bounds__(256) void final_gemm(const float* __restrict__ pooled,
    const ushort* __restrict__ W, const ushort* __restrict__ b, void* __restrict__ out,
    const uint* __restrict__ flag)
{
  const int g = blockIdx.x, c = threadIdx.x;
  float acc = bf2f(b[c]);
  const float* p = pooled + (size_t)g * C3_;
  for (int k = 0; k < C3_; ++k) acc += p[k] * bf2f(W[(size_t)c * C3_ + k]);
  if (*flag) ((float*)out)[g * C_ + c] = acc;
  else       ((ushort*)out)[g * C_ + c] = f2bf(acc);
}

// ---------------------------------------------------------------------------
extern "C" void kernel_launch(void* const* d_in, const int* in_sizes, int n_in,
                              void* d_out, int out_size, void* d_ws, size_t ws_size,
                              hipStream_t stream)
{
  const int* ei   = (const int*)d_in[1];
  const int* srcp = ei;
  const int* dstp = ei + E_TOT;

  const size_t NC = (size_t)N_TOT * C_;                        // 16,777,216
  const size_t NEEDED = (4ull << 20) + 4 * NC * sizeof(ushort); // 132 MB
  if (ws_size < NEEDED) return;

  unsigned char* wsb = (unsigned char*)d_ws;
  uint*   deg    = (uint*)wsb;
  float*  m1     = (float*)(wsb + (256u << 10));
  float*  m2     = (float*)(wsb + (384u << 10));
  float*  lst    = (float*)(wsb + (512u << 10));
  uint*   flag   = (uint*)(wsb + (516u << 10));
  float*  pooled = (float*)(wsb + (520u << 10));
  ushort* PB     = (ushort*)(wsb + (1u << 20));       // param pool bf16
  ushort* S0     = (ushort*)(wsb + (4u << 20));       // x1
  ushort* S1     = S0 + NC;
  ushort* S2     = S1 + NC;
  ushort* S3     = S2 + NC;
  ushort* qkvb   = S1;                                // [N][768] overlay
  ushort* XB     = S3;                                // x bf16 (lower 16MB of S3)
  unsigned char* s3hi = (unsigned char*)(S3 + (size_t)N_TOT * DIN_);
  int*  csr    = (int*)s3hi;                          // 2 MB
  uint* rowptr = (uint*)(s3hi + (2u << 20));          // 256 KB
  uint* cursor = (uint*)(s3hi + (2u << 20) + (256u << 10));
  float* psum  = (float*)S2;                          // pool partials (S2 dead then)
  float* pmax  = psum + (size_t)B_GR * 8 * C_;

  // ---- dtype probe + import ----
  probe_dtype<<<1, 1, 0, stream>>>((const uint*)d_in[10], flag);
  CvtArgs ca;
  ca.s[0]  = { d_in[3],  O_L0LW };  ca.s[1]  = { d_in[4],  O_L0LB };
  ca.s[2]  = { d_in[5],  O_L0RW };  ca.s[3]  = { d_in[6],  O_L0RES };
  ca.s[4]  = { d_in[7],  O_LWL  };  ca.s[5]  = { d_in[8],  O_LBL  };
  ca.s[6]  = { d_in[9],  O_LWR  };  ca.s[7]  = { d_in[10], O_GNW  };
  ca.s[8]  = { d_in[11], O_GNB  };  ca.s[9]  = { d_in[12], O_GNA  };
  ca.s[10] = { d_in[13], O_AIW  };  ca.s[11] = { d_in[14], O_AIB  };
  ca.s[12] = { d_in[15], O_AOW  };  ca.s[13] = { d_in[16], O_AOB  };
  ca.s[14] = { d_in[17], O_LNW  };  ca.s[15] = { d_in[18], O_LNB  };
  ca.s[16] = { d_in[19], O_PLW  };  ca.s[17] = { d_in[20], O_PLB  };
  ca.s[18] = { nullptr,  TOTALP };
  cvt_params<<<(TOTALP + 255) / 256, 256, 0, stream>>>(ca, PB, flag);
  cvt_flat<<<(N_TOT * DIN_) / 256, 256, 0, stream>>>(d_in[0], XB, flag);

  // ---- degree + CSR build ----
  hipMemsetAsync(deg, 0, N_TOT * sizeof(uint), stream);
  hipMemsetAsync(wsb + (512u << 10), 0, 1024, stream);           // lst
  deg_count<<<E_TOT / 256, 256, 0, stream>>>(dstp, deg);
  scan_deg<<<B_GR, 512, 0, stream>>>(deg, rowptr, cursor);
  scatter_edges<<<E_TOT / 256, 256, 0, stream>>>(srcp, dstp, cursor, csr);

  // ---- layer 0 (DIN=128 -> C=256) ----
  sage_agg_csr<DIN_><<<N_TOT / 4, 256, 0, stream>>>(XB, csr, rowptr, deg, S1);
  gemm_mfma<true><<<dim3(N_TOT / 64, C_ / 64), 256, 0, stream>>>(
      S1, DIN_, PB + O_L0LW, XB, DIN_, PB + O_L0RW, PB + O_L0LB, nullptr, S2, DIN_, C_);
  gemm_mfma<false><<<dim3(N_TOT / 64, C_ / 64), 256, 0, stream>>>(
      XB, DIN_, PB + O_L0RES, nullptr, 0, nullptr, nullptr, nullptr, S0, DIN_, C_);
  hipMemsetAsync(wsb + (256u << 10), 0, 256u << 10, stream);     // m1+m2
  rownorm_part<<<N_TOT / 32, 256, 0, stream>>>(S2, m1, m2);
  gn_gelu_add<<<(N_TOT * C_) / 1024, 256, 0, stream>>>(S2, S0, m1, m2,
      PB + O_GNW, PB + O_GNB, PB + O_GNA, S0);

  // ---- layers 1..3 (C -> C) ----
  for (int i = 0; i < 3; ++i) {
    sage_agg_csr<C_><<<N_TOT / 4, 256, 0, stream>>>(S0, csr, rowptr, deg, S1);
    gemm_mfma<true><<<dim3(N_TOT / 64, C_ / 64), 256, 0, stream>>>(
        S1, C_, PB + O_LWL + (size_t)i * C_ * C_, S0, C_, PB + O_LWR + (size_t)i * C_ * C_,
        PB + O_LBL + i * C_, nullptr, S2, C_, C_);
    hipMemsetAsync(wsb + (256u << 10), 0, 256u << 10, stream);   // m1+m2
    rownorm_part<<<N_TOT / 32, 256, 0, stream>>>(S2, m1, m2);
    gn_gelu_add<<<(N_TOT * C_) / 1024, 256, 0, stream>>>(S2, S0, m1, m2,
        PB + O_GNW + (i + 1) * C_, PB + O_GNB + (i + 1) * C_, PB + O_GNA + (i + 1) * C_, S0);
  }

  // ---- attention ----
  gemm_mfma<false><<<dim3(N_TOT / 64, C3_ / 64), 256, 0, stream>>>(
      S0, C_, PB + O_AIW, nullptr, 0, nullptr, PB + O_AIB, nullptr, qkvb, C_, C3_);
  attn_kernel<<<B_GR * H_, 512, 0, stream>>>(qkvb);
  gemm_mfma<false><<<dim3(N_TOT / 64, C_ / 64), 256, 0, stream>>>(
      qkvb + C_, C3_, PB + O_AOW, nullptr, 0, nullptr, PB + O_AOB, S0, S0, C_, C_);

  // ---- graph LayerNorm + gelu ----
  ln_part<<<dim3(B_GR, 8), 256, 0, stream>>>(S0, lst);
  ln_finalize<<<1, B_GR, 0, stream>>>(lst);
  ln_gelu<<<(N_TOT * C_) / 1024, 256, 0, stream>>>(S0, lst, PB + O_LNW, PB + O_LNB, S1);

  // ---- pool + projection ----
  pool_part<<<dim3(B_GR, 8), 256, 0, stream>>>(S1, psum, pmax);
  pool_final<<<B_GR, 256, 0, stream>>>(psum, pmax, pooled);
  final_gemm<<<B_GR, 256, 0, stream>>>(pooled, PB + O_PLW, PB + O_PLB, d_out, flag);
}

// Round 8
// 1388.898 us; speedup vs baseline: 5.9346x; 1.3364x over previous
//
#include <hip/hip_runtime.h>

// ---------------------------------------------------------------------------
// GraphSAGE GNN forward, MI355X round 8: restructured MFMA GEMM.
// 64x256 block tile, wave = 64x64 (16 MFMA per 8 loads), LDS-staged epilogue
// with packed 128B-contiguous bf16 stores (kills partial-line RMW: R7 showed
// WRITE 108MB vs 32MB ideal on 2B scalar stores).
// ---------------------------------------------------------------------------

#define N_TOT   65536
#define B_GR    128
#define NP_     512
#define E_TOT   524288
#define EPG     4096
#define DIN_    128
#define C_      256
#define C3_     768
#define H_      4

typedef unsigned int uint;
typedef unsigned short ushort;

// param pool element offsets (ushorts)
#define O_L0LW  0u
#define O_L0LB  32768u
#define O_L0RW  33024u
#define O_L0RES 65792u
#define O_LWL   98560u
#define O_LBL   295168u
#define O_LWR   295936u
#define O_GNW   492544u
#define O_GNB   493568u
#define O_GNA   494592u
#define O_AIW   495616u
#define O_AIB   692224u
#define O_AOW   692992u
#define O_AOB   758528u
#define O_LNW   758784u
#define O_LNB   759040u
#define O_PLW   759296u
#define O_PLB   955904u
#define TOTALP  956160u

typedef __attribute__((ext_vector_type(8))) short bf16x8_t;
typedef __attribute__((ext_vector_type(4))) float f32x4_t;

__device__ __forceinline__ float bf2f(ushort u){ union{uint i; float f;} v; v.i = ((uint)u) << 16; return v.f; }
__device__ __forceinline__ ushort f2bf(float f){
  union{float f; uint u;} v; v.f = f;
  uint u = v.u;
  u += 0x7fffu + ((u >> 16) & 1u);   // RNE
  return (ushort)(u >> 16);
}
__device__ __forceinline__ uint pack2(float a, float b){ return (uint)f2bf(a) | ((uint)f2bf(b) << 16); }
__device__ __forceinline__ float u2f_lo(uint u){ union{uint i; float f;} v; v.i = u << 16; return v.f; }
__device__ __forceinline__ float u2f_hi(uint u){ union{uint i; float f;} v; v.i = u & 0xffff0000u; return v.f; }
__device__ __forceinline__ float gelu_f(float x){ return 0.5f * x * (1.0f + erff(x * 0.70710678118654752440f)); }
__device__ __forceinline__ float wredsum(float v){
  #pragma unroll
  for (int off = 32; off; off >>= 1) v += __shfl_xor(v, off, 64);
  return v;
}

// ---------------------------------------------------------------------------
// dtype probe: gn_w[0]==1.0. f32 -> 0x3F800000 ; bf16 pair -> 0x3F803F80
__global__ void probe_dtype(const uint* __restrict__ gnw_raw, uint* __restrict__ flag){
  if (threadIdx.x == 0 && blockIdx.x == 0)
    *flag = (gnw_raw[0] == 0x3F800000u) ? 1u : 0u;   // 1 = f32 inputs
}

struct Seg { const void* p; uint ofs; };
struct CvtArgs { Seg s[19]; };

__global__ __launch_bounds__(256) void cvt_params(CvtArgs a, ushort* __restrict__ pb,
                                                  const uint* __restrict__ flag){
  uint gi = blockIdx.x * 256u + threadIdx.x;
  if (gi >= TOTALP) return;
  int lo = 0;
  #pragma unroll
  for (int s = 1; s < 18; ++s) if (gi >= a.s[s].ofs) lo = s;
  uint rel = gi - a.s[lo].ofs;
  pb[gi] = (*flag) ? f2bf(((const float*)a.s[lo].p)[rel]) : ((const ushort*)a.s[lo].p)[rel];
}

__global__ __launch_bounds__(256) void cvt_flat(const void* __restrict__ in, ushort* __restrict__ out,
                                                const uint* __restrict__ flag){
  uint i = blockIdx.x * 256u + threadIdx.x;
  out[i] = (*flag) ? f2bf(((const float*)in)[i]) : ((const ushort*)in)[i];
}

// ---------------------------------------------------------------------------
__global__ void deg_count(const int* __restrict__ dst, uint* __restrict__ deg){
  int e = blockIdx.x * 256 + threadIdx.x;
  atomicAdd(&deg[dst[e]], 1u);
}

// per-graph exclusive scan of deg (512 nodes) -> rowptr/cursor
__global__ __launch_bounds__(512) void scan_deg(const uint* __restrict__ deg,
    uint* __restrict__ rowptr, uint* __restrict__ cursor)
{
  __shared__ uint s[512];
  const int g = blockIdx.x, tid = threadIdx.x;
  uint v = deg[g * NP_ + tid];
  s[tid] = v;
  __syncthreads();
  #pragma unroll
  for (int off = 1; off < 512; off <<= 1) {
    uint t = (tid >= off) ? s[tid - off] : 0u;
    __syncthreads();
    s[tid] += t;
    __syncthreads();
  }
  uint p = g * EPG + (s[tid] - v);
  rowptr[g * NP_ + tid] = p;
  cursor[g * NP_ + tid] = p;
}

__global__ void scatter_edges(const int* __restrict__ src, const int* __restrict__ dst,
    uint* __restrict__ cursor, int* __restrict__ csr)
{
  int e = blockIdx.x * 256 + threadIdx.x;
  uint p = atomicAdd(&cursor[dst[e]], 1u);
  csr[p] = src[e];
}

// ---------------------------------------------------------------------------
// CSR mean-aggregation: one wave per node. Lane owns D/64 channels.
template<int D>
__global__ __launch_bounds__(256) void sage_agg_csr(const ushort* __restrict__ X,
    const int* __restrict__ csr, const uint* __restrict__ rowptr,
    const uint* __restrict__ deg, ushort* __restrict__ agg)
{
  constexpr int CPL = D / 64;
  const int tid = threadIdx.x, lane = tid & 63, wave = tid >> 6;
  const int n = blockIdx.x * 4 + wave;
  const uint start = rowptr[n];
  const uint dg = deg[n];
  const int co = lane * CPL;
  float acc[CPL];
  #pragma unroll
  for (int k = 0; k < CPL; ++k) acc[k] = 0.0f;

  auto addrow = [&](int s) {
    const ushort* r = X + (size_t)s * D + co;
    if constexpr (CPL == 2) {
      uint u = *(const uint*)r;
      acc[0] += u2f_lo(u); acc[1] += u2f_hi(u);
    } else {
      uint2 u = *(const uint2*)r;
      acc[0] += u2f_lo(u.x); acc[1] += u2f_hi(u.x);
      acc[2] += u2f_lo(u.y); acc[3] += u2f_hi(u.y);
    }
  };

  uint j = 0;
  for (; j + 4 <= dg; j += 4) {
    int s0 = csr[start + j],     s1 = csr[start + j + 1];
    int s2 = csr[start + j + 2], s3 = csr[start + j + 3];
    addrow(s0); addrow(s1); addrow(s2); addrow(s3);
  }
  for (; j < dg; ++j) addrow(csr[start + j]);

  float inv = 1.0f / (float)(dg < 1u ? 1u : dg);
  ushort* op = agg + (size_t)n * D + co;
  if constexpr (CPL == 2) {
    *(uint*)op = pack2(acc[0] * inv, acc[1] * inv);
  } else {
    uint2 o; o.x = pack2(acc[0] * inv, acc[1] * inv);
    o.y = pack2(acc[2] * inv, acc[3] * inv);
    *(uint2*)op = o;
  }
}

// ---------------------------------------------------------------------------
// MFMA GEMM v2: block = 64 rows x 256 cols, 4 waves, wave = 64x64 (16 tiles).
// Per K-step: 8 loads -> 16 MFMA. Epilogue: per-wave LDS staging (2 rounds of
// 32 rows, pitch 68 f32) -> packed uint2 bf16 stores, 128B-contiguous rows.
template<bool DUAL>
__global__ __launch_bounds__(256, 4) void gemm_mfma(
    const ushort* __restrict__ A1, int lda1, const ushort* __restrict__ W1,
    const ushort* __restrict__ A2, int lda2, const ushort* __restrict__ W2,
    const ushort* __restrict__ bias, const ushort* addend,   // addend may alias out
    ushort* out, int K, int ldOut)
{
  __shared__ float Cs[4][32 * 68];
  const int lane = threadIdx.x & 63, wave = threadIdx.x >> 6;
  const int lr = lane & 15, quad = lane >> 4;
  const int m0 = blockIdx.x * 64;
  const int n0 = blockIdx.y * 256 + wave * 64;
  f32x4_t acc[4][4];   // [row tile][col tile]
  #pragma unroll
  for (int rt = 0; rt < 4; ++rt)
    #pragma unroll
    for (int ct = 0; ct < 4; ++ct) acc[rt][ct] = (f32x4_t){0.f, 0.f, 0.f, 0.f};
  {
    const ushort* ap = A1 + (size_t)(m0 + lr) * lda1 + quad * 8;
    const ushort* wp = W1 + (size_t)(n0 + lr) * K + quad * 8;
    for (int kb = 0; kb < K; kb += 32) {
      bf16x8_t a[4], b[4];
      #pragma unroll
      for (int rt = 0; rt < 4; ++rt) a[rt] = *(const bf16x8_t*)(ap + (size_t)(rt * 16) * lda1 + kb);
      #pragma unroll
      for (int ct = 0; ct < 4; ++ct) b[ct] = *(const bf16x8_t*)(wp + (size_t)(ct * 16) * K + kb);
      #pragma unroll
      for (int rt = 0; rt < 4; ++rt)
        #pragma unroll
        for (int ct = 0; ct < 4; ++ct)
          acc[rt][ct] = __builtin_amdgcn_mfma_f32_16x16x32_bf16(a[rt], b[ct], acc[rt][ct], 0, 0, 0);
    }
  }
  if constexpr (DUAL) {
    const ushort* ap = A2 + (size_t)(m0 + lr) * lda2 + quad * 8;
    const ushort* wp = W2 + (size_t)(n0 + lr) * K + quad * 8;
    for (int kb = 0; kb < K; kb += 32) {
      bf16x8_t a[4], b[4];
      #pragma unroll
      for (int rt = 0; rt < 4; ++rt) a[rt] = *(const bf16x8_t*)(ap + (size_t)(rt * 16) * lda2 + kb);
      #pragma unroll
      for (int ct = 0; ct < 4; ++ct) b[ct] = *(const bf16x8_t*)(wp + (size_t)(ct * 16) * K + kb);
      #pragma unroll
      for (int rt = 0; rt < 4; ++rt)
        #pragma unroll
        for (int ct = 0; ct < 4; ++ct)
          acc[rt][ct] = __builtin_amdgcn_mfma_f32_16x16x32_bf16(a[rt], b[ct], acc[rt][ct], 0, 0, 0);
    }
  }
  // epilogue
  const int cb = lr * 4;                     // col base within wave's 64
  float bv[4] = {0.f, 0.f, 0.f, 0.f};
  if (bias) {
    #pragma unroll
    for (int j = 0; j < 4; ++j) bv[j] = bf2f(bias[n0 + cb + j]);
  }
  float* cs = &Cs[wave][0];
  #pragma unroll
  for (int round = 0; round < 2; ++round) {
    #pragma unroll
    for (int rt2 = 0; rt2 < 2; ++rt2) {
      int rt = round * 2 + rt2;
      #pragma unroll
      for (int ct = 0; ct < 4; ++ct)
        #pragma unroll
        for (int r = 0; r < 4; ++r)
          cs[(rt2 * 16 + quad * 4 + r) * 68 + ct * 16 + lr] = acc[rt][ct][r];
    }
    __syncthreads();
    #pragma unroll
    for (int it = 0; it < 8; ++it) {
      int Lr = it * 4 + quad;                // 0..31
      float4 v = *(const float4*)(cs + Lr * 68 + cb);
      int grow = m0 + round * 32 + Lr;
      size_t ob = (size_t)grow * ldOut + n0 + cb;
      float r0 = v.x + bv[0], r1 = v.y + bv[1], r2 = v.z + bv[2], r3 = v.w + bv[3];
      if (addend) {
        uint2 ad = *(const uint2*)(addend + ob);
        r0 += u2f_lo(ad.x); r1 += u2f_hi(ad.x);
        r2 += u2f_lo(ad.y); r3 += u2f_hi(ad.y);
      }
      uint2 o; o.x = pack2(r0, r1); o.y = pack2(r2, r3);
      *(uint2*)(out + ob) = o;
    }
    __syncthreads();
  }
}

// ---------------------------------------------------------------------------
// Row L2-normalize (in place) + per-(g,c) SUM moments via global atomics.
__global__ __launch_bounds__(256) void rownorm_part(ushort* __restrict__ h,
    float* __restrict__ m1, float* __restrict__ m2)
{
  const int tid = threadIdx.x, lane = tid & 63, wave = tid >> 6;
  const int wid = blockIdx.x * 4 + wave;
  const int r0 = wid * 8;
  const int g = r0 >> 9;
  const int co = lane * 4;
  float a1[4] = {0.f, 0.f, 0.f, 0.f}, a2[4] = {0.f, 0.f, 0.f, 0.f};
  #pragma unroll
  for (int j = 0; j < 8; ++j) {
    size_t idx = ((size_t)(r0 + j)) * C_ + co;
    uint2 u = *(const uint2*)(h + idx);
    float v0 = u2f_lo(u.x), v1 = u2f_hi(u.x), v2 = u2f_lo(u.y), v3 = u2f_hi(u.y);
    float ss = v0*v0 + v1*v1 + v2*v2 + v3*v3;
    ss = wredsum(ss);
    float inv = 1.0f / fmaxf(sqrtf(ss), 1e-12f);
    v0 *= inv; v1 *= inv; v2 *= inv; v3 *= inv;
    uint2 o; o.x = pack2(v0, v1); o.y = pack2(v2, v3);
    *(uint2*)(h + idx) = o;
    a1[0] += v0; a1[1] += v1; a1[2] += v2; a1[3] += v3;
    a2[0] += v0*v0; a2[1] += v1*v1; a2[2] += v2*v2; a2[3] += v3*v3;
  }
  #pragma unroll
  for (int k = 0; k < 4; ++k) {
    atomicAdd(&m1[g*C_ + co + k], a1[k]);
    atomicAdd(&m2[g*C_ + co + k], a2[k]);
  }
}

// GraphNorm + GELU + residual. m1/m2 hold SUMS over 512 nodes.
__global__ __launch_bounds__(256) void gn_gelu_add(const ushort* __restrict__ h,
    const ushort* res,
    const float* __restrict__ m1, const float* __restrict__ m2,
    const ushort* __restrict__ gw, const ushort* __restrict__ gb, const ushort* __restrict__ ga,
    ushort* out)
{
  size_t b4 = ((size_t)blockIdx.x * 256 + threadIdx.x) * 4;
  int c = (int)(b4 & (C_ - 1));
  int n = (int)(b4 >> 8);
  int g = n >> 9;
  uint2 hv = *(const uint2*)(h + b4);
  uint2 rv = *(const uint2*)(res + b4);
  float hh[4] = {u2f_lo(hv.x), u2f_hi(hv.x), u2f_lo(hv.y), u2f_hi(hv.y)};
  float rr[4] = {u2f_lo(rv.x), u2f_hi(rv.x), u2f_lo(rv.y), u2f_hi(rv.y)};
  float oo[4];
  #pragma unroll
  for (int j = 0; j < 4; ++j) {
    int cc = c + j;
    float a  = bf2f(ga[cc]);
    float mm = m1[g*C_ + cc] * (1.0f / 512.0f);
    float q2 = m2[g*C_ + cc] * (1.0f / 512.0f);
    float var = q2 - a * (2.0f - a) * mm * mm;
    float xo = hh[j] - a * mm;
    float y = bf2f(gw[cc]) * xo * rsqrtf(var + 1e-5f) + bf2f(gb[cc]);
    oo[j] = gelu_f(y) + rr[j];
  }
  uint2 ov; ov.x = pack2(oo[0], oo[1]); ov.y = pack2(oo[2], oo[3]);
  *(uint2*)(out + b4) = ov;
}

// ---------------------------------------------------------------------------
// MFMA attention: one block (512 thr = 8 waves) per (graph, head).
#define KS_P 72
#define VT_P 520
#define PW_P 40
__global__ __launch_bounds__(512, 2) void attn_kernel(ushort* __restrict__ qkv)
{
  __shared__ ushort Ks[NP_ * KS_P];
  __shared__ ushort Vt[64 * VT_P];
  __shared__ ushort Pw[8][16 * PW_P];
  const int bid = blockIdx.x;
  const int g = bid >> 2, h = bid & 3;
  const int tid = threadIdx.x, lane = tid & 63, wave = tid >> 6;
  const int lr = lane & 15, quad = lane >> 4;
  const size_t base = (size_t)g * NP_ * C3_;
  const int qoff = h * 64, koff = C_ + h * 64, voff = 2 * C_ + h * 64;
  for (int idx = tid; idx < NP_ * 64; idx += 512) {
    int j = idx >> 6, c = idx & 63;
    const ushort* row = qkv + base + (size_t)j * C3_;
    Ks[j * KS_P + c] = row[koff + c];
    Vt[c * VT_P + j] = row[voff + c];
  }
  __syncthreads();
  ushort* pw = &Pw[wave][0];
  const int q0 = wave * 64;
  for (int qt = 0; qt < 4; ++qt) {
    const int qr = q0 + qt * 16;
    const ushort* qp = qkv + base + (size_t)(qr + lr) * C3_ + qoff + quad * 8;
    bf16x8_t qa0 = *(const bf16x8_t*)(qp);
    bf16x8_t qa1 = *(const bf16x8_t*)(qp + 32);
    f32x4_t s[32];
    #pragma unroll
    for (int t = 0; t < 32; ++t) {
      const ushort* kp = Ks + (size_t)(t * 16 + lr) * KS_P + quad * 8;
      bf16x8_t b0 = *(const bf16x8_t*)(kp);
      bf16x8_t b1 = *(const bf16x8_t*)(kp + 32);
      f32x4_t a = (f32x4_t){0.f, 0.f, 0.f, 0.f};
      a = __builtin_amdgcn_mfma_f32_16x16x32_bf16(qa0, b0, a, 0, 0, 0);
      a = __builtin_amdgcn_mfma_f32_16x16x32_bf16(qa1, b1, a, 0, 0, 0);
      s[t] = a;
    }
    float invv[4];
    #pragma unroll
    for (int r = 0; r < 4; ++r) {
      float m = s[0][r];
      #pragma unroll
      for (int t = 1; t < 32; ++t) m = fmaxf(m, s[t][r]);
      #pragma unroll
      for (int off = 8; off; off >>= 1) m = fmaxf(m, __shfl_xor(m, off, 64));
      float sm = 0.0f;
      #pragma unroll
      for (int t = 0; t < 32; ++t) {
        float e = expf((s[t][r] - m) * 0.125f);
        s[t][r] = e; sm += e;
      }
      #pragma unroll
      for (int off = 8; off; off >>= 1) sm += __shfl_xor(sm, off, 64);
      invv[r] = 1.0f / sm;
    }
    f32x4_t o[4];
    #pragma unroll
    for (int t = 0; t < 4; ++t) o[t] = (f32x4_t){0.f, 0.f, 0.f, 0.f};
    for (int kc = 0; kc < 16; ++kc) {
      #pragma unroll
      for (int half = 0; half < 2; ++half) {
        int t = kc * 2 + half;
        #pragma unroll
        for (int r = 0; r < 4; ++r)
          pw[(quad * 4 + r) * PW_P + half * 16 + lr] = f2bf(s[t][r] * invv[r]);
      }
      __threadfence_block();
      bf16x8_t pa = *(const bf16x8_t*)(pw + lr * PW_P + quad * 8);
      #pragma unroll
      for (int nt = 0; nt < 4; ++nt) {
        const ushort* vp = Vt + (size_t)(nt * 16 + lr) * VT_P + kc * 32 + quad * 8;
        bf16x8_t b = *(const bf16x8_t*)(vp);
        o[nt] = __builtin_amdgcn_mfma_f32_16x16x32_bf16(pa, b, o[nt], 0, 0, 0);
      }
    }
    #pragma unroll
    for (int nt = 0; nt < 4; ++nt)
      #pragma unroll
      for (int r = 0; r < 4; ++r)
        qkv[base + (size_t)(qr + quad * 4 + r) * C3_ + koff + nt * 16 + lr] =
            f2bf(o[nt][r]);
  }
}

// ---------------------------------------------------------------------------
// Graph-LN: partial sums (grid 128x8) -> atomics; finalize converts to mu/var.
__global__ __launch_bounds__(256) void ln_part(const ushort* __restrict__ x2, float* __restrict__ st)
{
  __shared__ float a1[4], a2[4];
  const int g = blockIdx.x, sl = blockIdx.y;
  const int tid = threadIdx.x, lane = tid & 63, wave = tid >> 6;
  const ushort* p = x2 + ((size_t)g * NP_ + sl * 64) * C_;
  float s = 0.0f, q = 0.0f;
  for (int i = tid; i < 64 * C_; i += 256) { float v = bf2f(p[i]); s += v; q += v * v; }
  s = wredsum(s); q = wredsum(q);
  if (lane == 0) { a1[wave] = s; a2[wave] = q; }
  __syncthreads();
  if (tid == 0) {
    atomicAdd(&st[g * 2],     a1[0] + a1[1] + a1[2] + a1[3]);
    atomicAdd(&st[g * 2 + 1], a2[0] + a2[1] + a2[2] + a2[3]);
  }
}

__global__ void ln_finalize(float* __restrict__ st)
{
  int g = threadIdx.x;
  float S = st[g * 2], Q = st[g * 2 + 1];
  float mu = S * (1.0f / (NP_ * C_));
  float var = Q * (1.0f / (NP_ * C_)) - mu * mu;
  st[g * 2] = mu; st[g * 2 + 1] = var;
}

__global__ __launch_bounds__(256) void ln_gelu(const ushort* __restrict__ x2, const float* __restrict__ st,
    const ushort* __restrict__ lw, const ushort* __restrict__ lb, ushort* __restrict__ x3)
{
  size_t b4 = ((size_t)blockIdx.x * 256 + threadIdx.x) * 4;
  int c = (int)(b4 & (C_ - 1));
  int n = (int)(b4 >> 8);
  int g = n >> 9;
  float mu = st[g * 2], var = st[g * 2 + 1];
  float rs = rsqrtf(var + 1e-5f);
  uint2 v = *(const uint2*)(x2 + b4);
  float vv[4] = {u2f_lo(v.x), u2f_hi(v.x), u2f_lo(v.y), u2f_hi(v.y)};
  float oo[4];
  #pragma unroll
  for (int j = 0; j < 4; ++j) {
    int cc = c + j;
    float y = (vv[j] - mu) * rs * bf2f(lw[cc]) + bf2f(lb[cc]);
    oo[j] = gelu_f(y);
  }
  uint2 ov; ov.x = pack2(oo[0], oo[1]); ov.y = pack2(oo[2], oo[3]);
  *(uint2*)(x3 + b4) = ov;
}

// ---------------------------------------------------------------------------
// Pool: per-slice partials (grid 128x8) then combine.
__global__ __launch_bounds__(256) void pool_part(const ushort* __restrict__ x3,
    float* __restrict__ psum, float* __restrict__ pmax)
{
  const int g = blockIdx.x, sl = blockIdx.y, c = threadIdx.x;
  const ushort* p = x3 + ((size_t)g * NP_ + sl * 64) * C_ + c;
  float s = 0.0f, mx = -3.0e38f;
  #pragma unroll 4
  for (int r = 0; r < 64; ++r) {
    float v = bf2f(p[(size_t)r * C_]);
    s += v; mx = fmaxf(mx, v);
  }
  psum[((size_t)g * 8 + sl) * C_ + c] = s;
  pmax[((size_t)g * 8 + sl) * C_ + c] = mx;
}

__global__ __launch_bounds__(256) void pool_final(const float* __restrict__ psum,
    const float* __restrict__ pmax, float* __restrict__ pooled)
{
  const int g = blockIdx.x, c = threadIdx.x;
  float s = 0.0f, mx = -3.0e38f;
  #pragma unroll
  for (int sl = 0; sl < 8; ++sl) {
    s += psum[((size_t)g * 8 + sl) * C_ + c];
    mx = fmaxf(mx, pmax[((size_t)g * 8 + sl) * C_ + c]);
  }
  pooled[(size_t)g * C3_ + c]        = s * (1.0f / 512.0f);
  pooled[(size_t)g * C3_ + C_ + c]   = mx;
  pooled[(size_t)g * C3_ + 2*C_ + c] = s;
}

__global__ __launch_bounds__(256) void final_gemm(const float* __restrict__ pooled,
    const ushort* __restrict__ W, const ushort* __restrict__ b, void* __restrict__ out,
    const uint* __restrict__ flag)
{
  const int g = blockIdx.x, c = threadIdx.x;
  float acc = bf2f(b[c]);
  const float* p = pooled + (size_t)g * C3_;
  for (int k = 0; k < C3_; ++k) acc += p[k] * bf2f(W[(size_t)c * C3_ + k]);
  if (*flag) ((float*)out)[g * C_ + c] = acc;
  else       ((ushort*)out)[g * C_ + c] = f2bf(acc);
}

// ---------------------------------------------------------------------------
extern "C" void kernel_launch(void* const* d_in, const int* in_sizes, int n_in,
                              void* d_out, int out_size, void* d_ws, size_t ws_size,
                              hipStream_t stream)
{
  const int* ei   = (const int*)d_in[1];
  const int* srcp = ei;
  const int* dstp = ei + E_TOT;

  const size_t NC = (size_t)N_TOT * C_;                        // 16,777,216
  const size_t NEEDED = (4ull << 20) + 4 * NC * sizeof(ushort); // 132 MB
  if (ws_size < NEEDED) return;

  unsigned char* wsb = (unsigned char*)d_ws;
  uint*   deg    = (uint*)wsb;
  float*  m1     = (float*)(wsb + (256u << 10));
  float*  m2     = (float*)(wsb + (384u << 10));
  float*  lst    = (float*)(wsb + (512u << 10));
  uint*   flag   = (uint*)(wsb + (516u << 10));
  float*  pooled = (float*)(wsb + (520u << 10));
  ushort* PB     = (ushort*)(wsb + (1u << 20));       // param pool bf16
  ushort* S0     = (ushort*)(wsb + (4u << 20));       // x1
  ushort* S1     = S0 + NC;
  ushort* S2     = S1 + NC;
  ushort* S3     = S2 + NC;
  ushort* qkvb   = S1;                                // [N][768] overlay
  ushort* XB     = S3;                                // x bf16 (lower 16MB of S3)
  unsigned char* s3hi = (unsigned char*)(S3 + (size_t)N_TOT * DIN_);
  int*  csr    = (int*)s3hi;                          // 2 MB
  uint* rowptr = (uint*)(s3hi + (2u << 20));          // 256 KB
  uint* cursor = (uint*)(s3hi + (2u << 20) + (256u << 10));
  float* psum  = (float*)S2;                          // pool partials (S2 dead then)
  float* pmax  = psum + (size_t)B_GR * 8 * C_;

  // ---- dtype probe + import ----
  probe_dtype<<<1, 1, 0, stream>>>((const uint*)d_in[10], flag);
  CvtArgs ca;
  ca.s[0]  = { d_in[3],  O_L0LW };  ca.s[1]  = { d_in[4],  O_L0LB };
  ca.s[2]  = { d_in[5],  O_L0RW };  ca.s[3]  = { d_in[6],  O_L0RES };
  ca.s[4]  = { d_in[7],  O_LWL  };  ca.s[5]  = { d_in[8],  O_LBL  };
  ca.s[6]  = { d_in[9],  O_LWR  };  ca.s[7]  = { d_in[10], O_GNW  };
  ca.s[8]  = { d_in[11], O_GNB  };  ca.s[9]  = { d_in[12], O_GNA  };
  ca.s[10] = { d_in[13], O_AIW  };  ca.s[11] = { d_in[14], O_AIB  };
  ca.s[12] = { d_in[15], O_AOW  };  ca.s[13] = { d_in[16], O_AOB  };
  ca.s[14] = { d_in[17], O_LNW  };  ca.s[15] = { d_in[18], O_LNB  };
  ca.s[16] = { d_in[19], O_PLW  };  ca.s[17] = { d_in[20], O_PLB  };
  ca.s[18] = { nullptr,  TOTALP };
  cvt_params<<<(TOTALP + 255) / 256, 256, 0, stream>>>(ca, PB, flag);
  cvt_flat<<<(N_TOT * DIN_) / 256, 256, 0, stream>>>(d_in[0], XB, flag);

  // ---- degree + CSR build ----
  hipMemsetAsync(deg, 0, N_TOT * sizeof(uint), stream);
  hipMemsetAsync(wsb + (512u << 10), 0, 1024, stream);           // lst
  deg_count<<<E_TOT / 256, 256, 0, stream>>>(dstp, deg);
  scan_deg<<<B_GR, 512, 0, stream>>>(deg, rowptr, cursor);
  scatter_edges<<<E_TOT / 256, 256, 0, stream>>>(srcp, dstp, cursor, csr);

  // ---- layer 0 (DIN=128 -> C=256) ----
  sage_agg_csr<DIN_><<<N_TOT / 4, 256, 0, stream>>>(XB, csr, rowptr, deg, S1);
  gemm_mfma<true><<<dim3(N_TOT / 64, 1), 256, 0, stream>>>(
      S1, DIN_, PB + O_L0LW, XB, DIN_, PB + O_L0RW, PB + O_L0LB, nullptr, S2, DIN_, C_);
  gemm_mfma<false><<<dim3(N_TOT / 64, 1), 256, 0, stream>>>(
      XB, DIN_, PB + O_L0RES, nullptr, 0, nullptr, nullptr, nullptr, S0, DIN_, C_);
  hipMemsetAsync(wsb + (256u << 10), 0, 256u << 10, stream);     // m1+m2
  rownorm_part<<<N_TOT / 32, 256, 0, stream>>>(S2, m1, m2);
  gn_gelu_add<<<(N_TOT * C_) / 1024, 256, 0, stream>>>(S2, S0, m1, m2,
      PB + O_GNW, PB + O_GNB, PB + O_GNA, S0);

  // ---- layers 1..3 (C -> C) ----
  for (int i = 0; i < 3; ++i) {
    sage_agg_csr<C_><<<N_TOT / 4, 256, 0, stream>>>(S0, csr, rowptr, deg, S1);
    gemm_mfma<true><<<dim3(N_TOT / 64, 1), 256, 0, stream>>>(
        S1, C_, PB + O_LWL + (size_t)i * C_ * C_, S0, C_, PB + O_LWR + (size_t)i * C_ * C_,
        PB + O_LBL + i * C_, nullptr, S2, C_, C_);
    hipMemsetAsync(wsb + (256u << 10), 0, 256u << 10, stream);   // m1+m2
    rownorm_part<<<N_TOT / 32, 256, 0, stream>>>(S2, m1, m2);
    gn_gelu_add<<<(N_TOT * C_) / 1024, 256, 0, stream>>>(S2, S0, m1, m2,
        PB + O_GNW + (i + 1) * C_, PB + O_GNB + (i + 1) * C_, PB + O_GNA + (i + 1) * C_, S0);
  }

  // ---- attention ----
  gemm_mfma<false><<<dim3(N_TOT / 64, 3), 256, 0, stream>>>(
      S0, C_, PB + O_AIW, nullptr, 0, nullptr, PB + O_AIB, nullptr, qkvb, C_, C3_);
  attn_kernel<<<B_GR * H_, 512, 0, stream>>>(qkvb);
  gemm_mfma<false><<<dim3(N_TOT / 64, 1), 256, 0, stream>>>(
      qkvb + C_, C3_, PB + O_AOW, nullptr, 0, nullptr, PB + O_AOB, S0, S0, C_, C_);

  // ---- graph LayerNorm + gelu ----
  ln_part<<<dim3(B_GR, 8), 256, 0, stream>>>(S0, lst);
  ln_finalize<<<1, B_GR, 0, stream>>>(lst);
  ln_gelu<<<(N_TOT * C_) / 1024, 256, 0, stream>>>(S0, lst, PB + O_LNW, PB + O_LNB, S1);

  // ---- pool + projection ----
  pool_part<<<dim3(B_GR, 8), 256, 0, stream>>>(S1, psum, pmax);
  pool_final<<<B_GR, 256, 0, stream>>>(psum, pmax, pooled);
  final_gemm<<<B_GR, 256, 0, stream>>>(pooled, PB + O_PLW, PB + O_PLB, d_out, flag);
}

// Round 9
// 1206.569 us; speedup vs baseline: 6.8314x; 1.1511x over previous
//
#include <hip/hip_runtime.h>

// ---------------------------------------------------------------------------
// GraphSAGE GNN forward, MI355X round 9:
//  - rownorm (SAGE L2-normalize + GraphNorm moments) fused into GEMM epilogue
//  - A-stream register prefetch in GEMM K-loop
//  - __expf in attention softmax
// ---------------------------------------------------------------------------

#define N_TOT   65536
#define B_GR    128
#define NP_     512
#define E_TOT   524288
#define EPG     4096
#define DIN_    128
#define C_      256
#define C3_     768
#define H_      4

typedef unsigned int uint;
typedef unsigned short ushort;

// param pool element offsets (ushorts)
#define O_L0LW  0u
#define O_L0LB  32768u
#define O_L0RW  33024u
#define O_L0RES 65792u
#define O_LWL   98560u
#define O_LBL   295168u
#define O_LWR   295936u
#define O_GNW   492544u
#define O_GNB   493568u
#define O_GNA   494592u
#define O_AIW   495616u
#define O_AIB   692224u
#define O_AOW   692992u
#define O_AOB   758528u
#define O_LNW   758784u
#define O_LNB   759040u
#define O_PLW   759296u
#define O_PLB   955904u
#define TOTALP  956160u

typedef __attribute__((ext_vector_type(8))) short bf16x8_t;
typedef __attribute__((ext_vector_type(4))) float f32x4_t;

__device__ __forceinline__ float bf2f(ushort u){ union{uint i; float f;} v; v.i = ((uint)u) << 16; return v.f; }
__device__ __forceinline__ ushort f2bf(float f){
  union{float f; uint u;} v; v.f = f;
  uint u = v.u;
  u += 0x7fffu + ((u >> 16) & 1u);   // RNE
  return (ushort)(u >> 16);
}
__device__ __forceinline__ uint pack2(float a, float b){ return (uint)f2bf(a) | ((uint)f2bf(b) << 16); }
__device__ __forceinline__ float u2f_lo(uint u){ union{uint i; float f;} v; v.i = u << 16; return v.f; }
__device__ __forceinline__ float u2f_hi(uint u){ union{uint i; float f;} v; v.i = u & 0xffff0000u; return v.f; }
__device__ __forceinline__ float gelu_f(float x){ return 0.5f * x * (1.0f + erff(x * 0.70710678118654752440f)); }
__device__ __forceinline__ float wredsum(float v){
  #pragma unroll
  for (int off = 32; off; off >>= 1) v += __shfl_xor(v, off, 64);
  return v;
}

// ---------------------------------------------------------------------------
// dtype probe: gn_w[0]==1.0. f32 -> 0x3F800000 ; bf16 pair -> 0x3F803F80
__global__ void probe_dtype(const uint* __restrict__ gnw_raw, uint* __restrict__ flag){
  if (threadIdx.x == 0 && blockIdx.x == 0)
    *flag = (gnw_raw[0] == 0x3F800000u) ? 1u : 0u;   // 1 = f32 inputs
}

struct Seg { const void* p; uint ofs; };
struct CvtArgs { Seg s[19]; };

__global__ __launch_bounds__(256) void cvt_params(CvtArgs a, ushort* __restrict__ pb,
                                                  const uint* __restrict__ flag){
  uint gi = blockIdx.x * 256u + threadIdx.x;
  if (gi >= TOTALP) return;
  int lo = 0;
  #pragma unroll
  for (int s = 1; s < 18; ++s) if (gi >= a.s[s].ofs) lo = s;
  uint rel = gi - a.s[lo].ofs;
  pb[gi] = (*flag) ? f2bf(((const float*)a.s[lo].p)[rel]) : ((const ushort*)a.s[lo].p)[rel];
}

__global__ __launch_bounds__(256) void cvt_flat(const void* __restrict__ in, ushort* __restrict__ out,
                                                const uint* __restrict__ flag){
  uint i = blockIdx.x * 256u + threadIdx.x;
  out[i] = (*flag) ? f2bf(((const float*)in)[i]) : ((const ushort*)in)[i];
}

// ---------------------------------------------------------------------------
__global__ void deg_count(const int* __restrict__ dst, uint* __restrict__ deg){
  int e = blockIdx.x * 256 + threadIdx.x;
  atomicAdd(&deg[dst[e]], 1u);
}

// per-graph exclusive scan of deg (512 nodes) -> rowptr/cursor
__global__ __launch_bounds__(512) void scan_deg(const uint* __restrict__ deg,
    uint* __restrict__ rowptr, uint* __restrict__ cursor)
{
  __shared__ uint s[512];
  const int g = blockIdx.x, tid = threadIdx.x;
  uint v = deg[g * NP_ + tid];
  s[tid] = v;
  __syncthreads();
  #pragma unroll
  for (int off = 1; off < 512; off <<= 1) {
    uint t = (tid >= off) ? s[tid - off] : 0u;
    __syncthreads();
    s[tid] += t;
    __syncthreads();
  }
  uint p = g * EPG + (s[tid] - v);
  rowptr[g * NP_ + tid] = p;
  cursor[g * NP_ + tid] = p;
}

__global__ void scatter_edges(const int* __restrict__ src, const int* __restrict__ dst,
    uint* __restrict__ cursor, int* __restrict__ csr)
{
  int e = blockIdx.x * 256 + threadIdx.x;
  uint p = atomicAdd(&cursor[dst[e]], 1u);
  csr[p] = src[e];
}

// ---------------------------------------------------------------------------
// CSR mean-aggregation: one wave per node. Lane owns D/64 channels.
template<int D>
__global__ __launch_bounds__(256) void sage_agg_csr(const ushort* __restrict__ X,
    const int* __restrict__ csr, const uint* __restrict__ rowptr,
    const uint* __restrict__ deg, ushort* __restrict__ agg)
{
  constexpr int CPL = D / 64;
  const int tid = threadIdx.x, lane = tid & 63, wave = tid >> 6;
  const int n = blockIdx.x * 4 + wave;
  const uint start = rowptr[n];
  const uint dg = deg[n];
  const int co = lane * CPL;
  float acc[CPL];
  #pragma unroll
  for (int k = 0; k < CPL; ++k) acc[k] = 0.0f;

  auto addrow = [&](int s) {
    const ushort* r = X + (size_t)s * D + co;
    if constexpr (CPL == 2) {
      uint u = *(const uint*)r;
      acc[0] += u2f_lo(u); acc[1] += u2f_hi(u);
    } else {
      uint2 u = *(const uint2*)r;
      acc[0] += u2f_lo(u.x); acc[1] += u2f_hi(u.x);
      acc[2] += u2f_lo(u.y); acc[3] += u2f_hi(u.y);
    }
  };

  uint j = 0;
  for (; j + 4 <= dg; j += 4) {
    int s0 = csr[start + j],     s1 = csr[start + j + 1];
    int s2 = csr[start + j + 2], s3 = csr[start + j + 3];
    addrow(s0); addrow(s1); addrow(s2); addrow(s3);
  }
  for (; j < dg; ++j) addrow(csr[start + j]);

  float inv = 1.0f / (float)(dg < 1u ? 1u : dg);
  ushort* op = agg + (size_t)n * D + co;
  if constexpr (CPL == 2) {
    *(uint*)op = pack2(acc[0] * inv, acc[1] * inv);
  } else {
    uint2 o; o.x = pack2(acc[0] * inv, acc[1] * inv);
    o.y = pack2(acc[2] * inv, acc[3] * inv);
    *(uint2*)op = o;
  }
}

// ---------------------------------------------------------------------------
// MFMA GEMM v3: 64x256 block, 4 waves, wave = 64x64. A-stream prefetched.
// RN=true: fused SAGE row-L2-normalize + GraphNorm moment atomics (requires
// full rows in block: ldOut == 256, blockIdx.y == 0, bias != null, no addend).
template<bool DUAL, bool RN>
__global__ __launch_bounds__(256, 4) void gemm_mfma(
    const ushort* __restrict__ A1, int lda1, const ushort* __restrict__ W1,
    const ushort* __restrict__ A2, int lda2, const ushort* __restrict__ W2,
    const ushort* __restrict__ bias, const ushort* addend,   // addend may alias out
    ushort* out, int K, int ldOut,
    float* __restrict__ m1, float* __restrict__ m2)
{
  __shared__ float Cs[4][32 * 68];
  __shared__ float SSq[32];
  const int lane = threadIdx.x & 63, wave = threadIdx.x >> 6;
  const int lr = lane & 15, quad = lane >> 4;
  const int m0 = blockIdx.x * 64;
  const int n0 = blockIdx.y * 256 + wave * 64;
  f32x4_t acc[4][4];
  #pragma unroll
  for (int rt = 0; rt < 4; ++rt)
    #pragma unroll
    for (int ct = 0; ct < 4; ++ct) acc[rt][ct] = (f32x4_t){0.f, 0.f, 0.f, 0.f};
  {
    const ushort* ap = A1 + (size_t)(m0 + lr) * lda1 + quad * 8;
    const ushort* wp = W1 + (size_t)(n0 + lr) * K + quad * 8;
    bf16x8_t a[4];
    #pragma unroll
    for (int rt = 0; rt < 4; ++rt) a[rt] = *(const bf16x8_t*)(ap + (size_t)(rt * 16) * lda1);
    for (int kb = 0; kb < K; kb += 32) {
      int kn = (kb + 32 < K) ? kb + 32 : kb;
      bf16x8_t b[4], an[4];
      #pragma unroll
      for (int ct = 0; ct < 4; ++ct) b[ct] = *(const bf16x8_t*)(wp + (size_t)(ct * 16) * K + kb);
      #pragma unroll
      for (int rt = 0; rt < 4; ++rt) an[rt] = *(const bf16x8_t*)(ap + (size_t)(rt * 16) * lda1 + kn);
      #pragma unroll
      for (int rt = 0; rt < 4; ++rt)
        #pragma unroll
        for (int ct = 0; ct < 4; ++ct)
          acc[rt][ct] = __builtin_amdgcn_mfma_f32_16x16x32_bf16(a[rt], b[ct], acc[rt][ct], 0, 0, 0);
      #pragma unroll
      for (int rt = 0; rt < 4; ++rt) a[rt] = an[rt];
    }
  }
  if constexpr (DUAL) {
    const ushort* ap = A2 + (size_t)(m0 + lr) * lda2 + quad * 8;
    const ushort* wp = W2 + (size_t)(n0 + lr) * K + quad * 8;
    bf16x8_t a[4];
    #pragma unroll
    for (int rt = 0; rt < 4; ++rt) a[rt] = *(const bf16x8_t*)(ap + (size_t)(rt * 16) * lda2);
    for (int kb = 0; kb < K; kb += 32) {
      int kn = (kb + 32 < K) ? kb + 32 : kb;
      bf16x8_t b[4], an[4];
      #pragma unroll
      for (int ct = 0; ct < 4; ++ct) b[ct] = *(const bf16x8_t*)(wp + (size_t)(ct * 16) * K + kb);
      #pragma unroll
      for (int rt = 0; rt < 4; ++rt) an[rt] = *(const bf16x8_t*)(ap + (size_t)(rt * 16) * lda2 + kn);
      #pragma unroll
      for (int rt = 0; rt < 4; ++rt)
        #pragma unroll
        for (int ct = 0; ct < 4; ++ct)
          acc[rt][ct] = __builtin_amdgcn_mfma_f32_16x16x32_bf16(a[rt], b[ct], acc[rt][ct], 0, 0, 0);
      #pragma unroll
      for (int rt = 0; rt < 4; ++rt) a[rt] = an[rt];
    }
  }
  // ---- epilogue ----
  const int cb = lr * 4;                     // col base within wave's 64
  float bv[4] = {0.f, 0.f, 0.f, 0.f};
  if (bias) {
    #pragma unroll
    for (int j = 0; j < 4; ++j) bv[j] = bf2f(bias[n0 + cb + j]);
  }
  float* cs = &Cs[wave][0];
  float a1s[4] = {0.f, 0.f, 0.f, 0.f}, a2s[4] = {0.f, 0.f, 0.f, 0.f};
  #pragma unroll
  for (int round = 0; round < 2; ++round) {
    // stage acc (+bias for RN: bias precedes normalization)
    #pragma unroll
    for (int rt2 = 0; rt2 < 2; ++rt2) {
      int rt = round * 2 + rt2;
      #pragma unroll
      for (int ct = 0; ct < 4; ++ct)
        #pragma unroll
        for (int r = 0; r < 4; ++r) {
          float v = acc[rt][ct][r];
          if constexpr (RN) v += bias ? bf2f(bias[n0 + ct * 16 + lr]) : 0.0f;
          cs[(rt2 * 16 + quad * 4 + r) * 68 + ct * 16 + lr] = v;
        }
    }
    if constexpr (RN) { if (threadIdx.x < 32) SSq[threadIdx.x] = 0.0f; }
    __syncthreads();
    if constexpr (RN) {
      // per-row sum of squares (this wave's 64 cols), quad-reduce, LDS atomic
      #pragma unroll
      for (int it = 0; it < 8; ++it) {
        int Lr = it * 4 + quad;
        float4 v = *(const float4*)(cs + Lr * 68 + cb);
        float ss = v.x*v.x + v.y*v.y + v.z*v.z + v.w*v.w;
        #pragma unroll
        for (int off = 1; off < 16; off <<= 1) ss += __shfl_xor(ss, off, 64);
        if (lr == 0) atomicAdd(&SSq[Lr], ss);
      }
      __syncthreads();
      #pragma unroll
      for (int it = 0; it < 8; ++it) {
        int Lr = it * 4 + quad;
        float inv = 1.0f / fmaxf(sqrtf(SSq[Lr]), 1e-12f);
        float4 v = *(const float4*)(cs + Lr * 68 + cb);
        float r0 = v.x * inv, r1 = v.y * inv, r2 = v.z * inv, r3 = v.w * inv;
        a1s[0] += r0; a1s[1] += r1; a1s[2] += r2; a1s[3] += r3;
        a2s[0] += r0*r0; a2s[1] += r1*r1; a2s[2] += r2*r2; a2s[3] += r3*r3;
        size_t ob = (size_t)(m0 + round * 32 + Lr) * ldOut + n0 + cb;
        uint2 o; o.x = pack2(r0, r1); o.y = pack2(r2, r3);
        *(uint2*)(out + ob) = o;
      }
    } else {
      #pragma unroll
      for (int it = 0; it < 8; ++it) {
        int Lr = it * 4 + quad;
        float4 v = *(const float4*)(cs + Lr * 68 + cb);
        int grow = m0 + round * 32 + Lr;
        size_t ob = (size_t)grow * ldOut + n0 + cb;
        float r0 = v.x + bv[0], r1 = v.y + bv[1], r2 = v.z + bv[2], r3 = v.w + bv[3];
        if (addend) {
          uint2 ad = *(const uint2*)(addend + ob);
          r0 += u2f_lo(ad.x); r1 += u2f_hi(ad.x);
          r2 += u2f_lo(ad.y); r3 += u2f_hi(ad.y);
        }
        uint2 o; o.x = pack2(r0, r1); o.y = pack2(r2, r3);
        *(uint2*)(out + ob) = o;
      }
    }
    __syncthreads();
  }
  if constexpr (RN) {
    const int g = m0 >> 9;
    #pragma unroll
    for (int k = 0; k < 4; ++k) {
      atomicAdd(&m1[g*C_ + n0 + cb + k], a1s[k]);
      atomicAdd(&m2[g*C_ + n0 + cb + k], a2s[k]);
    }
  }
}

// GraphNorm + GELU + residual. m1/m2 hold SUMS over 512 nodes.
__global__ __launch_bounds__(256) void gn_gelu_add(const ushort* __restrict__ h,
    const ushort* res,
    const float* __restrict__ m1, const float* __restrict__ m2,
    const ushort* __restrict__ gw, const ushort* __restrict__ gb, const ushort* __restrict__ ga,
    ushort* out)
{
  size_t b4 = ((size_t)blockIdx.x * 256 + threadIdx.x) * 4;
  int c = (int)(b4 & (C_ - 1));
  int n = (int)(b4 >> 8);
  int g = n >> 9;
  uint2 hv = *(const uint2*)(h + b4);
  uint2 rv = *(const uint2*)(res + b4);
  float hh[4] = {u2f_lo(hv.x), u2f_hi(hv.x), u2f_lo(hv.y), u2f_hi(hv.y)};
  float rr[4] = {u2f_lo(rv.x), u2f_hi(rv.x), u2f_lo(rv.y), u2f_hi(rv.y)};
  float oo[4];
  #pragma unroll
  for (int j = 0; j < 4; ++j) {
    int cc = c + j;
    float a  = bf2f(ga[cc]);
    float mm = m1[g*C_ + cc] * (1.0f / 512.0f);
    float q2 = m2[g*C_ + cc] * (1.0f / 512.0f);
    float var = q2 - a * (2.0f - a) * mm * mm;
    float xo = hh[j] - a * mm;
    float y = bf2f(gw[cc]) * xo * rsqrtf(var + 1e-5f) + bf2f(gb[cc]);
    oo[j] = gelu_f(y) + rr[j];
  }
  uint2 ov; ov.x = pack2(oo[0], oo[1]); ov.y = pack2(oo[2], oo[3]);
  *(uint2*)(out + b4) = ov;
}

// ---------------------------------------------------------------------------
// MFMA attention: one block (512 thr = 8 waves) per (graph, head).
#define KS_P 72
#define VT_P 520
#define PW_P 40
__global__ __launch_bounds__(512, 2) void attn_kernel(ushort* __restrict__ qkv)
{
  __shared__ ushort Ks[NP_ * KS_P];
  __shared__ ushort Vt[64 * VT_P];
  __shared__ ushort Pw[8][16 * PW_P];
  const int bid = blockIdx.x;
  const int g = bid >> 2, h = bid & 3;
  const int tid = threadIdx.x, lane = tid & 63, wave = tid >> 6;
  const int lr = lane & 15, quad = lane >> 4;
  const size_t base = (size_t)g * NP_ * C3_;
  const int qoff = h * 64, koff = C_ + h * 64, voff = 2 * C_ + h * 64;
  for (int idx = tid; idx < NP_ * 64; idx += 512) {
    int j = idx >> 6, c = idx & 63;
    const ushort* row = qkv + base + (size_t)j * C3_;
    Ks[j * KS_P + c] = row[koff + c];
    Vt[c * VT_P + j] = row[voff + c];
  }
  __syncthreads();
  ushort* pw = &Pw[wave][0];
  const int q0 = wave * 64;
  for (int qt = 0; qt < 4; ++qt) {
    const int qr = q0 + qt * 16;
    const ushort* qp = qkv + base + (size_t)(qr + lr) * C3_ + qoff + quad * 8;
    bf16x8_t qa0 = *(const bf16x8_t*)(qp);
    bf16x8_t qa1 = *(const bf16x8_t*)(qp + 32);
    f32x4_t s[32];
    #pragma unroll
    for (int t = 0; t < 32; ++t) {
      const ushort* kp = Ks + (size_t)(t * 16 + lr) * KS_P + quad * 8;
      bf16x8_t b0 = *(const bf16x8_t*)(kp);
      bf16x8_t b1 = *(const bf16x8_t*)(kp + 32);
      f32x4_t a = (f32x4_t){0.f, 0.f, 0.f, 0.f};
      a = __builtin_amdgcn_mfma_f32_16x16x32_bf16(qa0, b0, a, 0, 0, 0);
      a = __builtin_amdgcn_mfma_f32_16x16x32_bf16(qa1, b1, a, 0, 0, 0);
      s[t] = a;
    }
    float invv[4];
    #pragma unroll
    for (int r = 0; r < 4; ++r) {
      float m = s[0][r];
      #pragma unroll
      for (int t = 1; t < 32; ++t) m = fmaxf(m, s[t][r]);
      #pragma unroll
      for (int off = 8; off; off >>= 1) m = fmaxf(m, __shfl_xor(m, off, 64));
      float sm = 0.0f;
      #pragma unroll
      for (int t = 0; t < 32; ++t) {
        float e = __expf((s[t][r] - m) * 0.125f);
        s[t][r] = e; sm += e;
      }
      #pragma unroll
      for (int off = 8; off; off >>= 1) sm += __shfl_xor(sm, off, 64);
      invv[r] = 1.0f / sm;
    }
    f32x4_t o[4];
    #pragma unroll
    for (int t = 0; t < 4; ++t) o[t] = (f32x4_t){0.f, 0.f, 0.f, 0.f};
    for (int kc = 0; kc < 16; ++kc) {
      #pragma unroll
      for (int half = 0; half < 2; ++half) {
        int t = kc * 2 + half;
        #pragma unroll
        for (int r = 0; r < 4; ++r)
          pw[(quad * 4 + r) * PW_P + half * 16 + lr] = f2bf(s[t][r] * invv[r]);
      }
      __threadfence_block();
      bf16x8_t pa = *(const bf16x8_t*)(pw + lr * PW_P + quad * 8);
      #pragma unroll
      for (int nt = 0; nt < 4; ++nt) {
        const ushort* vp = Vt + (size_t)(nt * 16 + lr) * VT_P + kc * 32 + quad * 8;
        bf16x8_t b = *(const bf16x8_t*)(vp);
        o[nt] = __builtin_amdgcn_mfma_f32_16x16x32_bf16(pa, b, o[nt], 0, 0, 0);
      }
    }
    #pragma unroll
    for (int nt = 0; nt < 4; ++nt)
      #pragma unroll
      for (int r = 0; r < 4; ++r)
        qkv[base + (size_t)(qr + quad * 4 + r) * C3_ + koff + nt * 16 + lr] =
            f2bf(o[nt][r]);
  }
}

// ---------------------------------------------------------------------------
// Graph-LN: partial sums (grid 128x8) -> atomics; finalize converts to mu/var.
__global__ __launch_bounds__(256) void ln_part(const ushort* __restrict__ x2, float* __restrict__ st)
{
  __shared__ float a1[4], a2[4];
  const int g = blockIdx.x, sl = blockIdx.y;
  const int tid = threadIdx.x, lane = tid & 63, wave = tid >> 6;
  const ushort* p = x2 + ((size_t)g * NP_ + sl * 64) * C_;
  float s = 0.0f, q = 0.0f;
  for (int i = tid; i < 64 * C_; i += 256) { float v = bf2f(p[i]); s += v; q += v * v; }
  s = wredsum(s); q = wredsum(q);
  if (lane == 0) { a1[wave] = s; a2[wave] = q; }
  __syncthreads();
  if (tid == 0) {
    atomicAdd(&st[g * 2],     a1[0] + a1[1] + a1[2] + a1[3]);
    atomicAdd(&st[g * 2 + 1], a2[0] + a2[1] + a2[2] + a2[3]);
  }
}

__global__ void ln_finalize(float* __restrict__ st)
{
  int g = threadIdx.x;
  float S = st[g * 2], Q = st[g * 2 + 1];
  float mu = S * (1.0f / (NP_ * C_));
  float var = Q * (1.0f / (NP_ * C_)) - mu * mu;
  st[g * 2] = mu; st[g * 2 + 1] = var;
}

__global__ __launch_bounds__(256) void ln_gelu(const ushort* __restrict__ x2, const float* __restrict__ st,
    const ushort* __restrict__ lw, const ushort* __restrict__ lb, ushort* __restrict__ x3)
{
  size_t b4 = ((size_t)blockIdx.x * 256 + threadIdx.x) * 4;
  int c = (int)(b4 & (C_ - 1));
  int n = (int)(b4 >> 8);
  int g = n >> 9;
  float mu = st[g * 2], var = st[g * 2 + 1];
  float rs = rsqrtf(var + 1e-5f);
  uint2 v = *(const uint2*)(x2 + b4);
  float vv[4] = {u2f_lo(v.x), u2f_hi(v.x), u2f_lo(v.y), u2f_hi(v.y)};
  float oo[4];
  #pragma unroll
  for (int j = 0; j < 4; ++j) {
    int cc = c + j;
    float y = (vv[j] - mu) * rs * bf2f(lw[cc]) + bf2f(lb[cc]);
    oo[j] = gelu_f(y);
  }
  uint2 ov; ov.x = pack2(oo[0], oo[1]); ov.y = pack2(oo[2], oo[3]);
  *(uint2*)(x3 + b4) = ov;
}

// ---------------------------------------------------------------------------
// Pool: per-slice partials (grid 128x8) then combine.
__global__ __launch_bounds__(256) void pool_part(const ushort* __restrict__ x3,
    float* __restrict__ psum, float* __restrict__ pmax)
{
  const int g = blockIdx.x, sl = blockIdx.y, c = threadIdx.x;
  const ushort* p = x3 + ((size_t)g * NP_ + sl * 64) * C_ + c;
  float s = 0.0f, mx = -3.0e38f;
  #pragma unroll 4
  for (int r = 0; r < 64; ++r) {
    float v = bf2f(p[(size_t)r * C_]);
    s += v; mx = fmaxf(mx, v);
  }
  psum[((size_t)g * 8 + sl) * C_ + c] = s;
  pmax[((size_t)g * 8 + sl) * C_ + c] = mx;
}

__global__ __launch_bounds__(256) void pool_final(const float* __restrict__ psum,
    const float* __restrict__ pmax, float* __restrict__ pooled)
{
  const int g = blockIdx.x, c = threadIdx.x;
  float s = 0.0f, mx = -3.0e38f;
  #pragma unroll
  for (int sl = 0; sl < 8; ++sl) {
    s += psum[((size_t)g * 8 + sl) * C_ + c];
    mx = fmaxf(mx, pmax[((size_t)g * 8 + sl) * C_ + c]);
  }
  pooled[(size_t)g * C3_ + c]        = s * (1.0f / 512.0f);
  pooled[(size_t)g * C3_ + C_ + c]   = mx;
  pooled[(size_t)g * C3_ + 2*C_ + c] = s;
}

__global__ __launch_bounds__(256) void final_gemm(const float* __restrict__ pooled,
    const ushort* __restrict__ W, const ushort* __restrict__ b, void* __restrict__ out,
    const uint* __restrict__ flag)
{
  const int g = blockIdx.x, c = threadIdx.x;
  float acc = bf2f(b[c]);
  const float* p = pooled + (size_t)g * C3_;
  for (int k = 0; k < C3_; ++k) acc += p[k] * bf2f(W[(size_t)c * C3_ + k]);
  if (*flag) ((float*)out)[g * C_ + c] = acc;
  else       ((ushort*)out)[g * C_ + c] = f2bf(acc);
}

// ---------------------------------------------------------------------------
extern "C" void kernel_launch(void* const* d_in, const int* in_sizes, int n_in,
                              void* d_out, int out_size, void* d_ws, size_t ws_size,
                              hipStream_t stream)
{
  const int* ei   = (const int*)d_in[1];
  const int* srcp = ei;
  const int* dstp = ei + E_TOT;

  const size_t NC = (size_t)N_TOT * C_;                        // 16,777,216
  const size_t NEEDED = (4ull << 20) + 4 * NC * sizeof(ushort); // 132 MB
  if (ws_size < NEEDED) return;

  unsigned char* wsb = (unsigned char*)d_ws;
  uint*   deg    = (uint*)wsb;
  float*  m1     = (float*)(wsb + (256u << 10));
  float*  m2     = (float*)(wsb + (384u << 10));
  float*  lst    = (float*)(wsb + (512u << 10));
  uint*   flag   = (uint*)(wsb + (516u << 10));
  float*  pooled = (float*)(wsb + (520u << 10));
  ushort* PB     = (ushort*)(wsb + (1u << 20));       // param pool bf16
  ushort* S0     = (ushort*)(wsb + (4u << 20));       // x1
  ushort* S1     = S0 + NC;
  ushort* S2     = S1 + NC;
  ushort* S3     = S2 + NC;
  ushort* qkvb   = S1;                                // [N][768] overlay
  ushort* XB     = S3;                                // x bf16 (lower 16MB of S3)
  unsigned char* s3hi = (unsigned char*)(S3 + (size_t)N_TOT * DIN_);
  int*  csr    = (int*)s3hi;                          // 2 MB
  uint* rowptr = (uint*)(s3hi + (2u << 20));          // 256 KB
  uint* cursor = (uint*)(s3hi + (2u << 20) + (256u << 10));
  float* psum  = (float*)S2;                          // pool partials (S2 dead then)
  float* pmax  = psum + (size_t)B_GR * 8 * C_;

  // ---- dtype probe + import ----
  probe_dtype<<<1, 1, 0, stream>>>((const uint*)d_in[10], flag);
  CvtArgs ca;
  ca.s[0]  = { d_in[3],  O_L0LW };  ca.s[1]  = { d_in[4],  O_L0LB };
  ca.s[2]  = { d_in[5],  O_L0RW };  ca.s[3]  = { d_in[6],  O_L0RES };
  ca.s[4]  = { d_in[7],  O_LWL  };  ca.s[5]  = { d_in[8],  O_LBL  };
  ca.s[6]  = { d_in[9],  O_LWR  };  ca.s[7]  = { d_in[10], O_GNW  };
  ca.s[8]  = { d_in[11], O_GNB  };  ca.s[9]  = { d_in[12], O_GNA  };
  ca.s[10] = { d_in[13], O_AIW  };  ca.s[11] = { d_in[14], O_AIB  };
  ca.s[12] = { d_in[15], O_AOW  };  ca.s[13] = { d_in[16], O_AOB  };
  ca.s[14] = { d_in[17], O_LNW  };  ca.s[15] = { d_in[18], O_LNB  };
  ca.s[16] = { d_in[19], O_PLW  };  ca.s[17] = { d_in[20], O_PLB  };
  ca.s[18] = { nullptr,  TOTALP };
  cvt_params<<<(TOTALP + 255) / 256, 256, 0, stream>>>(ca, PB, flag);
  cvt_flat<<<(N_TOT * DIN_) / 256, 256, 0, stream>>>(d_in[0], XB, flag);

  // ---- degree + CSR build ----
  hipMemsetAsync(deg, 0, N_TOT * sizeof(uint), stream);
  hipMemsetAsync(wsb + (512u << 10), 0, 1024, stream);           // lst
  deg_count<<<E_TOT / 256, 256, 0, stream>>>(dstp, deg);
  scan_deg<<<B_GR, 512, 0, stream>>>(deg, rowptr, cursor);
  scatter_edges<<<E_TOT / 256, 256, 0, stream>>>(srcp, dstp, cursor, csr);

  // ---- layer 0 (DIN=128 -> C=256) ----
  sage_agg_csr<DIN_><<<N_TOT / 4, 256, 0, stream>>>(XB, csr, rowptr, deg, S1);
  hipMemsetAsync(wsb + (256u << 10), 0, 256u << 10, stream);     // m1+m2
  gemm_mfma<true, true><<<dim3(N_TOT / 64, 1), 256, 0, stream>>>(
      S1, DIN_, PB + O_L0LW, XB, DIN_, PB + O_L0RW, PB + O_L0LB, nullptr, S2, DIN_, C_, m1, m2);
  gemm_mfma<false, false><<<dim3(N_TOT / 64, 1), 256, 0, stream>>>(
      XB, DIN_, PB + O_L0RES, nullptr, 0, nullptr, nullptr, nullptr, S0, DIN_, C_, nullptr, nullptr);
  gn_gelu_add<<<(N_TOT * C_) / 1024, 256, 0, stream>>>(S2, S0, m1, m2,
      PB + O_GNW, PB + O_GNB, PB + O_GNA, S0);

  // ---- layers 1..3 (C -> C) ----
  for (int i = 0; i < 3; ++i) {
    sage_agg_csr<C_><<<N_TOT / 4, 256, 0, stream>>>(S0, csr, rowptr, deg, S1);
    hipMemsetAsync(wsb + (256u << 10), 0, 256u << 10, stream);   // m1+m2
    gemm_mfma<true, true><<<dim3(N_TOT / 64, 1), 256, 0, stream>>>(
        S1, C_, PB + O_LWL + (size_t)i * C_ * C_, S0, C_, PB + O_LWR + (size_t)i * C_ * C_,
        PB + O_LBL + i * C_, nullptr, S2, C_, C_, m1, m2);
    gn_gelu_add<<<(N_TOT * C_) / 1024, 256, 0, stream>>>(S2, S0, m1, m2,
        PB + O_GNW + (i + 1) * C_, PB + O_GNB + (i + 1) * C_, PB + O_GNA + (i + 1) * C_, S0);
  }

  // ---- attention ----
  gemm_mfma<false, false><<<dim3(N_TOT / 64, 3), 256, 0, stream>>>(
      S0, C_, PB + O_AIW, nullptr, 0, nullptr, PB + O_AIB, nullptr, qkvb, C_, C3_, nullptr, nullptr);
  attn_kernel<<<B_GR * H_, 512, 0, stream>>>(qkvb);
  gemm_mfma<false, false><<<dim3(N_TOT / 64, 1), 256, 0, stream>>>(
      qkvb + C_, C3_, PB + O_AOW, nullptr, 0, nullptr, PB + O_AOB, S0, S0, C_, C_, nullptr, nullptr);

  // ---- graph LayerNorm + gelu ----
  ln_part<<<dim3(B_GR, 8), 256, 0, stream>>>(S0, lst);
  ln_finalize<<<1, B_GR, 0, stream>>>(lst);
  ln_gelu<<<(N_TOT * C_) / 1024, 256, 0, stream>>>(S0, lst, PB + O_LNW, PB + O_LNB, S1);

  // ---- pool + projection ----
  pool_part<<<dim3(B_GR, 8), 256, 0, stream>>>(S1, psum, pmax);
  pool_final<<<B_GR, 256, 0, stream>>>(psum, pmax, pooled);
  final_gemm<<<B_GR, 256, 0, stream>>>(pooled, PB + O_PLW, PB + O_PLB, d_out, flag);
}